// Round 4
// baseline (2246.291 us; speedup 1.0000x reference)
//
#include <hip/hip_runtime.h>
#include <hip/hip_bf16.h>

#define NPTS 4096
#define CC   128
#define KNN  16
#define CNT_PER_GROUP 1048576.0f  // 16 ch * 4096 n * 16 k

// ---------------------------------------------------------------- zero stats
__global__ void zero_kernel(float* __restrict__ p) { p[threadIdx.x] = 0.0f; }

// ------------------------------------------------- conv1d 64->128, f32 in, f32 out [b*N+n][128]
__global__ void conv64_kernel(const float* __restrict__ x, const float* __restrict__ w,
                              const float* __restrict__ bias, float* __restrict__ out) {
    int tx = threadIdx.x & 127, ty = threadIdx.x >> 7;
    int p = blockIdx.x * 2 + ty;            // b*N + n
    int b = p >> 12, n = p & 4095;
    float acc = bias[tx];
    const float* xb = x + (size_t)b * 64 * NPTS + n;
    const float* wr = w + tx * 64;
    #pragma unroll 8
    for (int ci = 0; ci < 64; ++ci)
        acc += wr[ci] * xb[(size_t)ci * NPTS];
    out[(size_t)p * CC + tx] = acc;
}

// ------------------------------------------------- KNN f32, BLAS/XLA-style rounding:
// s1,s2 = l2r sums of squares (no FMA); dot = FMA chain (GEMM-style); d2=(s1+s2)-2*dt.
// 256 threads = 64 queries x 4 candidate-quarters; per-thread lex-top-16, LDS merge 64->16.
__global__ __launch_bounds__(256) void knn_kernel(
        const float* __restrict__ pc1, const float* __restrict__ pc2,
        int* __restrict__ idx12, int* __restrict__ idx21) {
#pragma clang fp contract(off)
    __shared__ __align__(16) unsigned char smem[49152];   // 48 KB
    float* cx = (float*)smem;                // [4096]
    float* cy = cx + NPTS;                   // [4096]
    float* cz = cy + NPTS;                   // [4096]
    int dir = blockIdx.y;
    const float* qs = dir ? pc2 : pc1;
    const float* cs = dir ? pc1 : pc2;
    int* outIdx = dir ? idx21 : idx12;
    int tid = threadIdx.x;
    int qL = tid & 63, rng = tid >> 6;
    int q = blockIdx.x * 64 + qL;            // all queries of a block share one b
    int b = q >> 12, n = q & 4095;
    const float* cb = cs + (size_t)b * 3 * NPTS;
    for (int i = tid; i < NPTS; i += 256) {
        cx[i] = cb[i];
        cy[i] = cb[NPTS + i];
        cz[i] = cb[2 * NPTS + i];
    }
    __syncthreads();
    const float* qb = qs + (size_t)b * 3 * NPTS;
    float qx = qb[n], qy = qb[NPTS + n], qz = qb[2 * NPTS + n];
    float s1 = qx * qx + qy * qy + qz * qz;  // l2r, each op rounded (contract off)

    float bd[KNN]; int bi[KNN];
    int m0 = rng * 1024;
    for (int j = 0; j < KNN; ++j) {
        int m = m0 + j;
        float x = cx[m], y = cy[m], z = cz[m];
        float s2 = x * x + y * y + z * z;                     // l2r no-FMA
        float dt = __builtin_fmaf(z, qz, __builtin_fmaf(y, qy, x * qx));  // GEMM FMA chain
        bd[j] = (s1 + s2) - 2.0f * dt;
        bi[j] = m;
    }
    // current worst: lexicographically largest (d2, idx)
    float wv = bd[0]; int wi = bi[0], wj = 0;
    for (int j = 1; j < KNN; ++j)
        if (bd[j] > wv || (bd[j] == wv && bi[j] > wi)) { wv = bd[j]; wi = bi[j]; wj = j; }

    for (int m = m0 + KNN; m < m0 + 1024; ++m) {
        float x = cx[m], y = cy[m], z = cz[m];
        float s2 = x * x + y * y + z * z;
        float dt = __builtin_fmaf(z, qz, __builtin_fmaf(y, qy, x * qx));
        float d2 = (s1 + s2) - 2.0f * dt;
        if (d2 < wv) {   // m > all kept indices, so tie (==) keeps existing lower index
            bd[wj] = d2; bi[wj] = m;
            wv = bd[0]; wi = bi[0]; wj = 0;
            for (int j = 1; j < KNN; ++j)
                if (bd[j] > wv || (bd[j] == wv && bi[j] > wi)) { wv = bd[j]; wi = bi[j]; wj = j; }
        }
    }
    __syncthreads();                         // everyone done reading coords
    float* md = (float*)smem;                // [64*64] = 16 KB
    int*   mi = (int*)(smem + 16384);        // [64*64] = 16 KB
    for (int j = 0; j < KNN; ++j) {
        md[qL * 64 + rng * KNN + j] = bd[j];
        mi[qL * 64 + rng * KNN + j] = bi[j];
    }
    __syncthreads();
    if (tid < 64) {
        float* d = md + tid * 64;
        int*   ix = mi + tid * 64;
        int qq = blockIdx.x * 64 + tid;
        for (int k = 0; k < KNN; ++k) {
            float bv = d[0]; int bidx = ix[0]; int bj = 0;
            for (int j = 1; j < 64; ++j) {
                float dv = d[j]; int di = ix[j];
                if (dv < bv || (dv == bv && di < bidx)) { bv = dv; bidx = di; bj = j; }
            }
            d[bj] = 1e30f;                   // remove from pool
            outIdx[(size_t)qq * KNN + k] = bidx;
        }
    }
}

// ------------------------------------------------- h0 = group(p2) + p1 + pos_conv(direction)
__global__ void h0_kernel(const float* __restrict__ p1f, const float* __restrict__ p2f,
                          const float* __restrict__ pcA, const float* __restrict__ pcB,
                          const int* __restrict__ idx,
                          const float* __restrict__ pos_w, const float* __restrict__ pos_b,
                          float* __restrict__ buf) {
    int p = blockIdx.x;                    // b*N + n
    int b = p >> 12, n = p & 4095;
    int c = threadIdx.x;
    float pw0 = pos_w[c * 3], pw1 = pos_w[c * 3 + 1], pw2 = pos_w[c * 3 + 2];
    float pb = pos_b[c];
    float p1v = p1f[(size_t)p * CC + c];
    const float* pa = pcA + (size_t)b * 3 * NPTS;
    const float* pc = pcB + (size_t)b * 3 * NPTS;
    float qx = pa[n], qy = pa[NPTS + n], qz = pa[2 * NPTS + n];
    for (int k = 0; k < KNN; ++k) {
        int m = idx[(size_t)p * KNN + k];
        float dx = pc[m] - qx;
        float dy = pc[NPTS + m] - qy;
        float dz = pc[2 * NPTS + m] - qz;
        float pos = pw0 * dx + pw1 * dy + pw2 * dz + pb;
        float v = p2f[((size_t)b * NPTS + m) * CC + c] + p1v + pos;
        buf[((size_t)p * KNN + k) * CC + c] = v;
    }
}

// ------------------------------------------------- per-(b,group) sum / sumsq over [131072][128]
__global__ void stats_kernel(const float* __restrict__ buf, float* __restrict__ stats) {
    __shared__ float ls[256], lq[256];
    int tid = threadIdx.x;
    int c = tid & 127, sl = tid >> 7;
    int s0 = blockIdx.x * 256;             // 256 s-rows per block, never crosses b
    float sum = 0.f, sq = 0.f;
    for (int j = 0; j < 128; ++j) {
        float v = buf[(size_t)(s0 + sl + 2 * j) * CC + c];
        sum += v; sq += v * v;
    }
    ls[tid] = sum; lq[tid] = sq;
    __syncthreads();
    if (tid < 8) {
        int g = tid;
        float S = 0.f, Q = 0.f;
        for (int h = 0; h < 2; ++h)
            for (int i = 0; i < 16; ++i) { int t = h * 128 + g * 16 + i; S += ls[t]; Q += lq[t]; }
        int b = s0 >> 16;
        atomicAdd(&stats[(b * 8 + g) * 2], S);
        atomicAdd(&stats[(b * 8 + g) * 2 + 1], Q);
    }
}

// ------------------------------------------------- y = W * lrelu(gn(x)) + bias  (128x128)
__global__ __launch_bounds__(256) void convgn_kernel(
        const float* __restrict__ xbuf, const float* __restrict__ stats,
        const float* __restrict__ gam, const float* __restrict__ bet,
        const float* __restrict__ w, const float* __restrict__ bias,
        float* __restrict__ ybuf) {
    __shared__ float xt[32 * CC];
    __shared__ float sc[CC], sh[CC];
    int tid = threadIdx.x;
    int s0 = blockIdx.x * 32;              // 32 s-rows per tile, never crosses b
    int b = s0 >> 16;
    if (tid < CC) {
        int g = tid >> 4;
        float mu = stats[(b * 8 + g) * 2] / CNT_PER_GROUP;
        float var = stats[(b * 8 + g) * 2 + 1] / CNT_PER_GROUP - mu * mu;
        float rs = rsqrtf(var + 1e-5f);
        float scale = gam[tid] * rs;
        sc[tid] = scale;
        sh[tid] = bet[tid] - mu * scale;
    }
    __syncthreads();
    #pragma unroll
    for (int j = 0; j < 16; ++j) {
        int e = tid + 256 * j;
        int c = e & 127;
        float v = xbuf[(size_t)(s0 + (e >> 7)) * CC + c];
        v = v * sc[c] + sh[c];
        xt[e] = v >= 0.f ? v : 0.1f * v;
    }
    __syncthreads();
    int co = (tid & 63) * 2;               // pair of output channels
    int sg = tid >> 6;                     // 4 groups of 8 s-rows
    float acc0[8], acc1[8];
    float b0 = bias[co], b1 = bias[co + 1];
    #pragma unroll
    for (int j = 0; j < 8; ++j) { acc0[j] = b0; acc1[j] = b1; }
    const float* w0 = w + (size_t)co * CC;
    for (int ci = 0; ci < CC; ++ci) {
        float wv0 = w0[ci], wv1 = w0[CC + ci];
        #pragma unroll
        for (int j = 0; j < 8; ++j) {
            float xv = xt[(sg * 8 + j) * CC + ci];   // broadcast within wave
            acc0[j] += wv0 * xv;
            acc1[j] += wv1 * xv;
        }
    }
    #pragma unroll
    for (int j = 0; j < 8; ++j) {
        size_t s = (size_t)(s0 + sg * 8 + j);
        *(float2*)&ybuf[s * CC + co] = make_float2(acc0[j], acc1[j]);
    }
}

// ------------------------------------------------- out[b][n][c] = max_k lrelu(gn(y))
__global__ void maxpool_kernel(const float* __restrict__ ybuf, const float* __restrict__ stats,
                               const float* __restrict__ gam, const float* __restrict__ bet,
                               float* __restrict__ outf, float* __restrict__ outb) {
    int p = blockIdx.x;                    // b*N + n
    int b = p >> 12, n = p & 4095;
    int c = threadIdx.x;
    int g = c >> 4;
    float mu = stats[(b * 8 + g) * 2] / CNT_PER_GROUP;
    float var = stats[(b * 8 + g) * 2 + 1] / CNT_PER_GROUP - mu * mu;
    float rs = rsqrtf(var + 1e-5f);
    float scale = gam[c] * rs;
    float shift = bet[c] - mu * scale;
    float mx = -INFINITY;
    for (int k = 0; k < KNN; ++k) {
        float v = ybuf[((size_t)p * KNN + k) * CC + c] * scale + shift;
        v = v >= 0.f ? v : 0.1f * v;
        mx = fmaxf(mx, v);
    }
    if (outf) outf[(size_t)p * CC + c] = mx;
    if (outb) outb[((size_t)b * CC + c) * NPTS + n] = mx;
}

// ------------------------------------------------- final 128x128 conv, f32 in, f32 + f32 out
__global__ void conv128_kernel(const float* __restrict__ x, const float* __restrict__ w,
                               const float* __restrict__ bias, float* __restrict__ outf,
                               float* __restrict__ outb) {
    int tx = threadIdx.x & 127, ty = threadIdx.x >> 7;
    int p = blockIdx.x * 2 + ty;
    int b = p >> 12, n = p & 4095;
    float acc = bias[tx];
    const float* xr = x + (size_t)p * CC;
    const float* wr = w + (size_t)tx * CC;
    #pragma unroll 8
    for (int ci = 0; ci < CC; ++ci) acc += wr[ci] * xr[ci];
    outf[(size_t)p * CC + tx] = acc;
    outb[((size_t)b * CC + tx) * NPTS + n] = acc;
}

extern "C" void kernel_launch(void* const* d_in, const int* in_sizes, int n_in,
                              void* d_out, int out_size, void* d_ws, size_t ws_size,
                              hipStream_t stream) {
    (void)in_sizes; (void)n_in; (void)out_size; (void)ws_size;
    const float* pc1    = (const float*)d_in[0];
    const float* pc2    = (const float*)d_in[1];
    const float* feat1  = (const float*)d_in[2];
    const float* feat2  = (const float*)d_in[3];
    const float* t11_w  = (const float*)d_in[4];
    const float* t11_b  = (const float*)d_in[5];
    const float* t22_w  = (const float*)d_in[6];
    const float* t22_b  = (const float*)d_in[7];
    const float* pos1_w = (const float*)d_in[8];
    const float* pos1_b = (const float*)d_in[9];
    const float* gn1_g  = (const float*)d_in[10];
    const float* gn1_b  = (const float*)d_in[11];
    const float* m1a_w  = (const float*)d_in[12];
    const float* m1a_b  = (const float*)d_in[13];
    const float* m1a_g  = (const float*)d_in[14];
    const float* m1a_be = (const float*)d_in[15];
    const float* m1b_w  = (const float*)d_in[16];
    const float* m1b_b  = (const float*)d_in[17];
    const float* m1b_g  = (const float*)d_in[18];
    const float* m1b_be = (const float*)d_in[19];
    const float* t1_w   = (const float*)d_in[20];
    const float* t1_b   = (const float*)d_in[21];
    const float* t2_w   = (const float*)d_in[22];
    const float* t2_b   = (const float*)d_in[23];
    const float* pos2_w = (const float*)d_in[24];
    const float* pos2_b = (const float*)d_in[25];
    const float* gn2_g  = (const float*)d_in[26];
    const float* gn2_b  = (const float*)d_in[27];
    const float* m2a_w  = (const float*)d_in[28];
    const float* m2a_b  = (const float*)d_in[29];
    const float* m2a_g  = (const float*)d_in[30];
    const float* m2a_be = (const float*)d_in[31];

    float* out = (float*)d_out;
    const size_t PN = 2 * NPTS;              // 8192 points
    const size_t PT = PN * CC;               // 1,048,576 f32 per point-tensor
    float* ws   = (float*)d_ws;
    float* f1   = ws;
    float* f2   = f1 + PT;
    float* g1   = f2 + PT;
    float* g2   = g1 + PT;
    float* f1n  = g2 + PT;
    float* f2n  = f1n + PT;
    float* cr   = f2n + PT;
    int*   idx12 = (int*)(cr + PT);
    int*   idx21 = idx12 + PN * KNN;
    float* stats = (float*)(idx21 + PN * KNN);     // 8 slots * 32 f32
    float* bufX  = stats + 256;
    float* bufY  = bufX + (size_t)PN * KNN * CC;   // 16,777,216 f32 each

    zero_kernel<<<1, 256, 0, stream>>>(stats);

    conv64_kernel<<<PN / 2, 256, 0, stream>>>(feat1, t11_w, t11_b, f1);
    conv64_kernel<<<PN / 2, 256, 0, stream>>>(feat2, t22_w, t22_b, f2);
    conv64_kernel<<<PN / 2, 256, 0, stream>>>(feat2, t11_w, t11_b, g1);
    conv64_kernel<<<PN / 2, 256, 0, stream>>>(feat1, t22_w, t22_b, g2);
    knn_kernel<<<dim3(PN / 64, 2), 256, 0, stream>>>(pc1, pc2, idx12, idx21);

    // ---- cross1: (pc1, pc2, f1, f2) -> t1 -> feat1_new
    h0_kernel<<<PN, 128, 0, stream>>>(f1, f2, pc1, pc2, idx12, pos1_w, pos1_b, bufX);
    stats_kernel<<<512, 256, 0, stream>>>(bufX, stats + 0 * 32);
    convgn_kernel<<<4096, 256, 0, stream>>>(bufX, stats + 0 * 32, gn1_g, gn1_b, m1a_w, m1a_b, bufY);
    stats_kernel<<<512, 256, 0, stream>>>(bufY, stats + 1 * 32);
    convgn_kernel<<<4096, 256, 0, stream>>>(bufY, stats + 1 * 32, m1a_g, m1a_be, m1b_w, m1b_b, bufX);
    stats_kernel<<<512, 256, 0, stream>>>(bufX, stats + 2 * 32);
    maxpool_kernel<<<PN, 128, 0, stream>>>(bufX, stats + 2 * 32, m1b_g, m1b_be, cr, nullptr);
    conv128_kernel<<<PN / 2, 256, 0, stream>>>(cr, t1_w, t1_b, f1n, out);

    // ---- cross2: (pc2, pc1, g1, g2) -> t2 -> feat2_new
    h0_kernel<<<PN, 128, 0, stream>>>(g1, g2, pc2, pc1, idx21, pos1_w, pos1_b, bufX);
    stats_kernel<<<512, 256, 0, stream>>>(bufX, stats + 3 * 32);
    convgn_kernel<<<4096, 256, 0, stream>>>(bufX, stats + 3 * 32, gn1_g, gn1_b, m1a_w, m1a_b, bufY);
    stats_kernel<<<512, 256, 0, stream>>>(bufY, stats + 4 * 32);
    convgn_kernel<<<4096, 256, 0, stream>>>(bufY, stats + 4 * 32, m1a_g, m1a_be, m1b_w, m1b_b, bufX);
    stats_kernel<<<512, 256, 0, stream>>>(bufX, stats + 5 * 32);
    maxpool_kernel<<<PN, 128, 0, stream>>>(bufX, stats + 5 * 32, m1b_g, m1b_be, cr, nullptr);
    conv128_kernel<<<PN / 2, 256, 0, stream>>>(cr, t2_w, t2_b, f2n, out + PT);

    // ---- cross3: (pc1, pc2, feat1_new, feat2_new) -> feat1_final
    h0_kernel<<<PN, 128, 0, stream>>>(f1n, f2n, pc1, pc2, idx12, pos2_w, pos2_b, bufX);
    stats_kernel<<<512, 256, 0, stream>>>(bufX, stats + 6 * 32);
    convgn_kernel<<<4096, 256, 0, stream>>>(bufX, stats + 6 * 32, gn2_g, gn2_b, m2a_w, m2a_b, bufY);
    stats_kernel<<<512, 256, 0, stream>>>(bufY, stats + 7 * 32);
    maxpool_kernel<<<PN, 128, 0, stream>>>(bufY, stats + 7 * 32, m2a_g, m2a_be, nullptr, out + 2 * PT);
}

// Round 5
// 1495.187 us; speedup vs baseline: 1.5023x; 1.5023x over previous
//
#include <hip/hip_runtime.h>
#include <hip/hip_bf16.h>

#define NPTS 4096
#define CC   128
#define KNN  16
#define CNT_PER_GROUP 1048576.0f  // 16 ch * 4096 n * 16 k

// ---------------------------------------------------------------- zero stats
__global__ void zero_kernel(float* __restrict__ p) { p[threadIdx.x] = 0.0f; }

// ------------------------------------------------- conv1d 64->128, f32 in, f32 out [b*N+n][128]
__global__ void conv64_kernel(const float* __restrict__ x, const float* __restrict__ w,
                              const float* __restrict__ bias, float* __restrict__ out) {
    int tx = threadIdx.x & 127, ty = threadIdx.x >> 7;
    int p = blockIdx.x * 2 + ty;            // b*N + n
    int b = p >> 12, n = p & 4095;
    float acc = bias[tx];
    const float* xb = x + (size_t)b * 64 * NPTS + n;
    const float* wr = w + tx * 64;
    #pragma unroll 8
    for (int ci = 0; ci < 64; ++ci)
        acc += wr[ci] * xb[(size_t)ci * NPTS];
    out[(size_t)p * CC + tx] = acc;
}

// ---------------------------------------------------------------- 64-bit shuffles
static __device__ __forceinline__ unsigned long long sxor64(unsigned long long v, int m) {
    unsigned lo = (unsigned)__shfl_xor((int)(unsigned)v, m);
    unsigned hi = (unsigned)__shfl_xor((int)(v >> 32), m);
    return ((unsigned long long)hi << 32) | lo;
}
static __device__ __forceinline__ unsigned long long sup64(unsigned long long v, int d) {
    unsigned lo = (unsigned)__shfl_up((int)(unsigned)v, d);
    unsigned hi = (unsigned)__shfl_up((int)(v >> 32), d);
    return ((unsigned long long)hi << 32) | lo;
}

// ------------------------------------------------- KNN, wave-per-query, threshold filter.
// d2 rounding matches the passing round exactly: s1,s2 l2r no-FMA (contract off),
// dot = FMA chain, d2 = (s1+s2) - 2*dt. Selection = stable lex top-16 on (d2, idx).
__global__ __launch_bounds__(256) void knn_kernel(
        const float* __restrict__ pc1, const float* __restrict__ pc2,
        int* __restrict__ idx12, int* __restrict__ idx21) {
#pragma clang fp contract(off)
    __shared__ float cx[NPTS], cy[NPTS], cz[NPTS];        // 48 KB
    __shared__ unsigned long long lst[4][128];            // 4 KB, per-wave scratch
    int dir = blockIdx.y;
    const float* qs = dir ? pc2 : pc1;
    const float* cs = dir ? pc1 : pc2;
    int* outIdx = dir ? idx21 : idx12;
    int tid = threadIdx.x, lane = tid & 63, wv = tid >> 6;
    int qbase = blockIdx.x * 16;           // 16 queries per block, same b
    int b = qbase >> 12;
    const float* cb = cs + (size_t)b * 3 * NPTS;
    for (int i = tid; i < NPTS; i += 256) {
        cx[i] = cb[i]; cy[i] = cb[NPTS + i]; cz[i] = cb[2 * NPTS + i];
    }
    __syncthreads();
    const float* qb = qs + (size_t)b * 3 * NPTS;
    for (int r = 0; r < 4; ++r) {
        int q = qbase + wv * 4 + r;
        int n = q & 4095;
        float qx = qb[n], qy = qb[NPTS + n], qz = qb[2 * NPTS + n];  // uniform -> broadcast
        float s1 = qx * qx + qy * qy + qz * qz;   // l2r, no fma
        float d2v[64];
        float dmin = 1e30f;
        #pragma unroll
        for (int j = 0; j < 64; ++j) {            // lane's candidates: m = j*64 + lane
            int m = j * 64 + lane;
            float x = cx[m], y = cy[m], z = cz[m];
            float s2 = x * x + y * y + z * z;     // l2r, no fma
            float dt = __builtin_fmaf(z, qz, __builtin_fmaf(y, qy, x * qx));
            float d2 = (s1 + s2) - 2.0f * dt;
            d2v[j] = d2;
            dmin = fminf(dmin, d2);
        }
        // T = 16th smallest of the 64 per-lane minima: 16 distinct elements are <= T,
        // so the true global 16th-smallest d2 is <= T. Bitonic sort dmin across lanes.
        float sv = dmin;
        for (int k = 2; k <= 64; k <<= 1)
            for (int j = k >> 1; j > 0; j >>= 1) {
                float o = __shfl_xor(sv, j);
                bool tmin = (((lane & k) == 0) == ((lane & j) == 0));
                sv = tmin ? fminf(sv, o) : fmaxf(sv, o);
            }
        float T = __shfl(sv, 15);
        // Ballot-compact all candidates with d2 <= T (catches ties) into per-wave list.
        int base = 0;
        #pragma unroll
        for (int j = 0; j < 64; ++j) {
            bool p = (d2v[j] <= T);
            unsigned long long mk = __ballot(p);
            if (p) {
                int pos = base + (int)__popcll(mk & ((1ULL << lane) - 1ULL));
                unsigned u = __float_as_uint(d2v[j]);
                u ^= (unsigned)(((int)u >> 31) | 0x80000000);   // monotone total order incl. negatives
                unsigned long long key = ((unsigned long long)u << 32) | (unsigned)(j * 64 + lane);
                if (pos < 128) lst[wv][pos] = key;
            }
            base += (int)__popcll(mk);
        }
        int nT = base < 128 ? base : 128;         // E[base] ~ 19; >128 is ~e^-60 territory
        unsigned long long key = (lane < nT) ? lst[wv][lane] : ~0ULL;
        // bitonic sort 64 packed keys ascending -> lanes 0..15 hold stable top-16
        for (int k = 2; k <= 64; k <<= 1)
            for (int j = k >> 1; j > 0; j >>= 1) {
                unsigned long long o = sxor64(key, j);
                bool tmin = (((lane & k) == 0) == ((lane & j) == 0));
                unsigned long long mn = key < o ? key : o;
                unsigned long long mx = key < o ? o : key;
                key = tmin ? mn : mx;
            }
        // deterministic fold-in of extras beyond 64 (essentially never taken)
        for (int e = 64; e < nT; ++e) {
            unsigned long long ev = lst[wv][e];   // uniform broadcast read
            int pcnt = (int)__popcll(__ballot(key < ev));
            unsigned long long sh = sup64(key, 1);
            key = (lane < pcnt) ? key : (lane == pcnt ? ev : sh);
        }
        if (lane < KNN) outIdx[(size_t)q * KNN + lane] = (int)(unsigned)(key & 0xFFFFFFFFULL);
    }
}

// ------------------------------------------------- h0 = group(p2) + p1 + pos_conv(direction)
__global__ void h0_kernel(const float* __restrict__ p1f, const float* __restrict__ p2f,
                          const float* __restrict__ pcA, const float* __restrict__ pcB,
                          const int* __restrict__ idx,
                          const float* __restrict__ pos_w, const float* __restrict__ pos_b,
                          float* __restrict__ buf) {
    int p = blockIdx.x;                    // b*N + n
    int b = p >> 12, n = p & 4095;
    int c = threadIdx.x;
    float pw0 = pos_w[c * 3], pw1 = pos_w[c * 3 + 1], pw2 = pos_w[c * 3 + 2];
    float pb = pos_b[c];
    float p1v = p1f[(size_t)p * CC + c];
    const float* pa = pcA + (size_t)b * 3 * NPTS;
    const float* pc = pcB + (size_t)b * 3 * NPTS;
    float qx = pa[n], qy = pa[NPTS + n], qz = pa[2 * NPTS + n];
    for (int k = 0; k < KNN; ++k) {
        int m = idx[(size_t)p * KNN + k];
        float dx = pc[m] - qx;
        float dy = pc[NPTS + m] - qy;
        float dz = pc[2 * NPTS + m] - qz;
        float pos = pw0 * dx + pw1 * dy + pw2 * dz + pb;
        float v = p2f[((size_t)b * NPTS + m) * CC + c] + p1v + pos;
        buf[((size_t)p * KNN + k) * CC + c] = v;
    }
}

// ------------------------------------------------- per-(b,group) sum / sumsq over [131072][128]
__global__ void stats_kernel(const float* __restrict__ buf, float* __restrict__ stats) {
    __shared__ float ls[256], lq[256];
    int tid = threadIdx.x;
    int c = tid & 127, sl = tid >> 7;
    int s0 = blockIdx.x * 256;             // 256 s-rows per block, never crosses b
    float sum = 0.f, sq = 0.f;
    for (int j = 0; j < 128; ++j) {
        float v = buf[(size_t)(s0 + sl + 2 * j) * CC + c];
        sum += v; sq += v * v;
    }
    ls[tid] = sum; lq[tid] = sq;
    __syncthreads();
    if (tid < 8) {
        int g = tid;
        float S = 0.f, Q = 0.f;
        for (int h = 0; h < 2; ++h)
            for (int i = 0; i < 16; ++i) { int t = h * 128 + g * 16 + i; S += ls[t]; Q += lq[t]; }
        int b = s0 >> 16;
        atomicAdd(&stats[(b * 8 + g) * 2], S);
        atomicAdd(&stats[(b * 8 + g) * 2 + 1], Q);
    }
}

// ------------------------------------------------- y = W * lrelu(gn(x)) + bias  (128x128)
__global__ __launch_bounds__(256) void convgn_kernel(
        const float* __restrict__ xbuf, const float* __restrict__ stats,
        const float* __restrict__ gam, const float* __restrict__ bet,
        const float* __restrict__ w, const float* __restrict__ bias,
        float* __restrict__ ybuf) {
    __shared__ float xt[32 * CC];
    __shared__ float sc[CC], sh[CC];
    int tid = threadIdx.x;
    int s0 = blockIdx.x * 32;              // 32 s-rows per tile, never crosses b
    int b = s0 >> 16;
    if (tid < CC) {
        int g = tid >> 4;
        float mu = stats[(b * 8 + g) * 2] / CNT_PER_GROUP;
        float var = stats[(b * 8 + g) * 2 + 1] / CNT_PER_GROUP - mu * mu;
        float rs = rsqrtf(var + 1e-5f);
        float scale = gam[tid] * rs;
        sc[tid] = scale;
        sh[tid] = bet[tid] - mu * scale;
    }
    __syncthreads();
    #pragma unroll
    for (int j = 0; j < 16; ++j) {
        int e = tid + 256 * j;
        int c = e & 127;
        float v = xbuf[(size_t)(s0 + (e >> 7)) * CC + c];
        v = v * sc[c] + sh[c];
        xt[e] = v >= 0.f ? v : 0.1f * v;
    }
    __syncthreads();
    int co = (tid & 63) * 2;               // pair of output channels
    int sg = tid >> 6;                     // 4 groups of 8 s-rows
    float acc0[8], acc1[8];
    float b0 = bias[co], b1 = bias[co + 1];
    #pragma unroll
    for (int j = 0; j < 8; ++j) { acc0[j] = b0; acc1[j] = b1; }
    const float* w0 = w + (size_t)co * CC;
    for (int ci = 0; ci < CC; ++ci) {
        float wv0 = w0[ci], wv1 = w0[CC + ci];
        #pragma unroll
        for (int j = 0; j < 8; ++j) {
            float xv = xt[(sg * 8 + j) * CC + ci];   // broadcast within wave
            acc0[j] += wv0 * xv;
            acc1[j] += wv1 * xv;
        }
    }
    #pragma unroll
    for (int j = 0; j < 8; ++j) {
        size_t s = (size_t)(s0 + sg * 8 + j);
        *(float2*)&ybuf[s * CC + co] = make_float2(acc0[j], acc1[j]);
    }
}

// ------------------------------------------------- out[b][n][c] = max_k lrelu(gn(y))
__global__ void maxpool_kernel(const float* __restrict__ ybuf, const float* __restrict__ stats,
                               const float* __restrict__ gam, const float* __restrict__ bet,
                               float* __restrict__ outf, float* __restrict__ outb) {
    int p = blockIdx.x;                    // b*N + n
    int b = p >> 12, n = p & 4095;
    int c = threadIdx.x;
    int g = c >> 4;
    float mu = stats[(b * 8 + g) * 2] / CNT_PER_GROUP;
    float var = stats[(b * 8 + g) * 2 + 1] / CNT_PER_GROUP - mu * mu;
    float rs = rsqrtf(var + 1e-5f);
    float scale = gam[c] * rs;
    float shift = bet[c] - mu * scale;
    float mx = -INFINITY;
    for (int k = 0; k < KNN; ++k) {
        float v = ybuf[((size_t)p * KNN + k) * CC + c] * scale + shift;
        v = v >= 0.f ? v : 0.1f * v;
        mx = fmaxf(mx, v);
    }
    if (outf) outf[(size_t)p * CC + c] = mx;
    if (outb) outb[((size_t)b * CC + c) * NPTS + n] = mx;
}

// ------------------------------------------------- final 128x128 conv, f32 in, f32 + f32 out
__global__ void conv128_kernel(const float* __restrict__ x, const float* __restrict__ w,
                               const float* __restrict__ bias, float* __restrict__ outf,
                               float* __restrict__ outb) {
    int tx = threadIdx.x & 127, ty = threadIdx.x >> 7;
    int p = blockIdx.x * 2 + ty;
    int b = p >> 12, n = p & 4095;
    float acc = bias[tx];
    const float* xr = x + (size_t)p * CC;
    const float* wr = w + (size_t)tx * CC;
    #pragma unroll 8
    for (int ci = 0; ci < CC; ++ci) acc += wr[ci] * xr[ci];
    outf[(size_t)p * CC + tx] = acc;
    outb[((size_t)b * CC + tx) * NPTS + n] = acc;
}

extern "C" void kernel_launch(void* const* d_in, const int* in_sizes, int n_in,
                              void* d_out, int out_size, void* d_ws, size_t ws_size,
                              hipStream_t stream) {
    (void)in_sizes; (void)n_in; (void)out_size; (void)ws_size;
    const float* pc1    = (const float*)d_in[0];
    const float* pc2    = (const float*)d_in[1];
    const float* feat1  = (const float*)d_in[2];
    const float* feat2  = (const float*)d_in[3];
    const float* t11_w  = (const float*)d_in[4];
    const float* t11_b  = (const float*)d_in[5];
    const float* t22_w  = (const float*)d_in[6];
    const float* t22_b  = (const float*)d_in[7];
    const float* pos1_w = (const float*)d_in[8];
    const float* pos1_b = (const float*)d_in[9];
    const float* gn1_g  = (const float*)d_in[10];
    const float* gn1_b  = (const float*)d_in[11];
    const float* m1a_w  = (const float*)d_in[12];
    const float* m1a_b  = (const float*)d_in[13];
    const float* m1a_g  = (const float*)d_in[14];
    const float* m1a_be = (const float*)d_in[15];
    const float* m1b_w  = (const float*)d_in[16];
    const float* m1b_b  = (const float*)d_in[17];
    const float* m1b_g  = (const float*)d_in[18];
    const float* m1b_be = (const float*)d_in[19];
    const float* t1_w   = (const float*)d_in[20];
    const float* t1_b   = (const float*)d_in[21];
    const float* t2_w   = (const float*)d_in[22];
    const float* t2_b   = (const float*)d_in[23];
    const float* pos2_w = (const float*)d_in[24];
    const float* pos2_b = (const float*)d_in[25];
    const float* gn2_g  = (const float*)d_in[26];
    const float* gn2_b  = (const float*)d_in[27];
    const float* m2a_w  = (const float*)d_in[28];
    const float* m2a_b  = (const float*)d_in[29];
    const float* m2a_g  = (const float*)d_in[30];
    const float* m2a_be = (const float*)d_in[31];

    float* out = (float*)d_out;
    const size_t PN = 2 * NPTS;              // 8192 points
    const size_t PT = PN * CC;               // 1,048,576 f32 per point-tensor
    float* ws   = (float*)d_ws;
    float* f1   = ws;
    float* f2   = f1 + PT;
    float* g1   = f2 + PT;
    float* g2   = g1 + PT;
    float* f1n  = g2 + PT;
    float* f2n  = f1n + PT;
    float* cr   = f2n + PT;
    int*   idx12 = (int*)(cr + PT);
    int*   idx21 = idx12 + PN * KNN;
    float* stats = (float*)(idx21 + PN * KNN);     // 8 slots * 32 f32
    float* bufX  = stats + 256;
    float* bufY  = bufX + (size_t)PN * KNN * CC;   // 16,777,216 f32 each

    zero_kernel<<<1, 256, 0, stream>>>(stats);

    conv64_kernel<<<PN / 2, 256, 0, stream>>>(feat1, t11_w, t11_b, f1);
    conv64_kernel<<<PN / 2, 256, 0, stream>>>(feat2, t22_w, t22_b, f2);
    conv64_kernel<<<PN / 2, 256, 0, stream>>>(feat2, t11_w, t11_b, g1);
    conv64_kernel<<<PN / 2, 256, 0, stream>>>(feat1, t22_w, t22_b, g2);
    knn_kernel<<<dim3(PN / 16, 2), 256, 0, stream>>>(pc1, pc2, idx12, idx21);

    // ---- cross1: (pc1, pc2, f1, f2) -> t1 -> feat1_new
    h0_kernel<<<PN, 128, 0, stream>>>(f1, f2, pc1, pc2, idx12, pos1_w, pos1_b, bufX);
    stats_kernel<<<512, 256, 0, stream>>>(bufX, stats + 0 * 32);
    convgn_kernel<<<4096, 256, 0, stream>>>(bufX, stats + 0 * 32, gn1_g, gn1_b, m1a_w, m1a_b, bufY);
    stats_kernel<<<512, 256, 0, stream>>>(bufY, stats + 1 * 32);
    convgn_kernel<<<4096, 256, 0, stream>>>(bufY, stats + 1 * 32, m1a_g, m1a_be, m1b_w, m1b_b, bufX);
    stats_kernel<<<512, 256, 0, stream>>>(bufX, stats + 2 * 32);
    maxpool_kernel<<<PN, 128, 0, stream>>>(bufX, stats + 2 * 32, m1b_g, m1b_be, cr, nullptr);
    conv128_kernel<<<PN / 2, 256, 0, stream>>>(cr, t1_w, t1_b, f1n, out);

    // ---- cross2: (pc2, pc1, g1, g2) -> t2 -> feat2_new
    h0_kernel<<<PN, 128, 0, stream>>>(g1, g2, pc2, pc1, idx21, pos1_w, pos1_b, bufX);
    stats_kernel<<<512, 256, 0, stream>>>(bufX, stats + 3 * 32);
    convgn_kernel<<<4096, 256, 0, stream>>>(bufX, stats + 3 * 32, gn1_g, gn1_b, m1a_w, m1a_b, bufY);
    stats_kernel<<<512, 256, 0, stream>>>(bufY, stats + 4 * 32);
    convgn_kernel<<<4096, 256, 0, stream>>>(bufY, stats + 4 * 32, m1a_g, m1a_be, m1b_w, m1b_b, bufX);
    stats_kernel<<<512, 256, 0, stream>>>(bufX, stats + 5 * 32);
    maxpool_kernel<<<PN, 128, 0, stream>>>(bufX, stats + 5 * 32, m1b_g, m1b_be, cr, nullptr);
    conv128_kernel<<<PN / 2, 256, 0, stream>>>(cr, t2_w, t2_b, f2n, out + PT);

    // ---- cross3: (pc1, pc2, feat1_new, feat2_new) -> feat1_final
    h0_kernel<<<PN, 128, 0, stream>>>(f1n, f2n, pc1, pc2, idx12, pos2_w, pos2_b, bufX);
    stats_kernel<<<512, 256, 0, stream>>>(bufX, stats + 6 * 32);
    convgn_kernel<<<4096, 256, 0, stream>>>(bufX, stats + 6 * 32, gn2_g, gn2_b, m2a_w, m2a_b, bufY);
    stats_kernel<<<512, 256, 0, stream>>>(bufY, stats + 7 * 32);
    maxpool_kernel<<<PN, 128, 0, stream>>>(bufY, stats + 7 * 32, m2a_g, m2a_be, nullptr, out + 2 * PT);
}

// Round 6
// 798.761 us; speedup vs baseline: 2.8122x; 1.8719x over previous
//
#include <hip/hip_runtime.h>
#include <hip/hip_bf16.h>

#define NPTS 4096
#define CC   128
#define KNN  16
#define CNT_PER_GROUP 1048576.0f  // 16 ch * 4096 n * 16 k
// stats layout per stage: 32 partial slots x [b(2) x g(8) x 2] = 1024 floats
#define STAT_STRIDE 1024

// ---------------------------------------------------------------- zero stats (8 stages)
__global__ void zero_kernel(float* __restrict__ p) {
    p[blockIdx.x * 256 + threadIdx.x] = 0.0f;
}

// ---------------------------------------------------------------- transpose [O][C] -> [C][O]
__global__ void transpose_kernel(const float* __restrict__ in, float* __restrict__ out,
                                 int O, int Cdim) {
    int idx = blockIdx.x * 256 + threadIdx.x;
    if (idx < O * Cdim) {
        int o = idx / Cdim, c = idx % Cdim;
        out[c * O + o] = in[idx];
    }
}

// ------------------------------------------------- conv1d 64->128, wT[ci][co] coalesced
__global__ void conv64_kernel(const float* __restrict__ x, const float* __restrict__ wT,
                              const float* __restrict__ bias, float* __restrict__ out) {
    int tx = threadIdx.x & 127, ty = threadIdx.x >> 7;
    int p = blockIdx.x * 2 + ty;            // b*N + n
    int b = p >> 12, n = p & 4095;
    float acc = bias[tx];
    const float* xb = x + (size_t)b * 64 * NPTS + n;
    #pragma unroll 8
    for (int ci = 0; ci < 64; ++ci)
        acc += wT[(size_t)ci * CC + tx] * xb[(size_t)ci * NPTS];
    out[(size_t)p * CC + tx] = acc;
}

// ---------------------------------------------------------------- 64-bit shuffles
static __device__ __forceinline__ unsigned long long sxor64(unsigned long long v, int m) {
    unsigned lo = (unsigned)__shfl_xor((int)(unsigned)v, m);
    unsigned hi = (unsigned)__shfl_xor((int)(v >> 32), m);
    return ((unsigned long long)hi << 32) | lo;
}
static __device__ __forceinline__ unsigned long long sup64(unsigned long long v, int d) {
    unsigned lo = (unsigned)__shfl_up((int)(unsigned)v, d);
    unsigned hi = (unsigned)__shfl_up((int)(v >> 32), d);
    return ((unsigned long long)hi << 32) | lo;
}

// ------------------------------------------------- KNN (unchanged, passing)
__global__ __launch_bounds__(256) void knn_kernel(
        const float* __restrict__ pc1, const float* __restrict__ pc2,
        int* __restrict__ idx12, int* __restrict__ idx21) {
#pragma clang fp contract(off)
    __shared__ float cx[NPTS], cy[NPTS], cz[NPTS];        // 48 KB
    __shared__ unsigned long long lst[4][128];            // 4 KB
    int dir = blockIdx.y;
    const float* qs = dir ? pc2 : pc1;
    const float* cs = dir ? pc1 : pc2;
    int* outIdx = dir ? idx21 : idx12;
    int tid = threadIdx.x, lane = tid & 63, wv = tid >> 6;
    int qbase = blockIdx.x * 16;
    int b = qbase >> 12;
    const float* cb = cs + (size_t)b * 3 * NPTS;
    for (int i = tid; i < NPTS; i += 256) {
        cx[i] = cb[i]; cy[i] = cb[NPTS + i]; cz[i] = cb[2 * NPTS + i];
    }
    __syncthreads();
    const float* qb = qs + (size_t)b * 3 * NPTS;
    for (int r = 0; r < 4; ++r) {
        int q = qbase + wv * 4 + r;
        int n = q & 4095;
        float qx = qb[n], qy = qb[NPTS + n], qz = qb[2 * NPTS + n];
        float s1 = qx * qx + qy * qy + qz * qz;   // l2r, no fma
        float d2v[64];
        float dmin = 1e30f;
        #pragma unroll
        for (int j = 0; j < 64; ++j) {
            int m = j * 64 + lane;
            float x = cx[m], y = cy[m], z = cz[m];
            float s2 = x * x + y * y + z * z;
            float dt = __builtin_fmaf(z, qz, __builtin_fmaf(y, qy, x * qx));
            float d2 = (s1 + s2) - 2.0f * dt;
            d2v[j] = d2;
            dmin = fminf(dmin, d2);
        }
        float sv = dmin;
        for (int k = 2; k <= 64; k <<= 1)
            for (int j = k >> 1; j > 0; j >>= 1) {
                float o = __shfl_xor(sv, j);
                bool tmin = (((lane & k) == 0) == ((lane & j) == 0));
                sv = tmin ? fminf(sv, o) : fmaxf(sv, o);
            }
        float T = __shfl(sv, 15);
        int base = 0;
        #pragma unroll
        for (int j = 0; j < 64; ++j) {
            bool p = (d2v[j] <= T);
            unsigned long long mk = __ballot(p);
            if (p) {
                int pos = base + (int)__popcll(mk & ((1ULL << lane) - 1ULL));
                unsigned u = __float_as_uint(d2v[j]);
                u ^= (unsigned)(((int)u >> 31) | 0x80000000);
                unsigned long long key = ((unsigned long long)u << 32) | (unsigned)(j * 64 + lane);
                if (pos < 128) lst[wv][pos] = key;
            }
            base += (int)__popcll(mk);
        }
        int nT = base < 128 ? base : 128;
        unsigned long long key = (lane < nT) ? lst[wv][lane] : ~0ULL;
        for (int k = 2; k <= 64; k <<= 1)
            for (int j = k >> 1; j > 0; j >>= 1) {
                unsigned long long o = sxor64(key, j);
                bool tmin = (((lane & k) == 0) == ((lane & j) == 0));
                unsigned long long mn = key < o ? key : o;
                unsigned long long mx = key < o ? o : key;
                key = tmin ? mn : mx;
            }
        for (int e = 64; e < nT; ++e) {
            unsigned long long ev = lst[wv][e];
            int pcnt = (int)__popcll(__ballot(key < ev));
            unsigned long long sh = sup64(key, 1);
            key = (lane < pcnt) ? key : (lane == pcnt ? ev : sh);
        }
        if (lane < KNN) outIdx[(size_t)q * KNN + lane] = (int)(unsigned)(key & 0xFFFFFFFFULL);
    }
}

// ------------------------------------------------- h0 = group(p2) + p1 + pos_conv + fused stats
__global__ void h0_kernel(const float* __restrict__ p1f, const float* __restrict__ p2f,
                          const float* __restrict__ pcA, const float* __restrict__ pcB,
                          const int* __restrict__ idx,
                          const float* __restrict__ pos_w, const float* __restrict__ pos_b,
                          float* __restrict__ buf, float* __restrict__ stats_out) {
    __shared__ float redS[128], redQ[128];
    int p = blockIdx.x;                    // b*N + n
    int b = p >> 12, n = p & 4095;
    int c = threadIdx.x;
    float pw0 = pos_w[c * 3], pw1 = pos_w[c * 3 + 1], pw2 = pos_w[c * 3 + 2];
    float pb = pos_b[c];
    float p1v = p1f[(size_t)p * CC + c];
    const float* pa = pcA + (size_t)b * 3 * NPTS;
    const float* pc = pcB + (size_t)b * 3 * NPTS;
    float qx = pa[n], qy = pa[NPTS + n], qz = pa[2 * NPTS + n];
    float S = 0.f, Q = 0.f;
    for (int k = 0; k < KNN; ++k) {
        int m = idx[(size_t)p * KNN + k];
        float dx = pc[m] - qx;
        float dy = pc[NPTS + m] - qy;
        float dz = pc[2 * NPTS + m] - qz;
        float pos = pw0 * dx + pw1 * dy + pw2 * dz + pb;
        float v = p2f[((size_t)b * NPTS + m) * CC + c] + p1v + pos;
        buf[((size_t)p * KNN + k) * CC + c] = v;
        S += v; Q += v * v;
    }
    redS[c] = S; redQ[c] = Q;
    __syncthreads();
    if (c < 8) {
        float SS = 0.f, QQ = 0.f;
        for (int i = 0; i < 16; ++i) { SS += redS[c * 16 + i]; QQ += redQ[c * 16 + i]; }
        int s = blockIdx.x & 31;
        atomicAdd(&stats_out[s * 32 + (b * 8 + c) * 2],     SS);
        atomicAdd(&stats_out[s * 32 + (b * 8 + c) * 2 + 1], QQ);
    }
}

// ------------------------------------------------- y = W * lrelu(gn(x)) + bias, fused stats
// block: 64 rows x 128 co; thread: 4 co x 8 rows; wT[ci][co] coalesced float4 loads
__global__ __launch_bounds__(256) void convgn_kernel(
        const float* __restrict__ xbuf, const float* __restrict__ stats_in,
        const float* __restrict__ gam, const float* __restrict__ bet,
        const float* __restrict__ wT, const float* __restrict__ bias,
        float* __restrict__ ybuf, float* __restrict__ stats_out) {
    __shared__ float xt[64 * CC];          // 32 KB
    __shared__ float sc[CC], sh[CC];
    __shared__ float redS[256], redQ[256];
    int tid = threadIdx.x;
    int s0 = blockIdx.x * 64;              // 64 rows, never crosses b
    int b = s0 >> 16;
    if (tid < CC) {
        int g = tid >> 4;
        float S = 0.f, Q = 0.f;
        for (int s = 0; s < 32; ++s) {
            S += stats_in[s * 32 + (b * 8 + g) * 2];
            Q += stats_in[s * 32 + (b * 8 + g) * 2 + 1];
        }
        float mu = S / CNT_PER_GROUP;
        float var = Q / CNT_PER_GROUP - mu * mu;
        float rs = rsqrtf(var + 1e-5f);
        float scale = gam[tid] * rs;
        sc[tid] = scale;
        sh[tid] = bet[tid] - mu * scale;
    }
    __syncthreads();
    #pragma unroll
    for (int j = 0; j < 8; ++j) {
        int idx = tid + 256 * j;           // 2048 float4s
        int row = idx >> 5, c4 = (idx & 31) * 4;
        float4 v = *(const float4*)&xbuf[(size_t)(s0 + row) * CC + c4];
        v.x = v.x * sc[c4]     + sh[c4];     v.x = v.x >= 0.f ? v.x : 0.1f * v.x;
        v.y = v.y * sc[c4 + 1] + sh[c4 + 1]; v.y = v.y >= 0.f ? v.y : 0.1f * v.y;
        v.z = v.z * sc[c4 + 2] + sh[c4 + 2]; v.z = v.z >= 0.f ? v.z : 0.1f * v.z;
        v.w = v.w * sc[c4 + 3] + sh[c4 + 3]; v.w = v.w >= 0.f ? v.w : 0.1f * v.w;
        *(float4*)&xt[row * CC + c4] = v;
    }
    __syncthreads();
    int co = (tid & 31) * 4;               // 4 output channels (same GN group)
    int r0 = (tid >> 5) * 8;               // 8 rows
    float acc[4][8];
    float4 bv = *(const float4*)&bias[co];
    #pragma unroll
    for (int j = 0; j < 8; ++j) { acc[0][j] = bv.x; acc[1][j] = bv.y; acc[2][j] = bv.z; acc[3][j] = bv.w; }
    for (int ci4 = 0; ci4 < 32; ++ci4) {
        int ci = ci4 * 4;
        float4 xv[8];
        #pragma unroll
        for (int j = 0; j < 8; ++j) xv[j] = *(const float4*)&xt[(r0 + j) * CC + ci];
        #pragma unroll
        for (int k = 0; k < 4; ++k) {
            float4 wv = *(const float4*)&wT[(size_t)(ci + k) * CC + co];
            #pragma unroll
            for (int j = 0; j < 8; ++j) {
                float xk = k == 0 ? xv[j].x : k == 1 ? xv[j].y : k == 2 ? xv[j].z : xv[j].w;
                acc[0][j] += wv.x * xk;
                acc[1][j] += wv.y * xk;
                acc[2][j] += wv.z * xk;
                acc[3][j] += wv.w * xk;
            }
        }
    }
    float S = 0.f, Q = 0.f;
    #pragma unroll
    for (int j = 0; j < 8; ++j) {
        float4 o = make_float4(acc[0][j], acc[1][j], acc[2][j], acc[3][j]);
        *(float4*)&ybuf[(size_t)(s0 + r0 + j) * CC + co] = o;
        S += o.x + o.y + o.z + o.w;
        Q += o.x * o.x + o.y * o.y + o.z * o.z + o.w * o.w;
    }
    redS[tid] = S; redQ[tid] = Q;
    __syncthreads();
    if (tid < 32) {
        float Sg = 0.f, Qg = 0.f;
        for (int h = 0; h < 8; ++h) { Sg += redS[h * 32 + tid]; Qg += redQ[h * 32 + tid]; }
        Sg += __shfl_xor(Sg, 1); Sg += __shfl_xor(Sg, 2);
        Qg += __shfl_xor(Qg, 1); Qg += __shfl_xor(Qg, 2);
        if ((tid & 3) == 0) {
            int g = tid >> 2;
            int s = blockIdx.x & 31;
            atomicAdd(&stats_out[s * 32 + (b * 8 + g) * 2],     Sg);
            atomicAdd(&stats_out[s * 32 + (b * 8 + g) * 2 + 1], Qg);
        }
    }
}

// ------------------------------------------------- out[b][n][c] = max_k lrelu(gn(y))
__global__ void maxpool_kernel(const float* __restrict__ ybuf, const float* __restrict__ stats,
                               const float* __restrict__ gam, const float* __restrict__ bet,
                               float* __restrict__ outf, float* __restrict__ outb) {
    int p = blockIdx.x;                    // b*N + n
    int b = p >> 12, n = p & 4095;
    int c = threadIdx.x;
    int g = c >> 4;
    float S = 0.f, Q = 0.f;
    for (int s = 0; s < 32; ++s) {
        S += stats[s * 32 + (b * 8 + g) * 2];
        Q += stats[s * 32 + (b * 8 + g) * 2 + 1];
    }
    float mu = S / CNT_PER_GROUP;
    float var = Q / CNT_PER_GROUP - mu * mu;
    float rs = rsqrtf(var + 1e-5f);
    float scale = gam[c] * rs;
    float shift = bet[c] - mu * scale;
    float mx = -INFINITY;
    for (int k = 0; k < KNN; ++k) {
        float v = ybuf[((size_t)p * KNN + k) * CC + c] * scale + shift;
        v = v >= 0.f ? v : 0.1f * v;
        mx = fmaxf(mx, v);
    }
    if (outf) outf[(size_t)p * CC + c] = mx;
    if (outb) outb[((size_t)b * CC + c) * NPTS + n] = mx;
}

// ------------------------------------------------- final 128x128 conv, wT coalesced
__global__ void conv128_kernel(const float* __restrict__ x, const float* __restrict__ wT,
                               const float* __restrict__ bias, float* __restrict__ outf,
                               float* __restrict__ outb) {
    int tx = threadIdx.x & 127, ty = threadIdx.x >> 7;
    int p = blockIdx.x * 2 + ty;
    int b = p >> 12, n = p & 4095;
    float acc = bias[tx];
    const float* xr = x + (size_t)p * CC;
    #pragma unroll 8
    for (int ci = 0; ci < CC; ++ci) acc += wT[(size_t)ci * CC + tx] * xr[ci];
    outf[(size_t)p * CC + tx] = acc;
    outb[((size_t)b * CC + tx) * NPTS + n] = acc;
}

extern "C" void kernel_launch(void* const* d_in, const int* in_sizes, int n_in,
                              void* d_out, int out_size, void* d_ws, size_t ws_size,
                              hipStream_t stream) {
    (void)in_sizes; (void)n_in; (void)out_size; (void)ws_size;
    const float* pc1    = (const float*)d_in[0];
    const float* pc2    = (const float*)d_in[1];
    const float* feat1  = (const float*)d_in[2];
    const float* feat2  = (const float*)d_in[3];
    const float* t11_w  = (const float*)d_in[4];
    const float* t11_b  = (const float*)d_in[5];
    const float* t22_w  = (const float*)d_in[6];
    const float* t22_b  = (const float*)d_in[7];
    const float* pos1_w = (const float*)d_in[8];
    const float* pos1_b = (const float*)d_in[9];
    const float* gn1_g  = (const float*)d_in[10];
    const float* gn1_b  = (const float*)d_in[11];
    const float* m1a_w  = (const float*)d_in[12];
    const float* m1a_b  = (const float*)d_in[13];
    const float* m1a_g  = (const float*)d_in[14];
    const float* m1a_be = (const float*)d_in[15];
    const float* m1b_w  = (const float*)d_in[16];
    const float* m1b_b  = (const float*)d_in[17];
    const float* m1b_g  = (const float*)d_in[18];
    const float* m1b_be = (const float*)d_in[19];
    const float* t1_w   = (const float*)d_in[20];
    const float* t1_b   = (const float*)d_in[21];
    const float* t2_w   = (const float*)d_in[22];
    const float* t2_b   = (const float*)d_in[23];
    const float* pos2_w = (const float*)d_in[24];
    const float* pos2_b = (const float*)d_in[25];
    const float* gn2_g  = (const float*)d_in[26];
    const float* gn2_b  = (const float*)d_in[27];
    const float* m2a_w  = (const float*)d_in[28];
    const float* m2a_b  = (const float*)d_in[29];
    const float* m2a_g  = (const float*)d_in[30];
    const float* m2a_be = (const float*)d_in[31];

    float* out = (float*)d_out;
    const size_t PN = 2 * NPTS;              // 8192 points
    const size_t PT = PN * CC;               // 1,048,576 f32 per point-tensor
    float* ws   = (float*)d_ws;
    float* f1   = ws;
    float* f2   = f1 + PT;
    float* g1   = f2 + PT;
    float* g2   = g1 + PT;
    float* f1n  = g2 + PT;
    float* f2n  = f1n + PT;
    float* cr   = f2n + PT;
    int*   idx12 = (int*)(cr + PT);
    int*   idx21 = idx12 + PN * KNN;
    float* stats = (float*)(idx21 + PN * KNN);     // 8 stages * 1024
    float* wTt11 = stats + 8 * STAT_STRIDE;        // [64][128]
    float* wTt22 = wTt11 + 64 * CC;
    float* wTt1  = wTt22 + 64 * CC;                // [128][128]
    float* wTt2  = wTt1 + CC * CC;
    float* wTm1a = wTt2 + CC * CC;
    float* wTm1b = wTm1a + CC * CC;
    float* wTm2a = wTm1b + CC * CC;
    float* bufX  = wTm2a + CC * CC;
    float* bufY  = bufX + (size_t)PN * KNN * CC;   // 16,777,216 f32 each

    zero_kernel<<<32, 256, 0, stream>>>(stats);
    transpose_kernel<<<32, 256, 0, stream>>>(t11_w, wTt11, CC, 64);
    transpose_kernel<<<32, 256, 0, stream>>>(t22_w, wTt22, CC, 64);
    transpose_kernel<<<64, 256, 0, stream>>>(t1_w,  wTt1,  CC, CC);
    transpose_kernel<<<64, 256, 0, stream>>>(t2_w,  wTt2,  CC, CC);
    transpose_kernel<<<64, 256, 0, stream>>>(m1a_w, wTm1a, CC, CC);
    transpose_kernel<<<64, 256, 0, stream>>>(m1b_w, wTm1b, CC, CC);
    transpose_kernel<<<64, 256, 0, stream>>>(m2a_w, wTm2a, CC, CC);

    conv64_kernel<<<PN / 2, 256, 0, stream>>>(feat1, wTt11, t11_b, f1);
    conv64_kernel<<<PN / 2, 256, 0, stream>>>(feat2, wTt22, t22_b, f2);
    conv64_kernel<<<PN / 2, 256, 0, stream>>>(feat2, wTt11, t11_b, g1);
    conv64_kernel<<<PN / 2, 256, 0, stream>>>(feat1, wTt22, t22_b, g2);
    knn_kernel<<<dim3(PN / 16, 2), 256, 0, stream>>>(pc1, pc2, idx12, idx21);

    float* st0 = stats;
    // ---- cross1: (pc1, pc2, f1, f2) -> t1 -> feat1_new
    h0_kernel<<<PN, 128, 0, stream>>>(f1, f2, pc1, pc2, idx12, pos1_w, pos1_b, bufX, st0 + 0 * STAT_STRIDE);
    convgn_kernel<<<2048, 256, 0, stream>>>(bufX, st0 + 0 * STAT_STRIDE, gn1_g, gn1_b, wTm1a, m1a_b, bufY, st0 + 1 * STAT_STRIDE);
    convgn_kernel<<<2048, 256, 0, stream>>>(bufY, st0 + 1 * STAT_STRIDE, m1a_g, m1a_be, wTm1b, m1b_b, bufX, st0 + 2 * STAT_STRIDE);
    maxpool_kernel<<<PN, 128, 0, stream>>>(bufX, st0 + 2 * STAT_STRIDE, m1b_g, m1b_be, cr, nullptr);
    conv128_kernel<<<PN / 2, 256, 0, stream>>>(cr, wTt1, t1_b, f1n, out);

    // ---- cross2: (pc2, pc1, g1, g2) -> t2 -> feat2_new
    h0_kernel<<<PN, 128, 0, stream>>>(g1, g2, pc2, pc1, idx21, pos1_w, pos1_b, bufX, st0 + 3 * STAT_STRIDE);
    convgn_kernel<<<2048, 256, 0, stream>>>(bufX, st0 + 3 * STAT_STRIDE, gn1_g, gn1_b, wTm1a, m1a_b, bufY, st0 + 4 * STAT_STRIDE);
    convgn_kernel<<<2048, 256, 0, stream>>>(bufY, st0 + 4 * STAT_STRIDE, m1a_g, m1a_be, wTm1b, m1b_b, bufX, st0 + 5 * STAT_STRIDE);
    maxpool_kernel<<<PN, 128, 0, stream>>>(bufX, st0 + 5 * STAT_STRIDE, m1b_g, m1b_be, cr, nullptr);
    conv128_kernel<<<PN / 2, 256, 0, stream>>>(cr, wTt2, t2_b, f2n, out + PT);

    // ---- cross3: (pc1, pc2, feat1_new, feat2_new) -> feat1_final
    h0_kernel<<<PN, 128, 0, stream>>>(f1n, f2n, pc1, pc2, idx12, pos2_w, pos2_b, bufX, st0 + 6 * STAT_STRIDE);
    convgn_kernel<<<2048, 256, 0, stream>>>(bufX, st0 + 6 * STAT_STRIDE, gn2_g, gn2_b, wTm2a, m2a_b, bufY, st0 + 7 * STAT_STRIDE);
    maxpool_kernel<<<PN, 128, 0, stream>>>(bufY, st0 + 7 * STAT_STRIDE, m2a_g, m2a_be, nullptr, out + 2 * PT);
}

// Round 7
// 777.284 us; speedup vs baseline: 2.8899x; 1.0276x over previous
//
#include <hip/hip_runtime.h>
#include <hip/hip_bf16.h>

#define NPTS 4096
#define CC   128
#define KNN  16
#define CNT_PER_GROUP 1048576.0f  // 16 ch * 4096 n * 16 k
#define STAT_STRIDE 1024          // 32 partial slots x [b(2) x g(8) x 2]

// ---------------------------------------------------------------- prep: 7 transposes + zero stats
__global__ void prep_kernel(const float* __restrict__ t11_w, const float* __restrict__ t22_w,
                            const float* __restrict__ t1_w,  const float* __restrict__ t2_w,
                            const float* __restrict__ m1a_w, const float* __restrict__ m1b_w,
                            const float* __restrict__ m2a_w,
                            float* __restrict__ wTt11, float* __restrict__ wTt22,
                            float* __restrict__ wTt1,  float* __restrict__ wTt2,
                            float* __restrict__ wTm1a, float* __restrict__ wTm1b,
                            float* __restrict__ wTm2a, float* __restrict__ stats) {
    int y = blockIdx.y;
    int idx = blockIdx.x * 256 + threadIdx.x;
    if (y == 7) {
        if (idx < 8 * STAT_STRIDE) stats[idx] = 0.0f;
        return;
    }
    const float* in; float* outp; int Cdim;
    switch (y) {
        case 0: in = t11_w; outp = wTt11; Cdim = 64; break;
        case 1: in = t22_w; outp = wTt22; Cdim = 64; break;
        case 2: in = t1_w;  outp = wTt1;  Cdim = CC; break;
        case 3: in = t2_w;  outp = wTt2;  Cdim = CC; break;
        case 4: in = m1a_w; outp = wTm1a; Cdim = CC; break;
        case 5: in = m1b_w; outp = wTm1b; Cdim = CC; break;
        default: in = m2a_w; outp = wTm2a; Cdim = CC; break;
    }
    if (idx < CC * Cdim) {
        int o = idx / Cdim, c = idx % Cdim;
        outp[c * CC + o] = in[idx];
    }
}

// ------------------------------------------------- all 4 conv1d 64->128 in one dispatch
__global__ void conv64_kernel(const float* __restrict__ feat1, const float* __restrict__ feat2,
                              const float* __restrict__ wTt11, const float* __restrict__ wTt22,
                              const float* __restrict__ b11, const float* __restrict__ b22,
                              float* __restrict__ f1, float* __restrict__ f2,
                              float* __restrict__ g1, float* __restrict__ g2) {
    int y = blockIdx.y;
    const float* x  = (y == 0 || y == 3) ? feat1 : feat2;
    const float* wT = (y == 0 || y == 2) ? wTt11 : wTt22;
    const float* bias = (y == 0 || y == 2) ? b11 : b22;
    float* outp = y == 0 ? f1 : y == 1 ? f2 : y == 2 ? g1 : g2;
    int tx = threadIdx.x & 127, ty = threadIdx.x >> 7;
    int p = blockIdx.x * 2 + ty;            // b*N + n
    int b = p >> 12, n = p & 4095;
    float acc = bias[tx];
    const float* xb = x + (size_t)b * 64 * NPTS + n;
    #pragma unroll 8
    for (int ci = 0; ci < 64; ++ci)
        acc += wT[(size_t)ci * CC + tx] * xb[(size_t)ci * NPTS];
    outp[(size_t)p * CC + tx] = acc;
}

// ---------------------------------------------------------------- 64-bit shuffles
static __device__ __forceinline__ unsigned long long sxor64(unsigned long long v, int m) {
    unsigned lo = (unsigned)__shfl_xor((int)(unsigned)v, m);
    unsigned hi = (unsigned)__shfl_xor((int)(v >> 32), m);
    return ((unsigned long long)hi << 32) | lo;
}
static __device__ __forceinline__ unsigned long long sup64(unsigned long long v, int d) {
    unsigned lo = (unsigned)__shfl_up((int)(unsigned)v, d);
    unsigned hi = (unsigned)__shfl_up((int)(v >> 32), d);
    return ((unsigned long long)hi << 32) | lo;
}

// ------------------------------------------------- KNN, wave-per-query, two-pass (low VGPR).
// Pass 1: per-lane min over its 64 candidates (no d2 storage). Pass 2: recompute d2
// (deterministic -> bit-identical) and ballot-compact <=T. Same selection as passing rounds.
__global__ __launch_bounds__(256) void knn_kernel(
        const float* __restrict__ pc1, const float* __restrict__ pc2,
        int* __restrict__ idx12, int* __restrict__ idx21) {
#pragma clang fp contract(off)
    __shared__ float cx[NPTS], cy[NPTS], cz[NPTS];        // 48 KB
    __shared__ unsigned long long lst[4][128];            // 4 KB
    int dir = blockIdx.y;
    const float* qs = dir ? pc2 : pc1;
    const float* cs = dir ? pc1 : pc2;
    int* outIdx = dir ? idx21 : idx12;
    int tid = threadIdx.x, lane = tid & 63, wv = tid >> 6;
    int qbase = blockIdx.x * 16;
    int b = qbase >> 12;
    const float* cb = cs + (size_t)b * 3 * NPTS;
    for (int i = tid; i < NPTS; i += 256) {
        cx[i] = cb[i]; cy[i] = cb[NPTS + i]; cz[i] = cb[2 * NPTS + i];
    }
    __syncthreads();
    const float* qb = qs + (size_t)b * 3 * NPTS;
    for (int r = 0; r < 4; ++r) {
        int q = qbase + wv * 4 + r;
        int n = q & 4095;
        float qx = qb[n], qy = qb[NPTS + n], qz = qb[2 * NPTS + n];
        float s1 = qx * qx + qy * qy + qz * qz;   // l2r, no fma
        // pass 1: per-lane min
        float dmin = 1e30f;
        #pragma unroll 16
        for (int j = 0; j < 64; ++j) {
            int m = j * 64 + lane;
            float x = cx[m], y = cy[m], z = cz[m];
            float s2 = x * x + y * y + z * z;
            float dt = __builtin_fmaf(z, qz, __builtin_fmaf(y, qy, x * qx));
            float d2 = (s1 + s2) - 2.0f * dt;
            dmin = fminf(dmin, d2);
        }
        // T = 16th smallest of 64 per-lane minima (>= global 16th smallest)
        float sv = dmin;
        for (int k = 2; k <= 64; k <<= 1)
            for (int j = k >> 1; j > 0; j >>= 1) {
                float o = __shfl_xor(sv, j);
                bool tmin = (((lane & k) == 0) == ((lane & j) == 0));
                sv = tmin ? fminf(sv, o) : fmaxf(sv, o);
            }
        float T = __shfl(sv, 15);
        // pass 2: recompute d2 (bit-identical), compact survivors
        int base = 0;
        #pragma unroll 8
        for (int j = 0; j < 64; ++j) {
            int m = j * 64 + lane;
            float x = cx[m], y = cy[m], z = cz[m];
            float s2 = x * x + y * y + z * z;
            float dt = __builtin_fmaf(z, qz, __builtin_fmaf(y, qy, x * qx));
            float d2 = (s1 + s2) - 2.0f * dt;
            bool p = (d2 <= T);
            unsigned long long mk = __ballot(p);
            if (p) {
                int pos = base + (int)__popcll(mk & ((1ULL << lane) - 1ULL));
                unsigned u = __float_as_uint(d2);
                u ^= (unsigned)(((int)u >> 31) | 0x80000000);
                unsigned long long key = ((unsigned long long)u << 32) | (unsigned)m;
                if (pos < 128) lst[wv][pos] = key;
            }
            base += (int)__popcll(mk);
        }
        int nT = base < 128 ? base : 128;
        unsigned long long key = (lane < nT) ? lst[wv][lane] : ~0ULL;
        for (int k = 2; k <= 64; k <<= 1)
            for (int j = k >> 1; j > 0; j >>= 1) {
                unsigned long long o = sxor64(key, j);
                bool tmin = (((lane & k) == 0) == ((lane & j) == 0));
                unsigned long long mn = key < o ? key : o;
                unsigned long long mx = key < o ? o : key;
                key = tmin ? mn : mx;
            }
        for (int e = 64; e < nT; ++e) {
            unsigned long long ev = lst[wv][e];
            int pcnt = (int)__popcll(__ballot(key < ev));
            unsigned long long sh = sup64(key, 1);
            key = (lane < pcnt) ? key : (lane == pcnt ? ev : sh);
        }
        if (lane < KNN) outIdx[(size_t)q * KNN + lane] = (int)(unsigned)(key & 0xFFFFFFFFULL);
    }
}

// ------------------------------------------------- h0 = group(p2) + p1 + pos_conv + fused stats
__global__ void h0_kernel(const float* __restrict__ p1f, const float* __restrict__ p2f,
                          const float* __restrict__ pcA, const float* __restrict__ pcB,
                          const int* __restrict__ idx,
                          const float* __restrict__ pos_w, const float* __restrict__ pos_b,
                          float* __restrict__ buf, float* __restrict__ stats_out) {
    __shared__ float redS[128], redQ[128];
    int p = blockIdx.x;                    // b*N + n
    int b = p >> 12, n = p & 4095;
    int c = threadIdx.x;
    float pw0 = pos_w[c * 3], pw1 = pos_w[c * 3 + 1], pw2 = pos_w[c * 3 + 2];
    float pb = pos_b[c];
    float p1v = p1f[(size_t)p * CC + c];
    const float* pa = pcA + (size_t)b * 3 * NPTS;
    const float* pc = pcB + (size_t)b * 3 * NPTS;
    float qx = pa[n], qy = pa[NPTS + n], qz = pa[2 * NPTS + n];
    float S = 0.f, Q = 0.f;
    for (int k = 0; k < KNN; ++k) {
        int m = idx[(size_t)p * KNN + k];
        float dx = pc[m] - qx;
        float dy = pc[NPTS + m] - qy;
        float dz = pc[2 * NPTS + m] - qz;
        float pos = pw0 * dx + pw1 * dy + pw2 * dz + pb;
        float v = p2f[((size_t)b * NPTS + m) * CC + c] + p1v + pos;
        buf[((size_t)p * KNN + k) * CC + c] = v;
        S += v; Q += v * v;
    }
    redS[c] = S; redQ[c] = Q;
    __syncthreads();
    if (c < 8) {
        float SS = 0.f, QQ = 0.f;
        for (int i = 0; i < 16; ++i) { SS += redS[c * 16 + i]; QQ += redQ[c * 16 + i]; }
        int s = blockIdx.x & 31;
        atomicAdd(&stats_out[s * 32 + (b * 8 + c) * 2],     SS);
        atomicAdd(&stats_out[s * 32 + (b * 8 + c) * 2 + 1], QQ);
    }
}

// ------------------------------------------------- y = W * lrelu(gn(x)) + bias, fused stats
__global__ __launch_bounds__(256) void convgn_kernel(
        const float* __restrict__ xbuf, const float* __restrict__ stats_in,
        const float* __restrict__ gam, const float* __restrict__ bet,
        const float* __restrict__ wT, const float* __restrict__ bias,
        float* __restrict__ ybuf, float* __restrict__ stats_out) {
    __shared__ float xt[64 * CC];          // 32 KB
    __shared__ float sc[CC], sh[CC];
    __shared__ float redS[256], redQ[256];
    int tid = threadIdx.x;
    int s0 = blockIdx.x * 64;              // 64 rows, never crosses b
    int b = s0 >> 16;
    if (tid < CC) {
        int g = tid >> 4;
        float S = 0.f, Q = 0.f;
        for (int s = 0; s < 32; ++s) {
            S += stats_in[s * 32 + (b * 8 + g) * 2];
            Q += stats_in[s * 32 + (b * 8 + g) * 2 + 1];
        }
        float mu = S / CNT_PER_GROUP;
        float var = Q / CNT_PER_GROUP - mu * mu;
        float rs = rsqrtf(var + 1e-5f);
        float scale = gam[tid] * rs;
        sc[tid] = scale;
        sh[tid] = bet[tid] - mu * scale;
    }
    __syncthreads();
    #pragma unroll
    for (int j = 0; j < 8; ++j) {
        int idx = tid + 256 * j;           // 2048 float4s
        int row = idx >> 5, c4 = (idx & 31) * 4;
        float4 v = *(const float4*)&xbuf[(size_t)(s0 + row) * CC + c4];
        v.x = v.x * sc[c4]     + sh[c4];     v.x = v.x >= 0.f ? v.x : 0.1f * v.x;
        v.y = v.y * sc[c4 + 1] + sh[c4 + 1]; v.y = v.y >= 0.f ? v.y : 0.1f * v.y;
        v.z = v.z * sc[c4 + 2] + sh[c4 + 2]; v.z = v.z >= 0.f ? v.z : 0.1f * v.z;
        v.w = v.w * sc[c4 + 3] + sh[c4 + 3]; v.w = v.w >= 0.f ? v.w : 0.1f * v.w;
        *(float4*)&xt[row * CC + c4] = v;
    }
    __syncthreads();
    int co = (tid & 31) * 4;               // 4 output channels (same GN group)
    int r0 = (tid >> 5) * 8;               // 8 rows
    float acc[4][8];
    float4 bv = *(const float4*)&bias[co];
    #pragma unroll
    for (int j = 0; j < 8; ++j) { acc[0][j] = bv.x; acc[1][j] = bv.y; acc[2][j] = bv.z; acc[3][j] = bv.w; }
    for (int ci4 = 0; ci4 < 32; ++ci4) {
        int ci = ci4 * 4;
        float4 xv[8];
        #pragma unroll
        for (int j = 0; j < 8; ++j) xv[j] = *(const float4*)&xt[(r0 + j) * CC + ci];
        #pragma unroll
        for (int k = 0; k < 4; ++k) {
            float4 wv = *(const float4*)&wT[(size_t)(ci + k) * CC + co];
            #pragma unroll
            for (int j = 0; j < 8; ++j) {
                float xk = k == 0 ? xv[j].x : k == 1 ? xv[j].y : k == 2 ? xv[j].z : xv[j].w;
                acc[0][j] += wv.x * xk;
                acc[1][j] += wv.y * xk;
                acc[2][j] += wv.z * xk;
                acc[3][j] += wv.w * xk;
            }
        }
    }
    float S = 0.f, Q = 0.f;
    #pragma unroll
    for (int j = 0; j < 8; ++j) {
        float4 o = make_float4(acc[0][j], acc[1][j], acc[2][j], acc[3][j]);
        *(float4*)&ybuf[(size_t)(s0 + r0 + j) * CC + co] = o;
        S += o.x + o.y + o.z + o.w;
        Q += o.x * o.x + o.y * o.y + o.z * o.z + o.w * o.w;
    }
    redS[tid] = S; redQ[tid] = Q;
    __syncthreads();
    if (tid < 32) {
        float Sg = 0.f, Qg = 0.f;
        for (int h = 0; h < 8; ++h) { Sg += redS[h * 32 + tid]; Qg += redQ[h * 32 + tid]; }
        Sg += __shfl_xor(Sg, 1); Sg += __shfl_xor(Sg, 2);
        Qg += __shfl_xor(Qg, 1); Qg += __shfl_xor(Qg, 2);
        if ((tid & 3) == 0) {
            int g = tid >> 2;
            int s = blockIdx.x & 31;
            atomicAdd(&stats_out[s * 32 + (b * 8 + g) * 2],     Sg);
            atomicAdd(&stats_out[s * 32 + (b * 8 + g) * 2 + 1], Qg);
        }
    }
}

// ------------------------------------------------- maxpool only (cross3 tail)
__global__ void maxpool_kernel(const float* __restrict__ ybuf, const float* __restrict__ stats,
                               const float* __restrict__ gam, const float* __restrict__ bet,
                               float* __restrict__ outb) {
    int p = blockIdx.x;                    // b*N + n
    int b = p >> 12, n = p & 4095;
    int c = threadIdx.x;
    int g = c >> 4;
    float S = 0.f, Q = 0.f;
    for (int s = 0; s < 32; ++s) {
        S += stats[s * 32 + (b * 8 + g) * 2];
        Q += stats[s * 32 + (b * 8 + g) * 2 + 1];
    }
    float mu = S / CNT_PER_GROUP;
    float var = Q / CNT_PER_GROUP - mu * mu;
    float rs = rsqrtf(var + 1e-5f);
    float scale = gam[c] * rs;
    float shift = bet[c] - mu * scale;
    float mx = -INFINITY;
    for (int k = 0; k < KNN; ++k) {
        float v = ybuf[((size_t)p * KNN + k) * CC + c] * scale + shift;
        v = v >= 0.f ? v : 0.1f * v;
        mx = fmaxf(mx, v);
    }
    outb[((size_t)b * CC + c) * NPTS + n] = mx;
}

// ------------------------------------------------- fused maxpool + 128x128 conv (cross1/2 tail)
__global__ void maxconv_kernel(const float* __restrict__ ybuf, const float* __restrict__ stats,
                               const float* __restrict__ gam, const float* __restrict__ bet,
                               const float* __restrict__ wT, const float* __restrict__ bias,
                               float* __restrict__ outf, float* __restrict__ outb) {
    __shared__ float mxs[CC];
    int p = blockIdx.x;                    // b*N + n
    int b = p >> 12, n = p & 4095;
    int c = threadIdx.x;
    int g = c >> 4;
    float S = 0.f, Q = 0.f;
    for (int s = 0; s < 32; ++s) {
        S += stats[s * 32 + (b * 8 + g) * 2];
        Q += stats[s * 32 + (b * 8 + g) * 2 + 1];
    }
    float mu = S / CNT_PER_GROUP;
    float var = Q / CNT_PER_GROUP - mu * mu;
    float rs = rsqrtf(var + 1e-5f);
    float scale = gam[c] * rs;
    float shift = bet[c] - mu * scale;
    float mx = -INFINITY;
    for (int k = 0; k < KNN; ++k) {
        float v = ybuf[((size_t)p * KNN + k) * CC + c] * scale + shift;
        v = v >= 0.f ? v : 0.1f * v;
        mx = fmaxf(mx, v);
    }
    mxs[c] = mx;
    __syncthreads();
    float acc = bias[c];
    #pragma unroll 8
    for (int ci = 0; ci < CC; ++ci)
        acc += wT[(size_t)ci * CC + c] * mxs[ci];
    outf[(size_t)p * CC + c] = acc;
    outb[((size_t)b * CC + c) * NPTS + n] = acc;
}

extern "C" void kernel_launch(void* const* d_in, const int* in_sizes, int n_in,
                              void* d_out, int out_size, void* d_ws, size_t ws_size,
                              hipStream_t stream) {
    (void)in_sizes; (void)n_in; (void)out_size; (void)ws_size;
    const float* pc1    = (const float*)d_in[0];
    const float* pc2    = (const float*)d_in[1];
    const float* feat1  = (const float*)d_in[2];
    const float* feat2  = (const float*)d_in[3];
    const float* t11_w  = (const float*)d_in[4];
    const float* t11_b  = (const float*)d_in[5];
    const float* t22_w  = (const float*)d_in[6];
    const float* t22_b  = (const float*)d_in[7];
    const float* pos1_w = (const float*)d_in[8];
    const float* pos1_b = (const float*)d_in[9];
    const float* gn1_g  = (const float*)d_in[10];
    const float* gn1_b  = (const float*)d_in[11];
    const float* m1a_w  = (const float*)d_in[12];
    const float* m1a_b  = (const float*)d_in[13];
    const float* m1a_g  = (const float*)d_in[14];
    const float* m1a_be = (const float*)d_in[15];
    const float* m1b_w  = (const float*)d_in[16];
    const float* m1b_b  = (const float*)d_in[17];
    const float* m1b_g  = (const float*)d_in[18];
    const float* m1b_be = (const float*)d_in[19];
    const float* t1_w   = (const float*)d_in[20];
    const float* t1_b   = (const float*)d_in[21];
    const float* t2_w   = (const float*)d_in[22];
    const float* t2_b   = (const float*)d_in[23];
    const float* pos2_w = (const float*)d_in[24];
    const float* pos2_b = (const float*)d_in[25];
    const float* gn2_g  = (const float*)d_in[26];
    const float* gn2_b  = (const float*)d_in[27];
    const float* m2a_w  = (const float*)d_in[28];
    const float* m2a_b  = (const float*)d_in[29];
    const float* m2a_g  = (const float*)d_in[30];
    const float* m2a_be = (const float*)d_in[31];

    float* out = (float*)d_out;
    const size_t PN = 2 * NPTS;              // 8192 points
    const size_t PT = PN * CC;               // 1,048,576 f32 per point-tensor
    float* ws   = (float*)d_ws;
    float* f1   = ws;
    float* f2   = f1 + PT;
    float* g1   = f2 + PT;
    float* g2   = g1 + PT;
    float* f1n  = g2 + PT;
    float* f2n  = f1n + PT;
    int*   idx12 = (int*)(f2n + PT);
    int*   idx21 = idx12 + PN * KNN;
    float* stats = (float*)(idx21 + PN * KNN);     // 8 stages * 1024
    float* wTt11 = stats + 8 * STAT_STRIDE;        // [64][128]
    float* wTt22 = wTt11 + 64 * CC;
    float* wTt1  = wTt22 + 64 * CC;                // [128][128]
    float* wTt2  = wTt1 + CC * CC;
    float* wTm1a = wTt2 + CC * CC;
    float* wTm1b = wTm1a + CC * CC;
    float* wTm2a = wTm1b + CC * CC;
    float* bufX  = wTm2a + CC * CC;
    float* bufY  = bufX + (size_t)PN * KNN * CC;   // 16,777,216 f32 each

    prep_kernel<<<dim3(64, 8), 256, 0, stream>>>(
        t11_w, t22_w, t1_w, t2_w, m1a_w, m1b_w, m2a_w,
        wTt11, wTt22, wTt1, wTt2, wTm1a, wTm1b, wTm2a, stats);

    conv64_kernel<<<dim3(PN / 2, 4), 256, 0, stream>>>(
        feat1, feat2, wTt11, wTt22, t11_b, t22_b, f1, f2, g1, g2);
    knn_kernel<<<dim3(PN / 16, 2), 256, 0, stream>>>(pc1, pc2, idx12, idx21);

    float* st0 = stats;
    // ---- cross1: (pc1, pc2, f1, f2) -> t1 -> feat1_new
    h0_kernel<<<PN, 128, 0, stream>>>(f1, f2, pc1, pc2, idx12, pos1_w, pos1_b, bufX, st0 + 0 * STAT_STRIDE);
    convgn_kernel<<<2048, 256, 0, stream>>>(bufX, st0 + 0 * STAT_STRIDE, gn1_g, gn1_b, wTm1a, m1a_b, bufY, st0 + 1 * STAT_STRIDE);
    convgn_kernel<<<2048, 256, 0, stream>>>(bufY, st0 + 1 * STAT_STRIDE, m1a_g, m1a_be, wTm1b, m1b_b, bufX, st0 + 2 * STAT_STRIDE);
    maxconv_kernel<<<PN, 128, 0, stream>>>(bufX, st0 + 2 * STAT_STRIDE, m1b_g, m1b_be, wTt1, t1_b, f1n, out);

    // ---- cross2: (pc2, pc1, g1, g2) -> t2 -> feat2_new
    h0_kernel<<<PN, 128, 0, stream>>>(g1, g2, pc2, pc1, idx21, pos1_w, pos1_b, bufX, st0 + 3 * STAT_STRIDE);
    convgn_kernel<<<2048, 256, 0, stream>>>(bufX, st0 + 3 * STAT_STRIDE, gn1_g, gn1_b, wTm1a, m1a_b, bufY, st0 + 4 * STAT_STRIDE);
    convgn_kernel<<<2048, 256, 0, stream>>>(bufY, st0 + 4 * STAT_STRIDE, m1a_g, m1a_be, wTm1b, m1b_b, bufX, st0 + 5 * STAT_STRIDE);
    maxconv_kernel<<<PN, 128, 0, stream>>>(bufX, st0 + 5 * STAT_STRIDE, m1b_g, m1b_be, wTt2, t2_b, f2n, out + PT);

    // ---- cross3: (pc1, pc2, feat1_new, feat2_new) -> feat1_final
    h0_kernel<<<PN, 128, 0, stream>>>(f1n, f2n, pc1, pc2, idx12, pos2_w, pos2_b, bufX, st0 + 6 * STAT_STRIDE);
    convgn_kernel<<<2048, 256, 0, stream>>>(bufX, st0 + 6 * STAT_STRIDE, gn2_g, gn2_b, wTm2a, m2a_b, bufY, st0 + 7 * STAT_STRIDE);
    maxpool_kernel<<<PN, 128, 0, stream>>>(bufY, st0 + 7 * STAT_STRIDE, m2a_g, m2a_be, out + 2 * PT);
}

// Round 8
// 603.951 us; speedup vs baseline: 3.7193x; 1.2870x over previous
//
#include <hip/hip_runtime.h>
#include <hip/hip_bf16.h>

#define NPTS 4096
#define CC   128
#define KNN  16
#define CNT_PER_GROUP 1048576.0f  // 16 ch * 4096 n * 16 k
#define STAT_STRIDE 1024          // 32 partial slots x [b(2) x g(8) x 2]

typedef __attribute__((ext_vector_type(8))) short bf16x8;
typedef __attribute__((ext_vector_type(4))) float f32x4;
typedef unsigned short ushort_t;

static __device__ __forceinline__ ushort_t f2bf(float f) {
    __hip_bfloat16 h = __float2bfloat16(f);   // RNE
    ushort_t u; __builtin_memcpy(&u, &h, 2);
    return u;
}

// ---------------------------------------------------------------- prep:
// y 0-3: f32 transposes (conv64 + maxconv weights); y 4-6: bf16 MFMA-B-fragment
// swizzle of the three convgn weights; y 7: zero stats.
__global__ void prep_kernel(const float* __restrict__ t11_w, const float* __restrict__ t22_w,
                            const float* __restrict__ t1_w,  const float* __restrict__ t2_w,
                            const float* __restrict__ m1a_w, const float* __restrict__ m1b_w,
                            const float* __restrict__ m2a_w,
                            float* __restrict__ wTt11, float* __restrict__ wTt22,
                            float* __restrict__ wTt1,  float* __restrict__ wTt2,
                            ushort_t* __restrict__ W2m1a, ushort_t* __restrict__ W2m1b,
                            ushort_t* __restrict__ W2m2a, float* __restrict__ stats) {
    int y = blockIdx.y;
    int idx = blockIdx.x * 256 + threadIdx.x;
    if (y == 7) {
        if (idx < 8 * STAT_STRIDE) stats[idx] = 0.0f;
        return;
    }
    if (y < 4) {
        const float* in; float* outp; int Cdim;
        switch (y) {
            case 0: in = t11_w; outp = wTt11; Cdim = 64; break;
            case 1: in = t22_w; outp = wTt22; Cdim = 64; break;
            case 2: in = t1_w;  outp = wTt1;  Cdim = CC; break;
            default: in = t2_w; outp = wTt2;  Cdim = CC; break;
        }
        if (idx < CC * Cdim) {
            int o = idx / Cdim, c = idx % Cdim;
            outp[c * CC + o] = in[idx];
        }
        return;
    }
    // B-fragment swizzle: idx = kb*4096 + coT*512 + lane*8 + j
    const float* in = y == 4 ? m1a_w : y == 5 ? m1b_w : m2a_w;
    ushort_t* outp  = y == 4 ? W2m1a : y == 5 ? W2m1b : W2m2a;
    if (idx < 16384) {
        int j = idx & 7, lane = (idx >> 3) & 63, coT = (idx >> 9) & 7, kb = idx >> 12;
        int k  = kb * 32 + (lane >> 4) * 8 + j;
        int co = coT * 16 + (lane & 15);
        outp[idx] = f2bf(in[co * CC + k]);
    }
}

// ------------------------------------------------- all 4 conv1d 64->128 in one dispatch
__global__ void conv64_kernel(const float* __restrict__ feat1, const float* __restrict__ feat2,
                              const float* __restrict__ wTt11, const float* __restrict__ wTt22,
                              const float* __restrict__ b11, const float* __restrict__ b22,
                              float* __restrict__ f1, float* __restrict__ f2,
                              float* __restrict__ g1, float* __restrict__ g2) {
    int y = blockIdx.y;
    const float* x  = (y == 0 || y == 3) ? feat1 : feat2;
    const float* wT = (y == 0 || y == 2) ? wTt11 : wTt22;
    const float* bias = (y == 0 || y == 2) ? b11 : b22;
    float* outp = y == 0 ? f1 : y == 1 ? f2 : y == 2 ? g1 : g2;
    int tx = threadIdx.x & 127, ty = threadIdx.x >> 7;
    int p = blockIdx.x * 2 + ty;            // b*N + n
    int b = p >> 12, n = p & 4095;
    float acc = bias[tx];
    const float* xb = x + (size_t)b * 64 * NPTS + n;
    #pragma unroll 8
    for (int ci = 0; ci < 64; ++ci)
        acc += wT[(size_t)ci * CC + tx] * xb[(size_t)ci * NPTS];
    outp[(size_t)p * CC + tx] = acc;
}

// ---------------------------------------------------------------- 64-bit shuffles
static __device__ __forceinline__ unsigned long long sxor64(unsigned long long v, int m) {
    unsigned lo = (unsigned)__shfl_xor((int)(unsigned)v, m);
    unsigned hi = (unsigned)__shfl_xor((int)(v >> 32), m);
    return ((unsigned long long)hi << 32) | lo;
}
static __device__ __forceinline__ unsigned long long sup64(unsigned long long v, int d) {
    unsigned lo = (unsigned)__shfl_up((int)(unsigned)v, d);
    unsigned hi = (unsigned)__shfl_up((int)(v >> 32), d);
    return ((unsigned long long)hi << 32) | lo;
}

// ------------------------------------------------- KNN, wave-per-query.
// Candidates packed float4(x,y,z,s2) in LDS: one b128/candidate, s2 computed once
// per block (expression order identical to passing rounds -> d2 bits identical).
__global__ __launch_bounds__(512) void knn_kernel(
        const float* __restrict__ pc1, const float* __restrict__ pc2,
        int* __restrict__ idx12, int* __restrict__ idx21) {
#pragma clang fp contract(off)
    __shared__ float4 pk[NPTS];                           // 64 KB
    __shared__ unsigned long long lst[8][128];            // 8 KB
    int dir = blockIdx.y;
    const float* qs = dir ? pc2 : pc1;
    const float* cs = dir ? pc1 : pc2;
    int* outIdx = dir ? idx21 : idx12;
    int tid = threadIdx.x, lane = tid & 63, wv = tid >> 6;
    int qbase = blockIdx.x * 32;           // 32 queries per block, same b
    int b = qbase >> 12;
    const float* cb = cs + (size_t)b * 3 * NPTS;
    for (int i = tid; i < NPTS; i += 512) {
        float x = cb[i], y = cb[NPTS + i], z = cb[2 * NPTS + i];
        pk[i] = make_float4(x, y, z, x * x + y * y + z * z);  // l2r, no fma
    }
    __syncthreads();
    const float* qb = qs + (size_t)b * 3 * NPTS;
    for (int r = 0; r < 4; ++r) {
        int q = qbase + wv * 4 + r;
        int n = q & 4095;
        float qx = qb[n], qy = qb[NPTS + n], qz = qb[2 * NPTS + n];
        float s1 = qx * qx + qy * qy + qz * qz;   // l2r, no fma
        // pass 1: per-lane min over its 64 candidates
        float dmin = 1e30f;
        for (int j = 0; j < 16; ++j) {
            int m4 = j * 256 + lane * 4;
            #pragma unroll
            for (int c = 0; c < 4; ++c) {
                float4 P = pk[m4 + c];
                float dt = __builtin_fmaf(P.z, qz, __builtin_fmaf(P.y, qy, P.x * qx));
                float d2 = (s1 + P.w) - 2.0f * dt;
                dmin = fminf(dmin, d2);
            }
        }
        // T = 16th smallest of 64 per-lane minima (valid bound on global 16th)
        float sv = dmin;
        for (int k = 2; k <= 64; k <<= 1)
            for (int j = k >> 1; j > 0; j >>= 1) {
                float o = __shfl_xor(sv, j);
                bool tmin = (((lane & k) == 0) == ((lane & j) == 0));
                sv = tmin ? fminf(sv, o) : fmaxf(sv, o);
            }
        float T = __shfl(sv, 15);
        // pass 2: recompute d2 (bit-identical), ballot-compact survivors
        int base = 0;
        for (int j = 0; j < 16; ++j) {
            int m4 = j * 256 + lane * 4;
            #pragma unroll
            for (int c = 0; c < 4; ++c) {
                float4 P = pk[m4 + c];
                float dt = __builtin_fmaf(P.z, qz, __builtin_fmaf(P.y, qy, P.x * qx));
                float d2 = (s1 + P.w) - 2.0f * dt;
                bool p = (d2 <= T);
                unsigned long long mk = __ballot(p);
                if (p) {
                    int pos = base + (int)__popcll(mk & ((1ULL << lane) - 1ULL));
                    unsigned u = __float_as_uint(d2);
                    u ^= (unsigned)(((int)u >> 31) | 0x80000000);
                    unsigned long long key = ((unsigned long long)u << 32) | (unsigned)(m4 + c);
                    if (pos < 128) lst[wv][pos] = key;
                }
                base += (int)__popcll(mk);
            }
        }
        int nT = base < 128 ? base : 128;
        unsigned long long key = (lane < nT) ? lst[wv][lane] : ~0ULL;
        for (int k = 2; k <= 64; k <<= 1)
            for (int j = k >> 1; j > 0; j >>= 1) {
                unsigned long long o = sxor64(key, j);
                bool tmin = (((lane & k) == 0) == ((lane & j) == 0));
                unsigned long long mn = key < o ? key : o;
                unsigned long long mx = key < o ? o : key;
                key = tmin ? mn : mx;
            }
        for (int e = 64; e < nT; ++e) {
            unsigned long long ev = lst[wv][e];
            int pcnt = (int)__popcll(__ballot(key < ev));
            unsigned long long sh = sup64(key, 1);
            key = (lane < pcnt) ? key : (lane == pcnt ? ev : sh);
        }
        if (lane < KNN) outIdx[(size_t)q * KNN + lane] = (int)(unsigned)(key & 0xFFFFFFFFULL);
    }
}

// ------------------------------------------------- h0 = group(p2) + p1 + pos_conv + fused stats
__global__ void h0_kernel(const float* __restrict__ p1f, const float* __restrict__ p2f,
                          const float* __restrict__ pcA, const float* __restrict__ pcB,
                          const int* __restrict__ idx,
                          const float* __restrict__ pos_w, const float* __restrict__ pos_b,
                          float* __restrict__ buf, float* __restrict__ stats_out) {
    __shared__ float redS[128], redQ[128];
    int p = blockIdx.x;                    // b*N + n
    int b = p >> 12, n = p & 4095;
    int c = threadIdx.x;
    float pw0 = pos_w[c * 3], pw1 = pos_w[c * 3 + 1], pw2 = pos_w[c * 3 + 2];
    float pb = pos_b[c];
    float p1v = p1f[(size_t)p * CC + c];
    const float* pa = pcA + (size_t)b * 3 * NPTS;
    const float* pc = pcB + (size_t)b * 3 * NPTS;
    float qx = pa[n], qy = pa[NPTS + n], qz = pa[2 * NPTS + n];
    float S = 0.f, Q = 0.f;
    for (int k = 0; k < KNN; ++k) {
        int m = idx[(size_t)p * KNN + k];
        float dx = pc[m] - qx;
        float dy = pc[NPTS + m] - qy;
        float dz = pc[2 * NPTS + m] - qz;
        float pos = pw0 * dx + pw1 * dy + pw2 * dz + pb;
        float v = p2f[((size_t)b * NPTS + m) * CC + c] + p1v + pos;
        buf[((size_t)p * KNN + k) * CC + c] = v;
        S += v; Q += v * v;
    }
    redS[c] = S; redQ[c] = Q;
    __syncthreads();
    if (c < 8) {
        float SS = 0.f, QQ = 0.f;
        for (int i = 0; i < 16; ++i) { SS += redS[c * 16 + i]; QQ += redQ[c * 16 + i]; }
        int s = blockIdx.x & 31;
        atomicAdd(&stats_out[s * 32 + (b * 8 + c) * 2],     SS);
        atomicAdd(&stats_out[s * 32 + (b * 8 + c) * 2 + 1], QQ);
    }
}

// ------------------------------------------------- y = W * lrelu(gn(x)) + bias via bf16 MFMA
// block: 64 rows x 128 co, 4 waves; wave: 16 rows, 8 co-tiles, K-loop 4x32.
__global__ __launch_bounds__(256) void convgn_kernel(
        const float* __restrict__ xbuf, const float* __restrict__ stats_in,
        const float* __restrict__ gam, const float* __restrict__ bet,
        const ushort_t* __restrict__ W2, const float* __restrict__ bias,
        float* __restrict__ ybuf, float* __restrict__ stats_out) {
    __shared__ ushort_t xt[64 * 136];      // bf16, row stride 136 els (272B): 2-way alias only
    __shared__ float sc[CC], sh[CC];
    __shared__ float redS[4][8], redQ[4][8];
    int tid = threadIdx.x;
    int s0 = blockIdx.x * 64;              // 64 rows, never crosses b
    int b = s0 >> 16;
    if (tid < CC) {
        int g = tid >> 4;
        float S = 0.f, Q = 0.f;
        for (int s = 0; s < 32; ++s) {
            S += stats_in[s * 32 + (b * 8 + g) * 2];
            Q += stats_in[s * 32 + (b * 8 + g) * 2 + 1];
        }
        float mu = S / CNT_PER_GROUP;
        float var = Q / CNT_PER_GROUP - mu * mu;
        float rs = rsqrtf(var + 1e-5f);
        float scale = gam[tid] * rs;
        sc[tid] = scale;
        sh[tid] = bet[tid] - mu * scale;
    }
    __syncthreads();
    // stage GN+lrelu x into LDS as bf16
    #pragma unroll
    for (int j = 0; j < 8; ++j) {
        int idx = tid + 256 * j;           // 2048 float4 chunks
        int row = idx >> 5, c4 = (idx & 31) * 4;
        float4 v = *(const float4*)&xbuf[(size_t)(s0 + row) * CC + c4];
        v.x = v.x * sc[c4]     + sh[c4];     v.x = v.x >= 0.f ? v.x : 0.1f * v.x;
        v.y = v.y * sc[c4 + 1] + sh[c4 + 1]; v.y = v.y >= 0.f ? v.y : 0.1f * v.y;
        v.z = v.z * sc[c4 + 2] + sh[c4 + 2]; v.z = v.z >= 0.f ? v.z : 0.1f * v.z;
        v.w = v.w * sc[c4 + 3] + sh[c4 + 3]; v.w = v.w >= 0.f ? v.w : 0.1f * v.w;
        ushort4 o = make_ushort4(f2bf(v.x), f2bf(v.y), f2bf(v.z), f2bf(v.w));
        *(ushort4*)&xt[row * 136 + c4] = o;
    }
    __syncthreads();
    int lane = tid & 63, wv = tid >> 6;
    int r0 = wv * 16;
    int quad = lane >> 4;
    f32x4 acc[8];
    #pragma unroll
    for (int t = 0; t < 8; ++t) acc[t] = (f32x4){0.f, 0.f, 0.f, 0.f};
    int aoff = (r0 + (lane & 15)) * 136 + quad * 8;
    #pragma unroll
    for (int kb = 0; kb < 4; ++kb) {
        bf16x8 a = *(const bf16x8*)&xt[aoff + kb * 32];
        const ushort_t* wb = W2 + (size_t)kb * 4096 + lane * 8;
        #pragma unroll
        for (int t = 0; t < 8; ++t) {
            bf16x8 bf = *(const bf16x8*)&wb[t * 512];
            acc[t] = __builtin_amdgcn_mfma_f32_16x16x32_bf16(a, bf, acc[t], 0, 0, 0);
        }
    }
    // epilogue: bias, store f32, fused stats (group g == co-tile t)
    #pragma unroll
    for (int t = 0; t < 8; ++t) {
        int co = t * 16 + (lane & 15);
        float bv = bias[co];
        float S = 0.f, Q = 0.f;
        #pragma unroll
        for (int reg = 0; reg < 4; ++reg) {
            int row = s0 + r0 + quad * 4 + reg;
            float y = acc[t][reg] + bv;
            ybuf[(size_t)row * CC + co] = y;
            S += y; Q += y * y;
        }
        #pragma unroll
        for (int off = 1; off < 64; off <<= 1) {
            S += __shfl_xor(S, off);
            Q += __shfl_xor(Q, off);
        }
        if (lane == 0) { redS[wv][t] = S; redQ[wv][t] = Q; }
    }
    __syncthreads();
    if (tid < 8) {
        float S = redS[0][tid] + redS[1][tid] + redS[2][tid] + redS[3][tid];
        float Q = redQ[0][tid] + redQ[1][tid] + redQ[2][tid] + redQ[3][tid];
        int s = blockIdx.x & 31;
        atomicAdd(&stats_out[s * 32 + (b * 8 + tid) * 2],     S);
        atomicAdd(&stats_out[s * 32 + (b * 8 + tid) * 2 + 1], Q);
    }
}

// ------------------------------------------------- maxpool only (cross3 tail)
__global__ void maxpool_kernel(const float* __restrict__ ybuf, const float* __restrict__ stats,
                               const float* __restrict__ gam, const float* __restrict__ bet,
                               float* __restrict__ outb) {
    int p = blockIdx.x;                    // b*N + n
    int b = p >> 12, n = p & 4095;
    int c = threadIdx.x;
    int g = c >> 4;
    float S = 0.f, Q = 0.f;
    for (int s = 0; s < 32; ++s) {
        S += stats[s * 32 + (b * 8 + g) * 2];
        Q += stats[s * 32 + (b * 8 + g) * 2 + 1];
    }
    float mu = S / CNT_PER_GROUP;
    float var = Q / CNT_PER_GROUP - mu * mu;
    float rs = rsqrtf(var + 1e-5f);
    float scale = gam[c] * rs;
    float shift = bet[c] - mu * scale;
    float mx = -INFINITY;
    for (int k = 0; k < KNN; ++k) {
        float v = ybuf[((size_t)p * KNN + k) * CC + c] * scale + shift;
        v = v >= 0.f ? v : 0.1f * v;
        mx = fmaxf(mx, v);
    }
    outb[((size_t)b * CC + c) * NPTS + n] = mx;
}

// ------------------------------------------------- fused maxpool + 128x128 conv (cross1/2 tail)
__global__ void maxconv_kernel(const float* __restrict__ ybuf, const float* __restrict__ stats,
                               const float* __restrict__ gam, const float* __restrict__ bet,
                               const float* __restrict__ wT, const float* __restrict__ bias,
                               float* __restrict__ outf, float* __restrict__ outb) {
    __shared__ float mxs[CC];
    int p = blockIdx.x;                    // b*N + n
    int b = p >> 12, n = p & 4095;
    int c = threadIdx.x;
    int g = c >> 4;
    float S = 0.f, Q = 0.f;
    for (int s = 0; s < 32; ++s) {
        S += stats[s * 32 + (b * 8 + g) * 2];
        Q += stats[s * 32 + (b * 8 + g) * 2 + 1];
    }
    float mu = S / CNT_PER_GROUP;
    float var = Q / CNT_PER_GROUP - mu * mu;
    float rs = rsqrtf(var + 1e-5f);
    float scale = gam[c] * rs;
    float shift = bet[c] - mu * scale;
    float mx = -INFINITY;
    for (int k = 0; k < KNN; ++k) {
        float v = ybuf[((size_t)p * KNN + k) * CC + c] * scale + shift;
        v = v >= 0.f ? v : 0.1f * v;
        mx = fmaxf(mx, v);
    }
    mxs[c] = mx;
    __syncthreads();
    float acc = bias[c];
    #pragma unroll 8
    for (int ci = 0; ci < CC; ++ci)
        acc += wT[(size_t)ci * CC + c] * mxs[ci];
    outf[(size_t)p * CC + c] = acc;
    outb[((size_t)b * CC + c) * NPTS + n] = acc;
}

extern "C" void kernel_launch(void* const* d_in, const int* in_sizes, int n_in,
                              void* d_out, int out_size, void* d_ws, size_t ws_size,
                              hipStream_t stream) {
    (void)in_sizes; (void)n_in; (void)out_size; (void)ws_size;
    const float* pc1    = (const float*)d_in[0];
    const float* pc2    = (const float*)d_in[1];
    const float* feat1  = (const float*)d_in[2];
    const float* feat2  = (const float*)d_in[3];
    const float* t11_w  = (const float*)d_in[4];
    const float* t11_b  = (const float*)d_in[5];
    const float* t22_w  = (const float*)d_in[6];
    const float* t22_b  = (const float*)d_in[7];
    const float* pos1_w = (const float*)d_in[8];
    const float* pos1_b = (const float*)d_in[9];
    const float* gn1_g  = (const float*)d_in[10];
    const float* gn1_b  = (const float*)d_in[11];
    const float* m1a_w  = (const float*)d_in[12];
    const float* m1a_b  = (const float*)d_in[13];
    const float* m1a_g  = (const float*)d_in[14];
    const float* m1a_be = (const float*)d_in[15];
    const float* m1b_w  = (const float*)d_in[16];
    const float* m1b_b  = (const float*)d_in[17];
    const float* m1b_g  = (const float*)d_in[18];
    const float* m1b_be = (const float*)d_in[19];
    const float* t1_w   = (const float*)d_in[20];
    const float* t1_b   = (const float*)d_in[21];
    const float* t2_w   = (const float*)d_in[22];
    const float* t2_b   = (const float*)d_in[23];
    const float* pos2_w = (const float*)d_in[24];
    const float* pos2_b = (const float*)d_in[25];
    const float* gn2_g  = (const float*)d_in[26];
    const float* gn2_b  = (const float*)d_in[27];
    const float* m2a_w  = (const float*)d_in[28];
    const float* m2a_b  = (const float*)d_in[29];
    const float* m2a_g  = (const float*)d_in[30];
    const float* m2a_be = (const float*)d_in[31];

    float* out = (float*)d_out;
    const size_t PN = 2 * NPTS;              // 8192 points
    const size_t PT = PN * CC;               // 1,048,576 f32 per point-tensor
    float* ws   = (float*)d_ws;
    float* f1   = ws;
    float* f2   = f1 + PT;
    float* g1   = f2 + PT;
    float* g2   = g1 + PT;
    float* f1n  = g2 + PT;
    float* f2n  = f1n + PT;
    int*   idx12 = (int*)(f2n + PT);
    int*   idx21 = idx12 + PN * KNN;
    float* stats = (float*)(idx21 + PN * KNN);     // 8 stages * 1024
    float* wTt11 = stats + 8 * STAT_STRIDE;        // f32 [64][128]
    float* wTt22 = wTt11 + 64 * CC;
    float* wTt1  = wTt22 + 64 * CC;                // f32 [128][128]
    float* wTt2  = wTt1 + CC * CC;
    ushort_t* W2m1a = (ushort_t*)(wTt2 + CC * CC); // bf16 swizzled [16384]
    ushort_t* W2m1b = W2m1a + 16384;
    ushort_t* W2m2a = W2m1b + 16384;
    float* bufX  = (float*)(W2m2a + 16384);
    float* bufY  = bufX + (size_t)PN * KNN * CC;   // 16,777,216 f32 each

    prep_kernel<<<dim3(64, 8), 256, 0, stream>>>(
        t11_w, t22_w, t1_w, t2_w, m1a_w, m1b_w, m2a_w,
        wTt11, wTt22, wTt1, wTt2, W2m1a, W2m1b, W2m2a, stats);

    conv64_kernel<<<dim3(PN / 2, 4), 256, 0, stream>>>(
        feat1, feat2, wTt11, wTt22, t11_b, t22_b, f1, f2, g1, g2);
    knn_kernel<<<dim3(PN / 32, 2), 512, 0, stream>>>(pc1, pc2, idx12, idx21);

    float* st0 = stats;
    // ---- cross1: (pc1, pc2, f1, f2) -> t1 -> feat1_new
    h0_kernel<<<PN, 128, 0, stream>>>(f1, f2, pc1, pc2, idx12, pos1_w, pos1_b, bufX, st0 + 0 * STAT_STRIDE);
    convgn_kernel<<<2048, 256, 0, stream>>>(bufX, st0 + 0 * STAT_STRIDE, gn1_g, gn1_b, W2m1a, m1a_b, bufY, st0 + 1 * STAT_STRIDE);
    convgn_kernel<<<2048, 256, 0, stream>>>(bufY, st0 + 1 * STAT_STRIDE, m1a_g, m1a_be, W2m1b, m1b_b, bufX, st0 + 2 * STAT_STRIDE);
    maxconv_kernel<<<PN, 128, 0, stream>>>(bufX, st0 + 2 * STAT_STRIDE, m1b_g, m1b_be, wTt1, t1_b, f1n, out);

    // ---- cross2: (pc2, pc1, g1, g2) -> t2 -> feat2_new
    h0_kernel<<<PN, 128, 0, stream>>>(g1, g2, pc2, pc1, idx21, pos1_w, pos1_b, bufX, st0 + 3 * STAT_STRIDE);
    convgn_kernel<<<2048, 256, 0, stream>>>(bufX, st0 + 3 * STAT_STRIDE, gn1_g, gn1_b, W2m1a, m1a_b, bufY, st0 + 4 * STAT_STRIDE);
    convgn_kernel<<<2048, 256, 0, stream>>>(bufY, st0 + 4 * STAT_STRIDE, m1a_g, m1a_be, W2m1b, m1b_b, bufX, st0 + 5 * STAT_STRIDE);
    maxconv_kernel<<<PN, 128, 0, stream>>>(bufX, st0 + 5 * STAT_STRIDE, m1b_g, m1b_be, wTt2, t2_b, f2n, out + PT);

    // ---- cross3: (pc1, pc2, feat1_new, feat2_new) -> feat1_final
    h0_kernel<<<PN, 128, 0, stream>>>(f1n, f2n, pc1, pc2, idx12, pos2_w, pos2_b, bufX, st0 + 6 * STAT_STRIDE);
    convgn_kernel<<<2048, 256, 0, stream>>>(bufX, st0 + 6 * STAT_STRIDE, gn2_g, gn2_b, W2m2a, m2a_b, bufY, st0 + 7 * STAT_STRIDE);
    maxpool_kernel<<<PN, 128, 0, stream>>>(bufY, st0 + 7 * STAT_STRIDE, m2a_g, m2a_be, out + 2 * PT);
}

// Round 9
// 548.805 us; speedup vs baseline: 4.0931x; 1.1005x over previous
//
#include <hip/hip_runtime.h>
#include <hip/hip_bf16.h>

#define NPTS 4096
#define CC   128
#define KNN  16
#define CNT_PER_GROUP 1048576.0f  // 16 ch * 4096 n * 16 k
#define STAT_STRIDE 1024          // 32 partial slots x [b(2) x g(8) x 2]

typedef __attribute__((ext_vector_type(8))) short bf16x8;
typedef __attribute__((ext_vector_type(4))) float f32x4;
typedef unsigned short ushort_t;

static __device__ __forceinline__ ushort_t f2bf(float f) {
    __hip_bfloat16 h = __float2bfloat16(f);   // RNE
    ushort_t u; __builtin_memcpy(&u, &h, 2);
    return u;
}

// ---------------------------------------------------------------- prep:
// y 0-3: f32 transposes (conv64 + maxconv weights); y 4-6: bf16 MFMA-B-fragment
// swizzle of the three convgn weights; y 7: zero stats.
__global__ void prep_kernel(const float* __restrict__ t11_w, const float* __restrict__ t22_w,
                            const float* __restrict__ t1_w,  const float* __restrict__ t2_w,
                            const float* __restrict__ m1a_w, const float* __restrict__ m1b_w,
                            const float* __restrict__ m2a_w,
                            float* __restrict__ wTt11, float* __restrict__ wTt22,
                            float* __restrict__ wTt1,  float* __restrict__ wTt2,
                            ushort_t* __restrict__ W2m1a, ushort_t* __restrict__ W2m1b,
                            ushort_t* __restrict__ W2m2a, float* __restrict__ stats) {
    int y = blockIdx.y;
    int idx = blockIdx.x * 256 + threadIdx.x;
    if (y == 7) {
        if (idx < 8 * STAT_STRIDE) stats[idx] = 0.0f;
        return;
    }
    if (y < 4) {
        const float* in; float* outp; int Cdim;
        switch (y) {
            case 0: in = t11_w; outp = wTt11; Cdim = 64; break;
            case 1: in = t22_w; outp = wTt22; Cdim = 64; break;
            case 2: in = t1_w;  outp = wTt1;  Cdim = CC; break;
            default: in = t2_w; outp = wTt2;  Cdim = CC; break;
        }
        if (idx < CC * Cdim) {
            int o = idx / Cdim, c = idx % Cdim;
            outp[c * CC + o] = in[idx];
        }
        return;
    }
    // B-fragment swizzle: idx = kb*4096 + coT*512 + lane*8 + j
    const float* in = y == 4 ? m1a_w : y == 5 ? m1b_w : m2a_w;
    ushort_t* outp  = y == 4 ? W2m1a : y == 5 ? W2m1b : W2m2a;
    if (idx < 16384) {
        int j = idx & 7, lane = (idx >> 3) & 63, coT = (idx >> 9) & 7, kb = idx >> 12;
        int k  = kb * 32 + (lane >> 4) * 8 + j;
        int co = coT * 16 + (lane & 15);
        outp[idx] = f2bf(in[co * CC + k]);
    }
}

// ------------------------------------------------- all 4 conv1d 64->128 in one dispatch
__global__ void conv64_kernel(const float* __restrict__ feat1, const float* __restrict__ feat2,
                              const float* __restrict__ wTt11, const float* __restrict__ wTt22,
                              const float* __restrict__ b11, const float* __restrict__ b22,
                              float* __restrict__ f1, float* __restrict__ f2,
                              float* __restrict__ g1, float* __restrict__ g2) {
    int y = blockIdx.y;
    const float* x  = (y == 0 || y == 3) ? feat1 : feat2;
    const float* wT = (y == 0 || y == 2) ? wTt11 : wTt22;
    const float* bias = (y == 0 || y == 2) ? b11 : b22;
    float* outp = y == 0 ? f1 : y == 1 ? f2 : y == 2 ? g1 : g2;
    int tx = threadIdx.x & 127, ty = threadIdx.x >> 7;
    int p = blockIdx.x * 2 + ty;            // b*N + n
    int b = p >> 12, n = p & 4095;
    float acc = bias[tx];
    const float* xb = x + (size_t)b * 64 * NPTS + n;
    #pragma unroll 8
    for (int ci = 0; ci < 64; ++ci)
        acc += wT[(size_t)ci * CC + tx] * xb[(size_t)ci * NPTS];
    outp[(size_t)p * CC + tx] = acc;
}

// ---------------------------------------------------------------- 64-bit shuffles
static __device__ __forceinline__ unsigned long long sxor64(unsigned long long v, int m) {
    unsigned lo = (unsigned)__shfl_xor((int)(unsigned)v, m);
    unsigned hi = (unsigned)__shfl_xor((int)(v >> 32), m);
    return ((unsigned long long)hi << 32) | lo;
}

// ------------------------------------------------- KNN, wave-per-4-queries, 2-pass.
// pk[j*64+lane]: lane-consecutive float4 reads (conflict-free b128). Each candidate
// read is reused across 4 register-resident queries. d2 expression order identical
// to passing rounds -> bit-identical selection.
__global__ __launch_bounds__(512) void knn_kernel(
        const float* __restrict__ pc1, const float* __restrict__ pc2,
        int* __restrict__ idx12, int* __restrict__ idx21) {
#pragma clang fp contract(off)
    __shared__ float4 pk[NPTS];                           // 64 KB
    __shared__ unsigned long long lst[8][4][64];          // 16 KB
    int dir = blockIdx.y;
    const float* qs = dir ? pc2 : pc1;
    const float* cs = dir ? pc1 : pc2;
    int* outIdx = dir ? idx21 : idx12;
    int tid = threadIdx.x, lane = tid & 63, wv = tid >> 6;
    int qbase = blockIdx.x * 32;           // 32 queries per block, same b
    int b = qbase >> 12;
    const float* cb = cs + (size_t)b * 3 * NPTS;
    for (int i = tid; i < NPTS; i += 512) {
        float x = cb[i], y = cb[NPTS + i], z = cb[2 * NPTS + i];
        pk[i] = make_float4(x, y, z, x * x + y * y + z * z);  // l2r, no fma
    }
    __syncthreads();
    const float* qb = qs + (size_t)b * 3 * NPTS;
    int q0 = qbase + wv * 4;
    float qx[4], qy[4], qz[4], s1[4], dmin[4], T[4];
    #pragma unroll
    for (int t = 0; t < 4; ++t) {
        int n = (q0 + t) & 4095;
        qx[t] = qb[n]; qy[t] = qb[NPTS + n]; qz[t] = qb[2 * NPTS + n];
        s1[t] = qx[t] * qx[t] + qy[t] * qy[t] + qz[t] * qz[t];   // l2r, no fma
        dmin[t] = 1e30f;
    }
    // pass 1: per-lane min per query
    for (int j = 0; j < 64; ++j) {
        float4 P = pk[j * 64 + lane];
        #pragma unroll
        for (int t = 0; t < 4; ++t) {
            float dt = __builtin_fmaf(P.z, qz[t], __builtin_fmaf(P.y, qy[t], P.x * qx[t]));
            float d2 = (s1[t] + P.w) - 2.0f * dt;
            dmin[t] = fminf(dmin[t], d2);
        }
    }
    // T[t] = 16th smallest of the 64 per-lane minima (valid bound on global 16th)
    #pragma unroll
    for (int t = 0; t < 4; ++t) {
        float sv = dmin[t];
        for (int k = 2; k <= 64; k <<= 1)
            for (int j = k >> 1; j > 0; j >>= 1) {
                float o = __shfl_xor(sv, j);
                bool tmin = (((lane & k) == 0) == ((lane & j) == 0));
                sv = tmin ? fminf(sv, o) : fmaxf(sv, o);
            }
        T[t] = __shfl(sv, 15);
    }
    // pass 2: recompute d2 (bit-identical), ballot-compact survivors per query
    int base[4] = {0, 0, 0, 0};
    for (int j = 0; j < 64; ++j) {
        float4 P = pk[j * 64 + lane];
        int m = j * 64 + lane;
        #pragma unroll
        for (int t = 0; t < 4; ++t) {
            float dt = __builtin_fmaf(P.z, qz[t], __builtin_fmaf(P.y, qy[t], P.x * qx[t]));
            float d2 = (s1[t] + P.w) - 2.0f * dt;
            bool p = (d2 <= T[t]);
            unsigned long long mk = __ballot(p);
            if (p) {
                int pos = base[t] + (int)__popcll(mk & ((1ULL << lane) - 1ULL));
                unsigned u = __float_as_uint(d2);
                u ^= (unsigned)(((int)u >> 31) | 0x80000000);
                unsigned long long key = ((unsigned long long)u << 32) | (unsigned)m;
                if (pos < 64) lst[wv][t][pos] = key;
            }
            base[t] += (int)__popcll(mk);
        }
    }
    // per query: bitonic sort 64 keys ascending -> lanes 0..15 = stable top-16
    #pragma unroll
    for (int t = 0; t < 4; ++t) {
        int nT = base[t] < 64 ? base[t] : 64;   // E[survivors]~19; P(>64) ~ 1e-24
        unsigned long long key = (lane < nT) ? lst[wv][t][lane] : ~0ULL;
        for (int k = 2; k <= 64; k <<= 1)
            for (int j = k >> 1; j > 0; j >>= 1) {
                unsigned long long o = sxor64(key, j);
                bool tmin = (((lane & k) == 0) == ((lane & j) == 0));
                unsigned long long mn = key < o ? key : o;
                unsigned long long mx = key < o ? o : key;
                key = tmin ? mn : mx;
            }
        if (lane < KNN) outIdx[(size_t)(q0 + t) * KNN + lane] = (int)(unsigned)(key & 0xFFFFFFFFULL);
    }
}

// ------------------------------------------------- h0 = group(p2) + p1 + pos_conv + fused stats
__global__ void h0_kernel(const float* __restrict__ p1f, const float* __restrict__ p2f,
                          const float* __restrict__ pcA, const float* __restrict__ pcB,
                          const int* __restrict__ idx,
                          const float* __restrict__ pos_w, const float* __restrict__ pos_b,
                          float* __restrict__ buf, float* __restrict__ stats_out) {
    __shared__ float redS[128], redQ[128];
    int p = blockIdx.x;                    // b*N + n
    int b = p >> 12, n = p & 4095;
    int c = threadIdx.x;
    float pw0 = pos_w[c * 3], pw1 = pos_w[c * 3 + 1], pw2 = pos_w[c * 3 + 2];
    float pb = pos_b[c];
    float p1v = p1f[(size_t)p * CC + c];
    const float* pa = pcA + (size_t)b * 3 * NPTS;
    const float* pc = pcB + (size_t)b * 3 * NPTS;
    float qx = pa[n], qy = pa[NPTS + n], qz = pa[2 * NPTS + n];
    float S = 0.f, Q = 0.f;
    for (int k = 0; k < KNN; ++k) {
        int m = idx[(size_t)p * KNN + k];
        float dx = pc[m] - qx;
        float dy = pc[NPTS + m] - qy;
        float dz = pc[2 * NPTS + m] - qz;
        float pos = pw0 * dx + pw1 * dy + pw2 * dz + pb;
        float v = p2f[((size_t)b * NPTS + m) * CC + c] + p1v + pos;
        buf[((size_t)p * KNN + k) * CC + c] = v;
        S += v; Q += v * v;
    }
    redS[c] = S; redQ[c] = Q;
    __syncthreads();
    if (c < 8) {
        float SS = 0.f, QQ = 0.f;
        for (int i = 0; i < 16; ++i) { SS += redS[c * 16 + i]; QQ += redQ[c * 16 + i]; }
        int s = blockIdx.x & 31;
        atomicAdd(&stats_out[s * 32 + (b * 8 + c) * 2],     SS);
        atomicAdd(&stats_out[s * 32 + (b * 8 + c) * 2 + 1], QQ);
    }
}

// ------------------------------------------------- y = W * lrelu(gn(x)) + bias via bf16 MFMA
// block: 64 rows x 128 co, 4 waves; wave: 16 rows, 8 co-tiles, K-loop 4x32.
__global__ __launch_bounds__(256) void convgn_kernel(
        const float* __restrict__ xbuf, const float* __restrict__ stats_in,
        const float* __restrict__ gam, const float* __restrict__ bet,
        const ushort_t* __restrict__ W2, const float* __restrict__ bias,
        float* __restrict__ ybuf, float* __restrict__ stats_out) {
    __shared__ ushort_t xt[64 * 136];      // bf16, row stride 136 els (272B): 2-way alias only
    __shared__ float sc[CC], sh[CC];
    __shared__ float redS[4][8], redQ[4][8];
    int tid = threadIdx.x;
    int s0 = blockIdx.x * 64;              // 64 rows, never crosses b
    int b = s0 >> 16;
    if (tid < CC) {
        int g = tid >> 4;
        float S = 0.f, Q = 0.f;
        for (int s = 0; s < 32; ++s) {
            S += stats_in[s * 32 + (b * 8 + g) * 2];
            Q += stats_in[s * 32 + (b * 8 + g) * 2 + 1];
        }
        float mu = S / CNT_PER_GROUP;
        float var = Q / CNT_PER_GROUP - mu * mu;
        float rs = rsqrtf(var + 1e-5f);
        float scale = gam[tid] * rs;
        sc[tid] = scale;
        sh[tid] = bet[tid] - mu * scale;
    }
    __syncthreads();
    // stage GN+lrelu x into LDS as bf16
    #pragma unroll
    for (int j = 0; j < 8; ++j) {
        int idx = tid + 256 * j;           // 2048 float4 chunks
        int row = idx >> 5, c4 = (idx & 31) * 4;
        float4 v = *(const float4*)&xbuf[(size_t)(s0 + row) * CC + c4];
        v.x = v.x * sc[c4]     + sh[c4];     v.x = v.x >= 0.f ? v.x : 0.1f * v.x;
        v.y = v.y * sc[c4 + 1] + sh[c4 + 1]; v.y = v.y >= 0.f ? v.y : 0.1f * v.y;
        v.z = v.z * sc[c4 + 2] + sh[c4 + 2]; v.z = v.z >= 0.f ? v.z : 0.1f * v.z;
        v.w = v.w * sc[c4 + 3] + sh[c4 + 3]; v.w = v.w >= 0.f ? v.w : 0.1f * v.w;
        ushort4 o = make_ushort4(f2bf(v.x), f2bf(v.y), f2bf(v.z), f2bf(v.w));
        *(ushort4*)&xt[row * 136 + c4] = o;
    }
    __syncthreads();
    int lane = tid & 63, wv = tid >> 6;
    int r0 = wv * 16;
    int quad = lane >> 4;
    f32x4 acc[8];
    #pragma unroll
    for (int t = 0; t < 8; ++t) acc[t] = (f32x4){0.f, 0.f, 0.f, 0.f};
    int aoff = (r0 + (lane & 15)) * 136 + quad * 8;
    #pragma unroll
    for (int kb = 0; kb < 4; ++kb) {
        bf16x8 a = *(const bf16x8*)&xt[aoff + kb * 32];
        const ushort_t* wb = W2 + (size_t)kb * 4096 + lane * 8;
        #pragma unroll
        for (int t = 0; t < 8; ++t) {
            bf16x8 bf = *(const bf16x8*)&wb[t * 512];
            acc[t] = __builtin_amdgcn_mfma_f32_16x16x32_bf16(a, bf, acc[t], 0, 0, 0);
        }
    }
    // epilogue: bias, store f32, fused stats (group g == co-tile t)
    #pragma unroll
    for (int t = 0; t < 8; ++t) {
        int co = t * 16 + (lane & 15);
        float bv = bias[co];
        float S = 0.f, Q = 0.f;
        #pragma unroll
        for (int reg = 0; reg < 4; ++reg) {
            int row = s0 + r0 + quad * 4 + reg;
            float y = acc[t][reg] + bv;
            ybuf[(size_t)row * CC + co] = y;
            S += y; Q += y * y;
        }
        #pragma unroll
        for (int off = 1; off < 64; off <<= 1) {
            S += __shfl_xor(S, off);
            Q += __shfl_xor(Q, off);
        }
        if (lane == 0) { redS[wv][t] = S; redQ[wv][t] = Q; }
    }
    __syncthreads();
    if (tid < 8) {
        float S = redS[0][tid] + redS[1][tid] + redS[2][tid] + redS[3][tid];
        float Q = redQ[0][tid] + redQ[1][tid] + redQ[2][tid] + redQ[3][tid];
        int s = blockIdx.x & 31;
        atomicAdd(&stats_out[s * 32 + (b * 8 + tid) * 2],     S);
        atomicAdd(&stats_out[s * 32 + (b * 8 + tid) * 2 + 1], Q);
    }
}

// ------------------------------------------------- maxpool only (cross3 tail)
__global__ void maxpool_kernel(const float* __restrict__ ybuf, const float* __restrict__ stats,
                               const float* __restrict__ gam, const float* __restrict__ bet,
                               float* __restrict__ outb) {
    int p = blockIdx.x;                    // b*N + n
    int b = p >> 12, n = p & 4095;
    int c = threadIdx.x;
    int g = c >> 4;
    float S = 0.f, Q = 0.f;
    for (int s = 0; s < 32; ++s) {
        S += stats[s * 32 + (b * 8 + g) * 2];
        Q += stats[s * 32 + (b * 8 + g) * 2 + 1];
    }
    float mu = S / CNT_PER_GROUP;
    float var = Q / CNT_PER_GROUP - mu * mu;
    float rs = rsqrtf(var + 1e-5f);
    float scale = gam[c] * rs;
    float shift = bet[c] - mu * scale;
    float mx = -INFINITY;
    for (int k = 0; k < KNN; ++k) {
        float v = ybuf[((size_t)p * KNN + k) * CC + c] * scale + shift;
        v = v >= 0.f ? v : 0.1f * v;
        mx = fmaxf(mx, v);
    }
    outb[((size_t)b * CC + c) * NPTS + n] = mx;
}

// ------------------------------------------------- fused maxpool + 128x128 conv (cross1/2 tail)
__global__ void maxconv_kernel(const float* __restrict__ ybuf, const float* __restrict__ stats,
                               const float* __restrict__ gam, const float* __restrict__ bet,
                               const float* __restrict__ wT, const float* __restrict__ bias,
                               float* __restrict__ outf, float* __restrict__ outb) {
    __shared__ float mxs[CC];
    int p = blockIdx.x;                    // b*N + n
    int b = p >> 12, n = p & 4095;
    int c = threadIdx.x;
    int g = c >> 4;
    float S = 0.f, Q = 0.f;
    for (int s = 0; s < 32; ++s) {
        S += stats[s * 32 + (b * 8 + g) * 2];
        Q += stats[s * 32 + (b * 8 + g) * 2 + 1];
    }
    float mu = S / CNT_PER_GROUP;
    float var = Q / CNT_PER_GROUP - mu * mu;
    float rs = rsqrtf(var + 1e-5f);
    float scale = gam[c] * rs;
    float shift = bet[c] - mu * scale;
    float mx = -INFINITY;
    for (int k = 0; k < KNN; ++k) {
        float v = ybuf[((size_t)p * KNN + k) * CC + c] * scale + shift;
        v = v >= 0.f ? v : 0.1f * v;
        mx = fmaxf(mx, v);
    }
    mxs[c] = mx;
    __syncthreads();
    float acc = bias[c];
    #pragma unroll 8
    for (int ci = 0; ci < CC; ++ci)
        acc += wT[(size_t)ci * CC + c] * mxs[ci];
    outf[(size_t)p * CC + c] = acc;
    outb[((size_t)b * CC + c) * NPTS + n] = acc;
}

extern "C" void kernel_launch(void* const* d_in, const int* in_sizes, int n_in,
                              void* d_out, int out_size, void* d_ws, size_t ws_size,
                              hipStream_t stream) {
    (void)in_sizes; (void)n_in; (void)out_size; (void)ws_size;
    const float* pc1    = (const float*)d_in[0];
    const float* pc2    = (const float*)d_in[1];
    const float* feat1  = (const float*)d_in[2];
    const float* feat2  = (const float*)d_in[3];
    const float* t11_w  = (const float*)d_in[4];
    const float* t11_b  = (const float*)d_in[5];
    const float* t22_w  = (const float*)d_in[6];
    const float* t22_b  = (const float*)d_in[7];
    const float* pos1_w = (const float*)d_in[8];
    const float* pos1_b = (const float*)d_in[9];
    const float* gn1_g  = (const float*)d_in[10];
    const float* gn1_b  = (const float*)d_in[11];
    const float* m1a_w  = (const float*)d_in[12];
    const float* m1a_b  = (const float*)d_in[13];
    const float* m1a_g  = (const float*)d_in[14];
    const float* m1a_be = (const float*)d_in[15];
    const float* m1b_w  = (const float*)d_in[16];
    const float* m1b_b  = (const float*)d_in[17];
    const float* m1b_g  = (const float*)d_in[18];
    const float* m1b_be = (const float*)d_in[19];
    const float* t1_w   = (const float*)d_in[20];
    const float* t1_b   = (const float*)d_in[21];
    const float* t2_w   = (const float*)d_in[22];
    const float* t2_b   = (const float*)d_in[23];
    const float* pos2_w = (const float*)d_in[24];
    const float* pos2_b = (const float*)d_in[25];
    const float* gn2_g  = (const float*)d_in[26];
    const float* gn2_b  = (const float*)d_in[27];
    const float* m2a_w  = (const float*)d_in[28];
    const float* m2a_b  = (const float*)d_in[29];
    const float* m2a_g  = (const float*)d_in[30];
    const float* m2a_be = (const float*)d_in[31];

    float* out = (float*)d_out;
    const size_t PN = 2 * NPTS;              // 8192 points
    const size_t PT = PN * CC;               // 1,048,576 f32 per point-tensor
    float* ws   = (float*)d_ws;
    float* f1   = ws;
    float* f2   = f1 + PT;
    float* g1   = f2 + PT;
    float* g2   = g1 + PT;
    float* f1n  = g2 + PT;
    float* f2n  = f1n + PT;
    int*   idx12 = (int*)(f2n + PT);
    int*   idx21 = idx12 + PN * KNN;
    float* stats = (float*)(idx21 + PN * KNN);     // 8 stages * 1024
    float* wTt11 = stats + 8 * STAT_STRIDE;        // f32 [64][128]
    float* wTt22 = wTt11 + 64 * CC;
    float* wTt1  = wTt22 + 64 * CC;                // f32 [128][128]
    float* wTt2  = wTt1 + CC * CC;
    ushort_t* W2m1a = (ushort_t*)(wTt2 + CC * CC); // bf16 swizzled [16384]
    ushort_t* W2m1b = W2m1a + 16384;
    ushort_t* W2m2a = W2m1b + 16384;
    float* bufX  = (float*)(W2m2a + 16384);
    float* bufY  = bufX + (size_t)PN * KNN * CC;   // 16,777,216 f32 each

    prep_kernel<<<dim3(64, 8), 256, 0, stream>>>(
        t11_w, t22_w, t1_w, t2_w, m1a_w, m1b_w, m2a_w,
        wTt11, wTt22, wTt1, wTt2, W2m1a, W2m1b, W2m2a, stats);

    conv64_kernel<<<dim3(PN / 2, 4), 256, 0, stream>>>(
        feat1, feat2, wTt11, wTt22, t11_b, t22_b, f1, f2, g1, g2);
    knn_kernel<<<dim3(PN / 32, 2), 512, 0, stream>>>(pc1, pc2, idx12, idx21);

    float* st0 = stats;
    // ---- cross1: (pc1, pc2, f1, f2) -> t1 -> feat1_new
    h0_kernel<<<PN, 128, 0, stream>>>(f1, f2, pc1, pc2, idx12, pos1_w, pos1_b, bufX, st0 + 0 * STAT_STRIDE);
    convgn_kernel<<<2048, 256, 0, stream>>>(bufX, st0 + 0 * STAT_STRIDE, gn1_g, gn1_b, W2m1a, m1a_b, bufY, st0 + 1 * STAT_STRIDE);
    convgn_kernel<<<2048, 256, 0, stream>>>(bufY, st0 + 1 * STAT_STRIDE, m1a_g, m1a_be, W2m1b, m1b_b, bufX, st0 + 2 * STAT_STRIDE);
    maxconv_kernel<<<PN, 128, 0, stream>>>(bufX, st0 + 2 * STAT_STRIDE, m1b_g, m1b_be, wTt1, t1_b, f1n, out);

    // ---- cross2: (pc2, pc1, g1, g2) -> t2 -> feat2_new
    h0_kernel<<<PN, 128, 0, stream>>>(g1, g2, pc2, pc1, idx21, pos1_w, pos1_b, bufX, st0 + 3 * STAT_STRIDE);
    convgn_kernel<<<2048, 256, 0, stream>>>(bufX, st0 + 3 * STAT_STRIDE, gn1_g, gn1_b, W2m1a, m1a_b, bufY, st0 + 4 * STAT_STRIDE);
    convgn_kernel<<<2048, 256, 0, stream>>>(bufY, st0 + 4 * STAT_STRIDE, m1a_g, m1a_be, W2m1b, m1b_b, bufX, st0 + 5 * STAT_STRIDE);
    maxconv_kernel<<<PN, 128, 0, stream>>>(bufX, st0 + 5 * STAT_STRIDE, m1b_g, m1b_be, wTt2, t2_b, f2n, out + PT);

    // ---- cross3: (pc1, pc2, feat1_new, feat2_new) -> feat1_final
    h0_kernel<<<PN, 128, 0, stream>>>(f1n, f2n, pc1, pc2, idx12, pos2_w, pos2_b, bufX, st0 + 6 * STAT_STRIDE);
    convgn_kernel<<<2048, 256, 0, stream>>>(bufX, st0 + 6 * STAT_STRIDE, gn2_g, gn2_b, W2m2a, m2a_b, bufY, st0 + 7 * STAT_STRIDE);
    maxpool_kernel<<<PN, 128, 0, stream>>>(bufY, st0 + 7 * STAT_STRIDE, m2a_g, m2a_be, out + 2 * PT);
}

// Round 10
// 457.237 us; speedup vs baseline: 4.9127x; 1.2003x over previous
//
#include <hip/hip_runtime.h>
#include <hip/hip_bf16.h>

#define NPTS 4096
#define CC   128
#define KNN  16
#define CNT_PER_GROUP 1048576.0f  // 16 ch * 4096 n * 16 k
#define STAT_STRIDE 1024          // 32 partial slots x [b(2) x g(8) x 2]

typedef __attribute__((ext_vector_type(8))) short bf16x8;
typedef __attribute__((ext_vector_type(8))) unsigned short u16x8;
typedef __attribute__((ext_vector_type(4))) float f32x4;
typedef unsigned short ushort_t;

static __device__ __forceinline__ ushort_t f2bf(float f) {
    __hip_bfloat16 h = __float2bfloat16(f);   // RNE
    ushort_t u; __builtin_memcpy(&u, &h, 2);
    return u;
}
static __device__ __forceinline__ float bf2f(ushort_t u) {
    unsigned v = (unsigned)u << 16;
    float f; __builtin_memcpy(&f, &v, 4);
    return f;
}

// ---------------------------------------------------------------- prep:
// y 0-3: f32 transposes (conv64 + maxconv weights); y 4-6: bf16 MFMA-B-fragment
// swizzle of the three convgn weights; y 7: zero stats.
__global__ void prep_kernel(const float* __restrict__ t11_w, const float* __restrict__ t22_w,
                            const float* __restrict__ t1_w,  const float* __restrict__ t2_w,
                            const float* __restrict__ m1a_w, const float* __restrict__ m1b_w,
                            const float* __restrict__ m2a_w,
                            float* __restrict__ wTt11, float* __restrict__ wTt22,
                            float* __restrict__ wTt1,  float* __restrict__ wTt2,
                            ushort_t* __restrict__ W2m1a, ushort_t* __restrict__ W2m1b,
                            ushort_t* __restrict__ W2m2a, float* __restrict__ stats) {
    int y = blockIdx.y;
    int idx = blockIdx.x * 256 + threadIdx.x;
    if (y == 7) {
        if (idx < 8 * STAT_STRIDE) stats[idx] = 0.0f;
        return;
    }
    if (y < 4) {
        const float* in; float* outp; int Cdim;
        switch (y) {
            case 0: in = t11_w; outp = wTt11; Cdim = 64; break;
            case 1: in = t22_w; outp = wTt22; Cdim = 64; break;
            case 2: in = t1_w;  outp = wTt1;  Cdim = CC; break;
            default: in = t2_w; outp = wTt2;  Cdim = CC; break;
        }
        if (idx < CC * Cdim) {
            int o = idx / Cdim, c = idx % Cdim;
            outp[c * CC + o] = in[idx];
        }
        return;
    }
    // B-fragment swizzle: idx = kb*4096 + coT*512 + lane*8 + j
    const float* in = y == 4 ? m1a_w : y == 5 ? m1b_w : m2a_w;
    ushort_t* outp  = y == 4 ? W2m1a : y == 5 ? W2m1b : W2m2a;
    if (idx < 16384) {
        int j = idx & 7, lane = (idx >> 3) & 63, coT = (idx >> 9) & 7, kb = idx >> 12;
        int k  = kb * 32 + (lane >> 4) * 8 + j;
        int co = coT * 16 + (lane & 15);
        outp[idx] = f2bf(in[co * CC + k]);
    }
}

// ------------------------------------------------- conv1d 64->128, LDS-staged tile GEMM
// grid (PN/64, 4); block 256; 64 n-rows x 128 co per block.
__global__ __launch_bounds__(256) void conv64_kernel(
        const float* __restrict__ feat1, const float* __restrict__ feat2,
        const float* __restrict__ wTt11, const float* __restrict__ wTt22,
        const float* __restrict__ b11, const float* __restrict__ b22,
        float* __restrict__ f1, float* __restrict__ f2,
        float* __restrict__ g1, float* __restrict__ g2) {
    __shared__ float xs[64][68];           // [ci][n], pad 68 -> 17 KB
    int y = blockIdx.y;
    const float* x  = (y == 0 || y == 3) ? feat1 : feat2;
    const float* wT = (y == 0 || y == 2) ? wTt11 : wTt22;
    const float* bias = (y == 0 || y == 2) ? b11 : b22;
    float* outp = y == 0 ? f1 : y == 1 ? f2 : y == 2 ? g1 : g2;
    int tid = threadIdx.x;
    int n0 = blockIdx.x * 64;              // b*N + n base; never crosses b
    int b = n0 >> 12, nloc = n0 & 4095;
    const float* xb = x + (size_t)b * 64 * NPTS + nloc;
    #pragma unroll
    for (int i = 0; i < 16; ++i) {
        int e = tid + 256 * i;             // e = ci*64 + nn
        int ci = e >> 6, nn = e & 63;
        xs[ci][nn] = xb[(size_t)ci * NPTS + nn];
    }
    __syncthreads();
    int co = (tid & 31) * 4;
    int r0 = (tid >> 5) * 8;
    float acc[4][8];
    float4 bv = *(const float4*)&bias[co];
    #pragma unroll
    for (int j = 0; j < 8; ++j) { acc[0][j] = bv.x; acc[1][j] = bv.y; acc[2][j] = bv.z; acc[3][j] = bv.w; }
    for (int ci = 0; ci < 64; ++ci) {
        float4 wv = *(const float4*)&wT[(size_t)ci * CC + co];
        #pragma unroll
        for (int j = 0; j < 8; ++j) {
            float xv = xs[ci][r0 + j];     // broadcast within half-wave
            acc[0][j] += wv.x * xv;
            acc[1][j] += wv.y * xv;
            acc[2][j] += wv.z * xv;
            acc[3][j] += wv.w * xv;
        }
    }
    #pragma unroll
    for (int j = 0; j < 8; ++j) {
        *(float4*)&outp[(size_t)(n0 + r0 + j) * CC + co] =
            make_float4(acc[0][j], acc[1][j], acc[2][j], acc[3][j]);
    }
}

// ---------------------------------------------------------------- 64-bit shuffles
static __device__ __forceinline__ unsigned long long sxor64(unsigned long long v, int m) {
    unsigned lo = (unsigned)__shfl_xor((int)(unsigned)v, m);
    unsigned hi = (unsigned)__shfl_xor((int)(v >> 32), m);
    return ((unsigned long long)hi << 32) | lo;
}

// ------------------------------------------------- KNN (unchanged from round 9, passing)
__global__ __launch_bounds__(512) void knn_kernel(
        const float* __restrict__ pc1, const float* __restrict__ pc2,
        int* __restrict__ idx12, int* __restrict__ idx21) {
#pragma clang fp contract(off)
    __shared__ float4 pk[NPTS];                           // 64 KB
    __shared__ unsigned long long lst[8][4][64];          // 16 KB
    int dir = blockIdx.y;
    const float* qs = dir ? pc2 : pc1;
    const float* cs = dir ? pc1 : pc2;
    int* outIdx = dir ? idx21 : idx12;
    int tid = threadIdx.x, lane = tid & 63, wv = tid >> 6;
    int qbase = blockIdx.x * 32;           // 32 queries per block, same b
    int b = qbase >> 12;
    const float* cb = cs + (size_t)b * 3 * NPTS;
    for (int i = tid; i < NPTS; i += 512) {
        float x = cb[i], y = cb[NPTS + i], z = cb[2 * NPTS + i];
        pk[i] = make_float4(x, y, z, x * x + y * y + z * z);  // l2r, no fma
    }
    __syncthreads();
    const float* qb = qs + (size_t)b * 3 * NPTS;
    int q0 = qbase + wv * 4;
    float qx[4], qy[4], qz[4], s1[4], dmin[4], T[4];
    #pragma unroll
    for (int t = 0; t < 4; ++t) {
        int n = (q0 + t) & 4095;
        qx[t] = qb[n]; qy[t] = qb[NPTS + n]; qz[t] = qb[2 * NPTS + n];
        s1[t] = qx[t] * qx[t] + qy[t] * qy[t] + qz[t] * qz[t];   // l2r, no fma
        dmin[t] = 1e30f;
    }
    for (int j = 0; j < 64; ++j) {
        float4 P = pk[j * 64 + lane];
        #pragma unroll
        for (int t = 0; t < 4; ++t) {
            float dt = __builtin_fmaf(P.z, qz[t], __builtin_fmaf(P.y, qy[t], P.x * qx[t]));
            float d2 = (s1[t] + P.w) - 2.0f * dt;
            dmin[t] = fminf(dmin[t], d2);
        }
    }
    #pragma unroll
    for (int t = 0; t < 4; ++t) {
        float sv = dmin[t];
        for (int k = 2; k <= 64; k <<= 1)
            for (int j = k >> 1; j > 0; j >>= 1) {
                float o = __shfl_xor(sv, j);
                bool tmin = (((lane & k) == 0) == ((lane & j) == 0));
                sv = tmin ? fminf(sv, o) : fmaxf(sv, o);
            }
        T[t] = __shfl(sv, 15);
    }
    int base[4] = {0, 0, 0, 0};
    for (int j = 0; j < 64; ++j) {
        float4 P = pk[j * 64 + lane];
        int m = j * 64 + lane;
        #pragma unroll
        for (int t = 0; t < 4; ++t) {
            float dt = __builtin_fmaf(P.z, qz[t], __builtin_fmaf(P.y, qy[t], P.x * qx[t]));
            float d2 = (s1[t] + P.w) - 2.0f * dt;
            bool p = (d2 <= T[t]);
            unsigned long long mk = __ballot(p);
            if (p) {
                int pos = base[t] + (int)__popcll(mk & ((1ULL << lane) - 1ULL));
                unsigned u = __float_as_uint(d2);
                u ^= (unsigned)(((int)u >> 31) | 0x80000000);
                unsigned long long key = ((unsigned long long)u << 32) | (unsigned)m;
                if (pos < 64) lst[wv][t][pos] = key;
            }
            base[t] += (int)__popcll(mk);
        }
    }
    #pragma unroll
    for (int t = 0; t < 4; ++t) {
        int nT = base[t] < 64 ? base[t] : 64;   // E[survivors]~19; P(>64) ~ 1e-24
        unsigned long long key = (lane < nT) ? lst[wv][t][lane] : ~0ULL;
        for (int k = 2; k <= 64; k <<= 1)
            for (int j = k >> 1; j > 0; j >>= 1) {
                unsigned long long o = sxor64(key, j);
                bool tmin = (((lane & k) == 0) == ((lane & j) == 0));
                unsigned long long mn = key < o ? key : o;
                unsigned long long mx = key < o ? o : key;
                key = tmin ? mn : mx;
            }
        if (lane < KNN) outIdx[(size_t)(q0 + t) * KNN + lane] = (int)(unsigned)(key & 0xFFFFFFFFULL);
    }
}

// ------------------------------------------------- h0 = group(p2) + p1 + pos_conv + fused stats
// writes bf16 buf; stats from unrounded f32
__global__ void h0_kernel(const float* __restrict__ p1f, const float* __restrict__ p2f,
                          const float* __restrict__ pcA, const float* __restrict__ pcB,
                          const int* __restrict__ idx,
                          const float* __restrict__ pos_w, const float* __restrict__ pos_b,
                          ushort_t* __restrict__ buf, float* __restrict__ stats_out) {
    __shared__ float redS[128], redQ[128];
    int p = blockIdx.x;                    // b*N + n
    int b = p >> 12, n = p & 4095;
    int c = threadIdx.x;
    float pw0 = pos_w[c * 3], pw1 = pos_w[c * 3 + 1], pw2 = pos_w[c * 3 + 2];
    float pb = pos_b[c];
    float p1v = p1f[(size_t)p * CC + c];
    const float* pa = pcA + (size_t)b * 3 * NPTS;
    const float* pc = pcB + (size_t)b * 3 * NPTS;
    float qx = pa[n], qy = pa[NPTS + n], qz = pa[2 * NPTS + n];
    float S = 0.f, Q = 0.f;
    for (int k = 0; k < KNN; ++k) {
        int m = idx[(size_t)p * KNN + k];
        float dx = pc[m] - qx;
        float dy = pc[NPTS + m] - qy;
        float dz = pc[2 * NPTS + m] - qz;
        float pos = pw0 * dx + pw1 * dy + pw2 * dz + pb;
        float v = p2f[((size_t)b * NPTS + m) * CC + c] + p1v + pos;
        buf[((size_t)p * KNN + k) * CC + c] = f2bf(v);
        S += v; Q += v * v;
    }
    redS[c] = S; redQ[c] = Q;
    __syncthreads();
    if (c < 8) {
        float SS = 0.f, QQ = 0.f;
        for (int i = 0; i < 16; ++i) { SS += redS[c * 16 + i]; QQ += redQ[c * 16 + i]; }
        int s = blockIdx.x & 31;
        atomicAdd(&stats_out[s * 32 + (b * 8 + c) * 2],     SS);
        atomicAdd(&stats_out[s * 32 + (b * 8 + c) * 2 + 1], QQ);
    }
}

// ------------------------------------------------- y = W * lrelu(gn(x)) + bias via bf16 MFMA
// bf16 in / bf16 out; block: 64 rows x 128 co, 4 waves.
__global__ __launch_bounds__(256) void convgn_kernel(
        const ushort_t* __restrict__ xbuf, const float* __restrict__ stats_in,
        const float* __restrict__ gam, const float* __restrict__ bet,
        const ushort_t* __restrict__ W2, const float* __restrict__ bias,
        ushort_t* __restrict__ ybuf, float* __restrict__ stats_out) {
    __shared__ ushort_t xt[64 * 136];      // bf16, row stride 136 (272B = 17*16B: aligned, 2-way alias)
    __shared__ float sc[CC], sh[CC];
    __shared__ float redS[4][8], redQ[4][8];
    int tid = threadIdx.x;
    int s0 = blockIdx.x * 64;              // 64 rows, never crosses b
    int b = s0 >> 16;
    if (tid < CC) {
        int g = tid >> 4;
        float S = 0.f, Q = 0.f;
        for (int s = 0; s < 32; ++s) {
            S += stats_in[s * 32 + (b * 8 + g) * 2];
            Q += stats_in[s * 32 + (b * 8 + g) * 2 + 1];
        }
        float mu = S / CNT_PER_GROUP;
        float var = Q / CNT_PER_GROUP - mu * mu;
        float rs = rsqrtf(var + 1e-5f);
        float scale = gam[tid] * rs;
        sc[tid] = scale;
        sh[tid] = bet[tid] - mu * scale;
    }
    __syncthreads();
    // stage GN+lrelu x into LDS as bf16 (ushort8 = 16B loads/stores)
    #pragma unroll
    for (int j = 0; j < 4; ++j) {
        int idx = tid + 256 * j;           // 1024 ushort8 chunks
        int row = idx >> 4, c8 = (idx & 15) * 8;
        u16x8 vin = *(const u16x8*)&xbuf[(size_t)(s0 + row) * CC + c8];
        u16x8 vo;
        #pragma unroll
        for (int e = 0; e < 8; ++e) {
            float v = bf2f(vin[e]) * sc[c8 + e] + sh[c8 + e];
            v = v >= 0.f ? v : 0.1f * v;
            vo[e] = f2bf(v);
        }
        *(u16x8*)&xt[row * 136 + c8] = vo;
    }
    __syncthreads();
    int lane = tid & 63, wv = tid >> 6;
    int r0 = wv * 16;
    int quad = lane >> 4;
    f32x4 acc[8];
    #pragma unroll
    for (int t = 0; t < 8; ++t) acc[t] = (f32x4){0.f, 0.f, 0.f, 0.f};
    int aoff = (r0 + (lane & 15)) * 136 + quad * 8;
    #pragma unroll
    for (int kb = 0; kb < 4; ++kb) {
        bf16x8 a = *(const bf16x8*)&xt[aoff + kb * 32];
        const ushort_t* wb = W2 + (size_t)kb * 4096 + lane * 8;
        #pragma unroll
        for (int t = 0; t < 8; ++t) {
            bf16x8 bf = *(const bf16x8*)&wb[t * 512];
            acc[t] = __builtin_amdgcn_mfma_f32_16x16x32_bf16(a, bf, acc[t], 0, 0, 0);
        }
    }
    // epilogue: bias, store bf16, fused stats from f32 (group g == co-tile t)
    #pragma unroll
    for (int t = 0; t < 8; ++t) {
        int co = t * 16 + (lane & 15);
        float bv = bias[co];
        float S = 0.f, Q = 0.f;
        #pragma unroll
        for (int reg = 0; reg < 4; ++reg) {
            int row = s0 + r0 + quad * 4 + reg;
            float y = acc[t][reg] + bv;
            ybuf[(size_t)row * CC + co] = f2bf(y);
            S += y; Q += y * y;
        }
        #pragma unroll
        for (int off = 1; off < 64; off <<= 1) {
            S += __shfl_xor(S, off);
            Q += __shfl_xor(Q, off);
        }
        if (lane == 0) { redS[wv][t] = S; redQ[wv][t] = Q; }
    }
    __syncthreads();
    if (tid < 8) {
        float S = redS[0][tid] + redS[1][tid] + redS[2][tid] + redS[3][tid];
        float Q = redQ[0][tid] + redQ[1][tid] + redQ[2][tid] + redQ[3][tid];
        int s = blockIdx.x & 31;
        atomicAdd(&stats_out[s * 32 + (b * 8 + tid) * 2],     S);
        atomicAdd(&stats_out[s * 32 + (b * 8 + tid) * 2 + 1], Q);
    }
}

// ------------------------------------------------- maxpool only (cross3 tail)
__global__ void maxpool_kernel(const ushort_t* __restrict__ ybuf, const float* __restrict__ stats,
                               const float* __restrict__ gam, const float* __restrict__ bet,
                               float* __restrict__ outb) {
    int p = blockIdx.x;                    // b*N + n
    int b = p >> 12, n = p & 4095;
    int c = threadIdx.x;
    int g = c >> 4;
    float S = 0.f, Q = 0.f;
    for (int s = 0; s < 32; ++s) {
        S += stats[s * 32 + (b * 8 + g) * 2];
        Q += stats[s * 32 + (b * 8 + g) * 2 + 1];
    }
    float mu = S / CNT_PER_GROUP;
    float var = Q / CNT_PER_GROUP - mu * mu;
    float rs = rsqrtf(var + 1e-5f);
    float scale = gam[c] * rs;
    float shift = bet[c] - mu * scale;
    float mx = -INFINITY;
    for (int k = 0; k < KNN; ++k) {
        float v = bf2f(ybuf[((size_t)p * KNN + k) * CC + c]) * scale + shift;
        v = v >= 0.f ? v : 0.1f * v;
        mx = fmaxf(mx, v);
    }
    outb[((size_t)b * CC + c) * NPTS + n] = mx;
}

// ------------------------------------------------- fused maxpool + 128x128 conv (cross1/2 tail)
__global__ void maxconv_kernel(const ushort_t* __restrict__ ybuf, const float* __restrict__ stats,
                               const float* __restrict__ gam, const float* __restrict__ bet,
                               const float* __restrict__ wT, const float* __restrict__ bias,
                               float* __restrict__ outf, float* __restrict__ outb) {
    __shared__ float mxs[CC];
    int p = blockIdx.x;                    // b*N + n
    int b = p >> 12, n = p & 4095;
    int c = threadIdx.x;
    int g = c >> 4;
    float S = 0.f, Q = 0.f;
    for (int s = 0; s < 32; ++s) {
        S += stats[s * 32 + (b * 8 + g) * 2];
        Q += stats[s * 32 + (b * 8 + g) * 2 + 1];
    }
    float mu = S / CNT_PER_GROUP;
    float var = Q / CNT_PER_GROUP - mu * mu;
    float rs = rsqrtf(var + 1e-5f);
    float scale = gam[c] * rs;
    float shift = bet[c] - mu * scale;
    float mx = -INFINITY;
    for (int k = 0; k < KNN; ++k) {
        float v = bf2f(ybuf[((size_t)p * KNN + k) * CC + c]) * scale + shift;
        v = v >= 0.f ? v : 0.1f * v;
        mx = fmaxf(mx, v);
    }
    mxs[c] = mx;
    __syncthreads();
    float acc = bias[c];
    #pragma unroll 8
    for (int ci = 0; ci < CC; ++ci)
        acc += wT[(size_t)ci * CC + c] * mxs[ci];
    outf[(size_t)p * CC + c] = acc;
    outb[((size_t)b * CC + c) * NPTS + n] = acc;
}

extern "C" void kernel_launch(void* const* d_in, const int* in_sizes, int n_in,
                              void* d_out, int out_size, void* d_ws, size_t ws_size,
                              hipStream_t stream) {
    (void)in_sizes; (void)n_in; (void)out_size; (void)ws_size;
    const float* pc1    = (const float*)d_in[0];
    const float* pc2    = (const float*)d_in[1];
    const float* feat1  = (const float*)d_in[2];
    const float* feat2  = (const float*)d_in[3];
    const float* t11_w  = (const float*)d_in[4];
    const float* t11_b  = (const float*)d_in[5];
    const float* t22_w  = (const float*)d_in[6];
    const float* t22_b  = (const float*)d_in[7];
    const float* pos1_w = (const float*)d_in[8];
    const float* pos1_b = (const float*)d_in[9];
    const float* gn1_g  = (const float*)d_in[10];
    const float* gn1_b  = (const float*)d_in[11];
    const float* m1a_w  = (const float*)d_in[12];
    const float* m1a_b  = (const float*)d_in[13];
    const float* m1a_g  = (const float*)d_in[14];
    const float* m1a_be = (const float*)d_in[15];
    const float* m1b_w  = (const float*)d_in[16];
    const float* m1b_b  = (const float*)d_in[17];
    const float* m1b_g  = (const float*)d_in[18];
    const float* m1b_be = (const float*)d_in[19];
    const float* t1_w   = (const float*)d_in[20];
    const float* t1_b   = (const float*)d_in[21];
    const float* t2_w   = (const float*)d_in[22];
    const float* t2_b   = (const float*)d_in[23];
    const float* pos2_w = (const float*)d_in[24];
    const float* pos2_b = (const float*)d_in[25];
    const float* gn2_g  = (const float*)d_in[26];
    const float* gn2_b  = (const float*)d_in[27];
    const float* m2a_w  = (const float*)d_in[28];
    const float* m2a_b  = (const float*)d_in[29];
    const float* m2a_g  = (const float*)d_in[30];
    const float* m2a_be = (const float*)d_in[31];

    float* out = (float*)d_out;
    const size_t PN = 2 * NPTS;              // 8192 points
    const size_t PT = PN * CC;               // 1,048,576 elements per point-tensor
    float* ws   = (float*)d_ws;
    float* f1   = ws;
    float* f2   = f1 + PT;
    float* g1   = f2 + PT;
    float* g2   = g1 + PT;
    float* f1n  = g2 + PT;
    float* f2n  = f1n + PT;
    int*   idx12 = (int*)(f2n + PT);
    int*   idx21 = idx12 + PN * KNN;
    float* stats = (float*)(idx21 + PN * KNN);     // 8 stages * 1024
    float* wTt11 = stats + 8 * STAT_STRIDE;        // f32 [64][128]
    float* wTt22 = wTt11 + 64 * CC;
    float* wTt1  = wTt22 + 64 * CC;                // f32 [128][128]
    float* wTt2  = wTt1 + CC * CC;
    ushort_t* W2m1a = (ushort_t*)(wTt2 + CC * CC); // bf16 swizzled [16384]
    ushort_t* W2m1b = W2m1a + 16384;
    ushort_t* W2m2a = W2m1b + 16384;
    ushort_t* bufX  = W2m2a + 16384;               // bf16 [PN*KNN*CC]
    ushort_t* bufY  = bufX + (size_t)PN * KNN * CC;

    prep_kernel<<<dim3(64, 8), 256, 0, stream>>>(
        t11_w, t22_w, t1_w, t2_w, m1a_w, m1b_w, m2a_w,
        wTt11, wTt22, wTt1, wTt2, W2m1a, W2m1b, W2m2a, stats);

    conv64_kernel<<<dim3(PN / 64, 4), 256, 0, stream>>>(
        feat1, feat2, wTt11, wTt22, t11_b, t22_b, f1, f2, g1, g2);
    knn_kernel<<<dim3(PN / 32, 2), 512, 0, stream>>>(pc1, pc2, idx12, idx21);

    float* st0 = stats;
    // ---- cross1: (pc1, pc2, f1, f2) -> t1 -> feat1_new
    h0_kernel<<<PN, 128, 0, stream>>>(f1, f2, pc1, pc2, idx12, pos1_w, pos1_b, bufX, st0 + 0 * STAT_STRIDE);
    convgn_kernel<<<2048, 256, 0, stream>>>(bufX, st0 + 0 * STAT_STRIDE, gn1_g, gn1_b, W2m1a, m1a_b, bufY, st0 + 1 * STAT_STRIDE);
    convgn_kernel<<<2048, 256, 0, stream>>>(bufY, st0 + 1 * STAT_STRIDE, m1a_g, m1a_be, W2m1b, m1b_b, bufX, st0 + 2 * STAT_STRIDE);
    maxconv_kernel<<<PN, 128, 0, stream>>>(bufX, st0 + 2 * STAT_STRIDE, m1b_g, m1b_be, wTt1, t1_b, f1n, out);

    // ---- cross2: (pc2, pc1, g1, g2) -> t2 -> feat2_new
    h0_kernel<<<PN, 128, 0, stream>>>(g1, g2, pc2, pc1, idx21, pos1_w, pos1_b, bufX, st0 + 3 * STAT_STRIDE);
    convgn_kernel<<<2048, 256, 0, stream>>>(bufX, st0 + 3 * STAT_STRIDE, gn1_g, gn1_b, W2m1a, m1a_b, bufY, st0 + 4 * STAT_STRIDE);
    convgn_kernel<<<2048, 256, 0, stream>>>(bufY, st0 + 4 * STAT_STRIDE, m1a_g, m1a_be, W2m1b, m1b_b, bufX, st0 + 5 * STAT_STRIDE);
    maxconv_kernel<<<PN, 128, 0, stream>>>(bufX, st0 + 5 * STAT_STRIDE, m1b_g, m1b_be, wTt2, t2_b, f2n, out + PT);

    // ---- cross3: (pc1, pc2, feat1_new, feat2_new) -> feat1_final
    h0_kernel<<<PN, 128, 0, stream>>>(f1n, f2n, pc1, pc2, idx12, pos2_w, pos2_b, bufX, st0 + 6 * STAT_STRIDE);
    convgn_kernel<<<2048, 256, 0, stream>>>(bufX, st0 + 6 * STAT_STRIDE, gn2_g, gn2_b, W2m2a, m2a_b, bufY, st0 + 7 * STAT_STRIDE);
    maxpool_kernel<<<PN, 128, 0, stream>>>(bufY, st0 + 7 * STAT_STRIDE, m2a_g, m2a_be, out + 2 * PT);
}

// Round 11
// 397.922 us; speedup vs baseline: 5.6450x; 1.1491x over previous
//
#include <hip/hip_runtime.h>
#include <hip/hip_bf16.h>

#define NPTS 4096
#define CC   128
#define KNN  16
#define CNT_PER_GROUP 1048576.0f  // 16 ch * 4096 n * 16 k
#define STAT_STRIDE 1024          // 32 partial slots x [b(2) x g(8) x 2]

typedef __attribute__((ext_vector_type(8))) short bf16x8;
typedef __attribute__((ext_vector_type(8))) unsigned short u16x8;
typedef __attribute__((ext_vector_type(4))) float f32x4;
typedef unsigned short ushort_t;

static __device__ __forceinline__ ushort_t f2bf(float f) {
    __hip_bfloat16 h = __float2bfloat16(f);   // RNE
    ushort_t u; __builtin_memcpy(&u, &h, 2);
    return u;
}
static __device__ __forceinline__ float bf2f(ushort_t u) {
    unsigned v = (unsigned)u << 16;
    float f; __builtin_memcpy(&f, &v, 4);
    return f;
}

// ---------------------------------------------------------------- prep:
// y 0-3: f32 transposes (conv64 + maxconv weights); y 4-6: bf16 MFMA-B-fragment
// swizzle of the three convgn weights; y 7: zero stats.
__global__ void prep_kernel(const float* __restrict__ t11_w, const float* __restrict__ t22_w,
                            const float* __restrict__ t1_w,  const float* __restrict__ t2_w,
                            const float* __restrict__ m1a_w, const float* __restrict__ m1b_w,
                            const float* __restrict__ m2a_w,
                            float* __restrict__ wTt11, float* __restrict__ wTt22,
                            float* __restrict__ wTt1,  float* __restrict__ wTt2,
                            ushort_t* __restrict__ W2m1a, ushort_t* __restrict__ W2m1b,
                            ushort_t* __restrict__ W2m2a, float* __restrict__ stats) {
    int y = blockIdx.y;
    int idx = blockIdx.x * 256 + threadIdx.x;
    if (y == 7) {
        if (idx < 8 * STAT_STRIDE) stats[idx] = 0.0f;
        return;
    }
    if (y < 4) {
        const float* in; float* outp; int Cdim;
        switch (y) {
            case 0: in = t11_w; outp = wTt11; Cdim = 64; break;
            case 1: in = t22_w; outp = wTt22; Cdim = 64; break;
            case 2: in = t1_w;  outp = wTt1;  Cdim = CC; break;
            default: in = t2_w; outp = wTt2;  Cdim = CC; break;
        }
        if (idx < CC * Cdim) {
            int o = idx / Cdim, c = idx % Cdim;
            outp[c * CC + o] = in[idx];
        }
        return;
    }
    // B-fragment swizzle: idx = kb*4096 + coT*512 + lane*8 + j
    const float* in = y == 4 ? m1a_w : y == 5 ? m1b_w : m2a_w;
    ushort_t* outp  = y == 4 ? W2m1a : y == 5 ? W2m1b : W2m2a;
    if (idx < 16384) {
        int j = idx & 7, lane = (idx >> 3) & 63, coT = (idx >> 9) & 7, kb = idx >> 12;
        int k  = kb * 32 + (lane >> 4) * 8 + j;
        int co = coT * 16 + (lane & 15);
        outp[idx] = f2bf(in[co * CC + k]);
    }
}

// ------------------------------------------------- conv1d 64->128, LDS-staged tile GEMM
__global__ __launch_bounds__(256) void conv64_kernel(
        const float* __restrict__ feat1, const float* __restrict__ feat2,
        const float* __restrict__ wTt11, const float* __restrict__ wTt22,
        const float* __restrict__ b11, const float* __restrict__ b22,
        float* __restrict__ f1, float* __restrict__ f2,
        float* __restrict__ g1, float* __restrict__ g2) {
    __shared__ float xs[64][68];           // [ci][n], pad 68 -> 17 KB
    int y = blockIdx.y;
    const float* x  = (y == 0 || y == 3) ? feat1 : feat2;
    const float* wT = (y == 0 || y == 2) ? wTt11 : wTt22;
    const float* bias = (y == 0 || y == 2) ? b11 : b22;
    float* outp = y == 0 ? f1 : y == 1 ? f2 : y == 2 ? g1 : g2;
    int tid = threadIdx.x;
    int n0 = blockIdx.x * 64;              // b*N + n base; never crosses b
    int b = n0 >> 12, nloc = n0 & 4095;
    const float* xb = x + (size_t)b * 64 * NPTS + nloc;
    #pragma unroll
    for (int i = 0; i < 16; ++i) {
        int e = tid + 256 * i;             // e = ci*64 + nn
        int ci = e >> 6, nn = e & 63;
        xs[ci][nn] = xb[(size_t)ci * NPTS + nn];
    }
    __syncthreads();
    int co = (tid & 31) * 4;
    int r0 = (tid >> 5) * 8;
    float acc[4][8];
    float4 bv = *(const float4*)&bias[co];
    #pragma unroll
    for (int j = 0; j < 8; ++j) { acc[0][j] = bv.x; acc[1][j] = bv.y; acc[2][j] = bv.z; acc[3][j] = bv.w; }
    for (int ci = 0; ci < 64; ++ci) {
        float4 wv = *(const float4*)&wT[(size_t)ci * CC + co];
        #pragma unroll
        for (int j = 0; j < 8; ++j) {
            float xv = xs[ci][r0 + j];     // broadcast within half-wave
            acc[0][j] += wv.x * xv;
            acc[1][j] += wv.y * xv;
            acc[2][j] += wv.z * xv;
            acc[3][j] += wv.w * xv;
        }
    }
    #pragma unroll
    for (int j = 0; j < 8; ++j) {
        *(float4*)&outp[(size_t)(n0 + r0 + j) * CC + co] =
            make_float4(acc[0][j], acc[1][j], acc[2][j], acc[3][j]);
    }
}

// ---------------------------------------------------------------- 64-bit shuffles
static __device__ __forceinline__ unsigned long long sxor64(unsigned long long v, int m) {
    unsigned lo = (unsigned)__shfl_xor((int)(unsigned)v, m);
    unsigned hi = (unsigned)__shfl_xor((int)(v >> 32), m);
    return ((unsigned long long)hi << 32) | lo;
}

// ------------------------------------------------- KNN (unchanged, passing)
__global__ __launch_bounds__(512) void knn_kernel(
        const float* __restrict__ pc1, const float* __restrict__ pc2,
        int* __restrict__ idx12, int* __restrict__ idx21) {
#pragma clang fp contract(off)
    __shared__ float4 pk[NPTS];                           // 64 KB
    __shared__ unsigned long long lst[8][4][64];          // 16 KB
    int dir = blockIdx.y;
    const float* qs = dir ? pc2 : pc1;
    const float* cs = dir ? pc1 : pc2;
    int* outIdx = dir ? idx21 : idx12;
    int tid = threadIdx.x, lane = tid & 63, wv = tid >> 6;
    int qbase = blockIdx.x * 32;           // 32 queries per block, same b
    int b = qbase >> 12;
    const float* cb = cs + (size_t)b * 3 * NPTS;
    for (int i = tid; i < NPTS; i += 512) {
        float x = cb[i], y = cb[NPTS + i], z = cb[2 * NPTS + i];
        pk[i] = make_float4(x, y, z, x * x + y * y + z * z);  // l2r, no fma
    }
    __syncthreads();
    const float* qb = qs + (size_t)b * 3 * NPTS;
    int q0 = qbase + wv * 4;
    float qx[4], qy[4], qz[4], s1[4], dmin[4], T[4];
    #pragma unroll
    for (int t = 0; t < 4; ++t) {
        int n = (q0 + t) & 4095;
        qx[t] = qb[n]; qy[t] = qb[NPTS + n]; qz[t] = qb[2 * NPTS + n];
        s1[t] = qx[t] * qx[t] + qy[t] * qy[t] + qz[t] * qz[t];   // l2r, no fma
        dmin[t] = 1e30f;
    }
    for (int j = 0; j < 64; ++j) {
        float4 P = pk[j * 64 + lane];
        #pragma unroll
        for (int t = 0; t < 4; ++t) {
            float dt = __builtin_fmaf(P.z, qz[t], __builtin_fmaf(P.y, qy[t], P.x * qx[t]));
            float d2 = (s1[t] + P.w) - 2.0f * dt;
            dmin[t] = fminf(dmin[t], d2);
        }
    }
    #pragma unroll
    for (int t = 0; t < 4; ++t) {
        float sv = dmin[t];
        for (int k = 2; k <= 64; k <<= 1)
            for (int j = k >> 1; j > 0; j >>= 1) {
                float o = __shfl_xor(sv, j);
                bool tmin = (((lane & k) == 0) == ((lane & j) == 0));
                sv = tmin ? fminf(sv, o) : fmaxf(sv, o);
            }
        T[t] = __shfl(sv, 15);
    }
    int base[4] = {0, 0, 0, 0};
    for (int j = 0; j < 64; ++j) {
        float4 P = pk[j * 64 + lane];
        int m = j * 64 + lane;
        #pragma unroll
        for (int t = 0; t < 4; ++t) {
            float dt = __builtin_fmaf(P.z, qz[t], __builtin_fmaf(P.y, qy[t], P.x * qx[t]));
            float d2 = (s1[t] + P.w) - 2.0f * dt;
            bool p = (d2 <= T[t]);
            unsigned long long mk = __ballot(p);
            if (p) {
                int pos = base[t] + (int)__popcll(mk & ((1ULL << lane) - 1ULL));
                unsigned u = __float_as_uint(d2);
                u ^= (unsigned)(((int)u >> 31) | 0x80000000);
                unsigned long long key = ((unsigned long long)u << 32) | (unsigned)m;
                if (pos < 64) lst[wv][t][pos] = key;
            }
            base[t] += (int)__popcll(mk);
        }
    }
    #pragma unroll
    for (int t = 0; t < 4; ++t) {
        int nT = base[t] < 64 ? base[t] : 64;   // E[survivors]~19; P(>64) ~ 1e-24
        unsigned long long key = (lane < nT) ? lst[wv][t][lane] : ~0ULL;
        for (int k = 2; k <= 64; k <<= 1)
            for (int j = k >> 1; j > 0; j >>= 1) {
                unsigned long long o = sxor64(key, j);
                bool tmin = (((lane & k) == 0) == ((lane & j) == 0));
                unsigned long long mn = key < o ? key : o;
                unsigned long long mx = key < o ? o : key;
                key = tmin ? mn : mx;
            }
        if (lane < KNN) outIdx[(size_t)(q0 + t) * KNN + lane] = (int)(unsigned)(key & 0xFFFFFFFFULL);
    }
}

// ------------------------------------------------- h0 = group(p2) + p1 + pos_conv + fused stats
__global__ void h0_kernel(const float* __restrict__ p1f, const float* __restrict__ p2f,
                          const float* __restrict__ pcA, const float* __restrict__ pcB,
                          const int* __restrict__ idx,
                          const float* __restrict__ pos_w, const float* __restrict__ pos_b,
                          ushort_t* __restrict__ buf, float* __restrict__ stats_out) {
    __shared__ float redS[128], redQ[128];
    int p = blockIdx.x;                    // b*N + n
    int b = p >> 12, n = p & 4095;
    int c = threadIdx.x;
    float pw0 = pos_w[c * 3], pw1 = pos_w[c * 3 + 1], pw2 = pos_w[c * 3 + 2];
    float pb = pos_b[c];
    float p1v = p1f[(size_t)p * CC + c];
    const float* pa = pcA + (size_t)b * 3 * NPTS;
    const float* pc = pcB + (size_t)b * 3 * NPTS;
    float qx = pa[n], qy = pa[NPTS + n], qz = pa[2 * NPTS + n];
    float S = 0.f, Q = 0.f;
    for (int k = 0; k < KNN; ++k) {
        int m = idx[(size_t)p * KNN + k];
        float dx = pc[m] - qx;
        float dy = pc[NPTS + m] - qy;
        float dz = pc[2 * NPTS + m] - qz;
        float pos = pw0 * dx + pw1 * dy + pw2 * dz + pb;
        float v = p2f[((size_t)b * NPTS + m) * CC + c] + p1v + pos;
        buf[((size_t)p * KNN + k) * CC + c] = f2bf(v);
        S += v; Q += v * v;
    }
    redS[c] = S; redQ[c] = Q;
    __syncthreads();
    if (c < 8) {
        float SS = 0.f, QQ = 0.f;
        for (int i = 0; i < 16; ++i) { SS += redS[c * 16 + i]; QQ += redQ[c * 16 + i]; }
        int s = blockIdx.x & 31;
        atomicAdd(&stats_out[s * 32 + (b * 8 + c) * 2],     SS);
        atomicAdd(&stats_out[s * 32 + (b * 8 + c) * 2 + 1], QQ);
    }
}

// ------------------------------------------------- y = W * lrelu(gn(x)) + bias via bf16 MFMA
__global__ __launch_bounds__(256) void convgn_kernel(
        const ushort_t* __restrict__ xbuf, const float* __restrict__ stats_in,
        const float* __restrict__ gam, const float* __restrict__ bet,
        const ushort_t* __restrict__ W2, const float* __restrict__ bias,
        ushort_t* __restrict__ ybuf, float* __restrict__ stats_out) {
    __shared__ ushort_t xt[64 * 136];      // bf16, row stride 136 (272B = 17*16B: aligned, 2-way alias)
    __shared__ float sc[CC], sh[CC];
    __shared__ float redS[4][8], redQ[4][8];
    int tid = threadIdx.x;
    int s0 = blockIdx.x * 64;              // 64 rows, never crosses b
    int b = s0 >> 16;
    if (tid < CC) {
        int g = tid >> 4;
        float S = 0.f, Q = 0.f;
        for (int s = 0; s < 32; ++s) {
            S += stats_in[s * 32 + (b * 8 + g) * 2];
            Q += stats_in[s * 32 + (b * 8 + g) * 2 + 1];
        }
        float mu = S / CNT_PER_GROUP;
        float var = Q / CNT_PER_GROUP - mu * mu;
        float rs = rsqrtf(var + 1e-5f);
        float scale = gam[tid] * rs;
        sc[tid] = scale;
        sh[tid] = bet[tid] - mu * scale;
    }
    __syncthreads();
    // stage GN+lrelu x into LDS as bf16 (ushort8 = 16B loads/stores)
    #pragma unroll
    for (int j = 0; j < 4; ++j) {
        int idx = tid + 256 * j;           // 1024 ushort8 chunks
        int row = idx >> 4, c8 = (idx & 15) * 8;
        u16x8 vin = *(const u16x8*)&xbuf[(size_t)(s0 + row) * CC + c8];
        u16x8 vo;
        #pragma unroll
        for (int e = 0; e < 8; ++e) {
            float v = bf2f(vin[e]) * sc[c8 + e] + sh[c8 + e];
            v = v >= 0.f ? v : 0.1f * v;
            vo[e] = f2bf(v);
        }
        *(u16x8*)&xt[row * 136 + c8] = vo;
    }
    __syncthreads();
    int lane = tid & 63, wv = tid >> 6;
    int r0 = wv * 16;
    int quad = lane >> 4;
    f32x4 acc[8];
    #pragma unroll
    for (int t = 0; t < 8; ++t) acc[t] = (f32x4){0.f, 0.f, 0.f, 0.f};
    int aoff = (r0 + (lane & 15)) * 136 + quad * 8;
    #pragma unroll
    for (int kb = 0; kb < 4; ++kb) {
        bf16x8 a = *(const bf16x8*)&xt[aoff + kb * 32];
        const ushort_t* wb = W2 + (size_t)kb * 4096 + lane * 8;
        #pragma unroll
        for (int t = 0; t < 8; ++t) {
            bf16x8 bf = *(const bf16x8*)&wb[t * 512];
            acc[t] = __builtin_amdgcn_mfma_f32_16x16x32_bf16(a, bf, acc[t], 0, 0, 0);
        }
    }
    // epilogue: bias, store bf16, fused stats from f32 (group g == co-tile t)
    #pragma unroll
    for (int t = 0; t < 8; ++t) {
        int co = t * 16 + (lane & 15);
        float bv = bias[co];
        float S = 0.f, Q = 0.f;
        #pragma unroll
        for (int reg = 0; reg < 4; ++reg) {
            int row = s0 + r0 + quad * 4 + reg;
            float y = acc[t][reg] + bv;
            ybuf[(size_t)row * CC + co] = f2bf(y);
            S += y; Q += y * y;
        }
        #pragma unroll
        for (int off = 1; off < 64; off <<= 1) {
            S += __shfl_xor(S, off);
            Q += __shfl_xor(Q, off);
        }
        if (lane == 0) { redS[wv][t] = S; redQ[wv][t] = Q; }
    }
    __syncthreads();
    if (tid < 8) {
        float S = redS[0][tid] + redS[1][tid] + redS[2][tid] + redS[3][tid];
        float Q = redQ[0][tid] + redQ[1][tid] + redQ[2][tid] + redQ[3][tid];
        int s = blockIdx.x & 31;
        atomicAdd(&stats_out[s * 32 + (b * 8 + tid) * 2],     S);
        atomicAdd(&stats_out[s * 32 + (b * 8 + tid) * 2 + 1], Q);
    }
}

// ------------------------------------------------- maxpool (cross3 tail), n-run writes
// block: 16 points x 128 ch; thread (c, half) owns 8 rows -> 32B contiguous outb runs
__global__ __launch_bounds__(256) void maxpool_kernel(
        const ushort_t* __restrict__ ybuf, const float* __restrict__ stats,
        const float* __restrict__ gam, const float* __restrict__ bet,
        float* __restrict__ outb) {
    int p0 = blockIdx.x * 16;              // b*N + n base, same b
    int b = p0 >> 12, n0 = p0 & 4095;
    int tid = threadIdx.x;
    int c = tid & 127, half = tid >> 7;
    int g = c >> 4;
    float S = 0.f, Q = 0.f;
    for (int s = 0; s < 32; ++s) {
        S += stats[s * 32 + (b * 8 + g) * 2];
        Q += stats[s * 32 + (b * 8 + g) * 2 + 1];
    }
    float mu = S / CNT_PER_GROUP;
    float var = Q / CNT_PER_GROUP - mu * mu;
    float rs = rsqrtf(var + 1e-5f);
    float scale = gam[c] * rs;
    float shift = bet[c] - mu * scale;
    float* orow = outb + ((size_t)b * CC + c) * NPTS + n0 + half * 8;
    #pragma unroll
    for (int j = 0; j < 8; ++j) {
        int nl = half * 8 + j;
        float mx = -INFINITY;
        for (int k = 0; k < KNN; ++k) {
            float v = bf2f(ybuf[((size_t)(p0 + nl) * KNN + k) * CC + c]) * scale + shift;
            v = v >= 0.f ? v : 0.1f * v;
            mx = fmaxf(mx, v);
        }
        orow[j] = mx;
    }
}

// ------------------------------------------------- fused maxpool + 128x128 conv (cross1/2 tail)
// block: 16 points x 128 ch; LDS mxs; conv ci-ascending (bit-identical); n-run outb writes
__global__ __launch_bounds__(256) void maxconv_kernel(
        const ushort_t* __restrict__ ybuf, const float* __restrict__ stats,
        const float* __restrict__ gam, const float* __restrict__ bet,
        const float* __restrict__ wT, const float* __restrict__ bias,
        float* __restrict__ outf, float* __restrict__ outb) {
    __shared__ float mxs[16][CC + 4];
    int p0 = blockIdx.x * 16;              // b*N + n base, same b
    int b = p0 >> 12, n0 = p0 & 4095;
    int tid = threadIdx.x;
    int c = tid & 127, half = tid >> 7;
    int g = c >> 4;
    float S = 0.f, Q = 0.f;
    for (int s = 0; s < 32; ++s) {
        S += stats[s * 32 + (b * 8 + g) * 2];
        Q += stats[s * 32 + (b * 8 + g) * 2 + 1];
    }
    float mu = S / CNT_PER_GROUP;
    float var = Q / CNT_PER_GROUP - mu * mu;
    float rs = rsqrtf(var + 1e-5f);
    float scale = gam[c] * rs;
    float shift = bet[c] - mu * scale;
    #pragma unroll
    for (int j = 0; j < 8; ++j) {
        int nl = half * 8 + j;
        float mx = -INFINITY;
        for (int k = 0; k < KNN; ++k) {
            float v = bf2f(ybuf[((size_t)(p0 + nl) * KNN + k) * CC + c]) * scale + shift;
            v = v >= 0.f ? v : 0.1f * v;
            mx = fmaxf(mx, v);
        }
        mxs[nl][c] = mx;
    }
    __syncthreads();
    float acc[8];
    float bv = bias[c];
    #pragma unroll
    for (int j = 0; j < 8; ++j) acc[j] = bv;
    for (int ci = 0; ci < CC; ++ci) {
        float wv = wT[(size_t)ci * CC + c];
        #pragma unroll
        for (int j = 0; j < 8; ++j)
            acc[j] += wv * mxs[half * 8 + j][ci];   // broadcast (wave-uniform nl, ci)
    }
    #pragma unroll
    for (int j = 0; j < 8; ++j)
        outf[(size_t)(p0 + half * 8 + j) * CC + c] = acc[j];
    float* orow = outb + ((size_t)b * CC + c) * NPTS + n0 + half * 8;
    #pragma unroll
    for (int j = 0; j < 8; ++j) orow[j] = acc[j];
}

extern "C" void kernel_launch(void* const* d_in, const int* in_sizes, int n_in,
                              void* d_out, int out_size, void* d_ws, size_t ws_size,
                              hipStream_t stream) {
    (void)in_sizes; (void)n_in; (void)out_size; (void)ws_size;
    const float* pc1    = (const float*)d_in[0];
    const float* pc2    = (const float*)d_in[1];
    const float* feat1  = (const float*)d_in[2];
    const float* feat2  = (const float*)d_in[3];
    const float* t11_w  = (const float*)d_in[4];
    const float* t11_b  = (const float*)d_in[5];
    const float* t22_w  = (const float*)d_in[6];
    const float* t22_b  = (const float*)d_in[7];
    const float* pos1_w = (const float*)d_in[8];
    const float* pos1_b = (const float*)d_in[9];
    const float* gn1_g  = (const float*)d_in[10];
    const float* gn1_b  = (const float*)d_in[11];
    const float* m1a_w  = (const float*)d_in[12];
    const float* m1a_b  = (const float*)d_in[13];
    const float* m1a_g  = (const float*)d_in[14];
    const float* m1a_be = (const float*)d_in[15];
    const float* m1b_w  = (const float*)d_in[16];
    const float* m1b_b  = (const float*)d_in[17];
    const float* m1b_g  = (const float*)d_in[18];
    const float* m1b_be = (const float*)d_in[19];
    const float* t1_w   = (const float*)d_in[20];
    const float* t1_b   = (const float*)d_in[21];
    const float* t2_w   = (const float*)d_in[22];
    const float* t2_b   = (const float*)d_in[23];
    const float* pos2_w = (const float*)d_in[24];
    const float* pos2_b = (const float*)d_in[25];
    const float* gn2_g  = (const float*)d_in[26];
    const float* gn2_b  = (const float*)d_in[27];
    const float* m2a_w  = (const float*)d_in[28];
    const float* m2a_b  = (const float*)d_in[29];
    const float* m2a_g  = (const float*)d_in[30];
    const float* m2a_be = (const float*)d_in[31];

    float* out = (float*)d_out;
    const size_t PN = 2 * NPTS;              // 8192 points
    const size_t PT = PN * CC;               // 1,048,576 elements per point-tensor
    float* ws   = (float*)d_ws;
    float* f1   = ws;
    float* f2   = f1 + PT;
    float* g1   = f2 + PT;
    float* g2   = g1 + PT;
    float* f1n  = g2 + PT;
    float* f2n  = f1n + PT;
    int*   idx12 = (int*)(f2n + PT);
    int*   idx21 = idx12 + PN * KNN;
    float* stats = (float*)(idx21 + PN * KNN);     // 8 stages * 1024
    float* wTt11 = stats + 8 * STAT_STRIDE;        // f32 [64][128]
    float* wTt22 = wTt11 + 64 * CC;
    float* wTt1  = wTt22 + 64 * CC;                // f32 [128][128]
    float* wTt2  = wTt1 + CC * CC;
    ushort_t* W2m1a = (ushort_t*)(wTt2 + CC * CC); // bf16 swizzled [16384]
    ushort_t* W2m1b = W2m1a + 16384;
    ushort_t* W2m2a = W2m1b + 16384;
    ushort_t* bufX  = W2m2a + 16384;               // bf16 [PN*KNN*CC]
    ushort_t* bufY  = bufX + (size_t)PN * KNN * CC;

    prep_kernel<<<dim3(64, 8), 256, 0, stream>>>(
        t11_w, t22_w, t1_w, t2_w, m1a_w, m1b_w, m2a_w,
        wTt11, wTt22, wTt1, wTt2, W2m1a, W2m1b, W2m2a, stats);

    conv64_kernel<<<dim3(PN / 64, 4), 256, 0, stream>>>(
        feat1, feat2, wTt11, wTt22, t11_b, t22_b, f1, f2, g1, g2);
    knn_kernel<<<dim3(PN / 32, 2), 512, 0, stream>>>(pc1, pc2, idx12, idx21);

    float* st0 = stats;
    // ---- cross1: (pc1, pc2, f1, f2) -> t1 -> feat1_new
    h0_kernel<<<PN, 128, 0, stream>>>(f1, f2, pc1, pc2, idx12, pos1_w, pos1_b, bufX, st0 + 0 * STAT_STRIDE);
    convgn_kernel<<<2048, 256, 0, stream>>>(bufX, st0 + 0 * STAT_STRIDE, gn1_g, gn1_b, W2m1a, m1a_b, bufY, st0 + 1 * STAT_STRIDE);
    convgn_kernel<<<2048, 256, 0, stream>>>(bufY, st0 + 1 * STAT_STRIDE, m1a_g, m1a_be, W2m1b, m1b_b, bufX, st0 + 2 * STAT_STRIDE);
    maxconv_kernel<<<PN / 16, 256, 0, stream>>>(bufX, st0 + 2 * STAT_STRIDE, m1b_g, m1b_be, wTt1, t1_b, f1n, out);

    // ---- cross2: (pc2, pc1, g1, g2) -> t2 -> feat2_new
    h0_kernel<<<PN, 128, 0, stream>>>(g1, g2, pc2, pc1, idx21, pos1_w, pos1_b, bufX, st0 + 3 * STAT_STRIDE);
    convgn_kernel<<<2048, 256, 0, stream>>>(bufX, st0 + 3 * STAT_STRIDE, gn1_g, gn1_b, W2m1a, m1a_b, bufY, st0 + 4 * STAT_STRIDE);
    convgn_kernel<<<2048, 256, 0, stream>>>(bufY, st0 + 4 * STAT_STRIDE, m1a_g, m1a_be, W2m1b, m1b_b, bufX, st0 + 5 * STAT_STRIDE);
    maxconv_kernel<<<PN / 16, 256, 0, stream>>>(bufX, st0 + 5 * STAT_STRIDE, m1b_g, m1b_be, wTt2, t2_b, f2n, out + PT);

    // ---- cross3: (pc1, pc2, feat1_new, feat2_new) -> feat1_final
    h0_kernel<<<PN, 128, 0, stream>>>(f1n, f2n, pc1, pc2, idx12, pos2_w, pos2_b, bufX, st0 + 6 * STAT_STRIDE);
    convgn_kernel<<<2048, 256, 0, stream>>>(bufX, st0 + 6 * STAT_STRIDE, gn2_g, gn2_b, W2m2a, m2a_b, bufY, st0 + 7 * STAT_STRIDE);
    maxpool_kernel<<<PN / 16, 256, 0, stream>>>(bufY, st0 + 7 * STAT_STRIDE, m2a_g, m2a_be, out + 2 * PT);
}

// Round 12
// 375.703 us; speedup vs baseline: 5.9789x; 1.0591x over previous
//
#include <hip/hip_runtime.h>
#include <hip/hip_bf16.h>

#define NPTS 4096
#define CC   128
#define KNN  16
#define CNT_PER_GROUP 1048576.0f  // 16 ch * 4096 n * 16 k
#define STAT_STRIDE 1024          // 32 partial slots x [b(2) x g(8) x 2]

typedef __attribute__((ext_vector_type(8))) short bf16x8;
typedef __attribute__((ext_vector_type(8))) unsigned short u16x8;
typedef __attribute__((ext_vector_type(4))) float f32x4;
typedef unsigned short ushort_t;

static __device__ __forceinline__ ushort_t f2bf(float f) {
    __hip_bfloat16 h = __float2bfloat16(f);   // RNE
    ushort_t u; __builtin_memcpy(&u, &h, 2);
    return u;
}
static __device__ __forceinline__ float bf2f(ushort_t u) {
    unsigned v = (unsigned)u << 16;
    float f; __builtin_memcpy(&f, &v, 4);
    return f;
}

// ---------------------------------------------------------------- prep
__global__ void prep_kernel(const float* __restrict__ t11_w, const float* __restrict__ t22_w,
                            const float* __restrict__ t1_w,  const float* __restrict__ t2_w,
                            const float* __restrict__ m1a_w, const float* __restrict__ m1b_w,
                            const float* __restrict__ m2a_w,
                            float* __restrict__ wTt11, float* __restrict__ wTt22,
                            float* __restrict__ wTt1,  float* __restrict__ wTt2,
                            ushort_t* __restrict__ W2m1a, ushort_t* __restrict__ W2m1b,
                            ushort_t* __restrict__ W2m2a, float* __restrict__ stats) {
    int y = blockIdx.y;
    int idx = blockIdx.x * 256 + threadIdx.x;
    if (y == 7) {
        if (idx < 8 * STAT_STRIDE) stats[idx] = 0.0f;
        return;
    }
    if (y < 4) {
        const float* in; float* outp; int Cdim;
        switch (y) {
            case 0: in = t11_w; outp = wTt11; Cdim = 64; break;
            case 1: in = t22_w; outp = wTt22; Cdim = 64; break;
            case 2: in = t1_w;  outp = wTt1;  Cdim = CC; break;
            default: in = t2_w; outp = wTt2;  Cdim = CC; break;
        }
        if (idx < CC * Cdim) {
            int o = idx / Cdim, c = idx % Cdim;
            outp[c * CC + o] = in[idx];
        }
        return;
    }
    const float* in = y == 4 ? m1a_w : y == 5 ? m1b_w : m2a_w;
    ushort_t* outp  = y == 4 ? W2m1a : y == 5 ? W2m1b : W2m2a;
    if (idx < 16384) {
        int j = idx & 7, lane = (idx >> 3) & 63, coT = (idx >> 9) & 7, kb = idx >> 12;
        int k  = kb * 32 + (lane >> 4) * 8 + j;
        int co = coT * 16 + (lane & 15);
        outp[idx] = f2bf(in[co * CC + k]);
    }
}

// ------------------------------------------------- conv1d 64->128, LDS-staged tile GEMM
__global__ __launch_bounds__(256) void conv64_kernel(
        const float* __restrict__ feat1, const float* __restrict__ feat2,
        const float* __restrict__ wTt11, const float* __restrict__ wTt22,
        const float* __restrict__ b11, const float* __restrict__ b22,
        float* __restrict__ f1, float* __restrict__ f2,
        float* __restrict__ g1, float* __restrict__ g2) {
    __shared__ float xs[64][68];
    int y = blockIdx.y;
    const float* x  = (y == 0 || y == 3) ? feat1 : feat2;
    const float* wT = (y == 0 || y == 2) ? wTt11 : wTt22;
    const float* bias = (y == 0 || y == 2) ? b11 : b22;
    float* outp = y == 0 ? f1 : y == 1 ? f2 : y == 2 ? g1 : g2;
    int tid = threadIdx.x;
    int n0 = blockIdx.x * 64;
    int b = n0 >> 12, nloc = n0 & 4095;
    const float* xb = x + (size_t)b * 64 * NPTS + nloc;
    #pragma unroll
    for (int i = 0; i < 16; ++i) {
        int e = tid + 256 * i;
        int ci = e >> 6, nn = e & 63;
        xs[ci][nn] = xb[(size_t)ci * NPTS + nn];
    }
    __syncthreads();
    int co = (tid & 31) * 4;
    int r0 = (tid >> 5) * 8;
    float acc[4][8];
    float4 bv = *(const float4*)&bias[co];
    #pragma unroll
    for (int j = 0; j < 8; ++j) { acc[0][j] = bv.x; acc[1][j] = bv.y; acc[2][j] = bv.z; acc[3][j] = bv.w; }
    for (int ci = 0; ci < 64; ++ci) {
        float4 wv = *(const float4*)&wT[(size_t)ci * CC + co];
        #pragma unroll
        for (int j = 0; j < 8; ++j) {
            float xv = xs[ci][r0 + j];
            acc[0][j] += wv.x * xv;
            acc[1][j] += wv.y * xv;
            acc[2][j] += wv.z * xv;
            acc[3][j] += wv.w * xv;
        }
    }
    #pragma unroll
    for (int j = 0; j < 8; ++j) {
        *(float4*)&outp[(size_t)(n0 + r0 + j) * CC + co] =
            make_float4(acc[0][j], acc[1][j], acc[2][j], acc[3][j]);
    }
}

// ---------------------------------------------------------------- 64-bit shuffles
static __device__ __forceinline__ unsigned long long sxor64(unsigned long long v, int m) {
    unsigned lo = (unsigned)__shfl_xor((int)(unsigned)v, m);
    unsigned hi = (unsigned)__shfl_xor((int)(v >> 32), m);
    return ((unsigned long long)hi << 32) | lo;
}

// ------------------------------------------------- KNN: atomic-append pass 2
// Append order is irrelevant: final bitonic sort on (d2-bits, idx) is a total order.
__global__ __launch_bounds__(512) void knn_kernel(
        const float* __restrict__ pc1, const float* __restrict__ pc2,
        int* __restrict__ idx12, int* __restrict__ idx21) {
#pragma clang fp contract(off)
    __shared__ float4 pk[NPTS];                           // 64 KB
    __shared__ unsigned long long lst[8][4][63];          // 15.75 KB
    __shared__ int cnt[8][4];                             // 128 B  (total 81792 <= 81920)
    int dir = blockIdx.y;
    const float* qs = dir ? pc2 : pc1;
    const float* cs = dir ? pc1 : pc2;
    int* outIdx = dir ? idx21 : idx12;
    int tid = threadIdx.x, lane = tid & 63, wv = tid >> 6;
    int qbase = blockIdx.x * 32;
    int b = qbase >> 12;
    const float* cb = cs + (size_t)b * 3 * NPTS;
    for (int i = tid; i < NPTS; i += 512) {
        float x = cb[i], y = cb[NPTS + i], z = cb[2 * NPTS + i];
        pk[i] = make_float4(x, y, z, x * x + y * y + z * z);  // l2r, no fma
    }
    __syncthreads();
    const float* qb = qs + (size_t)b * 3 * NPTS;
    int q0 = qbase + wv * 4;
    float qx[4], qy[4], qz[4], s1[4], dmin[4], T[4];
    #pragma unroll
    for (int t = 0; t < 4; ++t) {
        int n = (q0 + t) & 4095;
        qx[t] = qb[n]; qy[t] = qb[NPTS + n]; qz[t] = qb[2 * NPTS + n];
        s1[t] = qx[t] * qx[t] + qy[t] * qy[t] + qz[t] * qz[t];
        dmin[t] = 1e30f;
    }
    for (int j = 0; j < 64; ++j) {
        float4 P = pk[j * 64 + lane];
        #pragma unroll
        for (int t = 0; t < 4; ++t) {
            float dt = __builtin_fmaf(P.z, qz[t], __builtin_fmaf(P.y, qy[t], P.x * qx[t]));
            float d2 = (s1[t] + P.w) - 2.0f * dt;
            dmin[t] = fminf(dmin[t], d2);
        }
    }
    #pragma unroll
    for (int t = 0; t < 4; ++t) {
        float sv = dmin[t];
        for (int k = 2; k <= 64; k <<= 1)
            for (int j = k >> 1; j > 0; j >>= 1) {
                float o = __shfl_xor(sv, j);
                bool tmin = (((lane & k) == 0) == ((lane & j) == 0));
                sv = tmin ? fminf(sv, o) : fmaxf(sv, o);
            }
        T[t] = __shfl(sv, 15);
    }
    if (lane < 4) cnt[wv][lane] = 0;     // per-wave, program-order visible
    for (int j = 0; j < 64; ++j) {
        float4 P = pk[j * 64 + lane];
        int m = j * 64 + lane;
        #pragma unroll
        for (int t = 0; t < 4; ++t) {
            float dt = __builtin_fmaf(P.z, qz[t], __builtin_fmaf(P.y, qy[t], P.x * qx[t]));
            float d2 = (s1[t] + P.w) - 2.0f * dt;
            if (d2 <= T[t]) {            // rare (~19/4096)
                unsigned u = __float_as_uint(d2);
                u ^= (unsigned)(((int)u >> 31) | 0x80000000);
                int pos = atomicAdd(&cnt[wv][t], 1);
                if (pos < 63) lst[wv][t][pos] = ((unsigned long long)u << 32) | (unsigned)m;
            }
        }
    }
    #pragma unroll
    for (int t = 0; t < 4; ++t) {
        int nT = cnt[wv][t]; if (nT > 63) nT = 63;   // P(>63) astronomically small
        unsigned long long key = (lane < nT) ? lst[wv][t][lane] : ~0ULL;
        for (int k = 2; k <= 64; k <<= 1)
            for (int j = k >> 1; j > 0; j >>= 1) {
                unsigned long long o = sxor64(key, j);
                bool tmin = (((lane & k) == 0) == ((lane & j) == 0));
                unsigned long long mn = key < o ? key : o;
                unsigned long long mx = key < o ? o : key;
                key = tmin ? mn : mx;
            }
        if (lane < KNN) outIdx[(size_t)(q0 + t) * KNN + lane] = (int)(unsigned)(key & 0xFFFFFFFFULL);
    }
}

// ------------------------------------------------- h0 (dual: cross1 / cross2 by blockIdx.y)
__global__ void h0_kernel(const float* p1f_1, const float* p2f_1,
                          const float* p1f_2, const float* p2f_2,
                          const float* __restrict__ pc1, const float* __restrict__ pc2,
                          const int* idx_1, const int* idx_2,
                          const float* __restrict__ pos_w, const float* __restrict__ pos_b,
                          ushort_t* buf_1, ushort_t* buf_2,
                          float* stats_1, float* stats_2) {
    __shared__ float redS[128], redQ[128];
    int y = blockIdx.y;
    const float* p1f = y ? p1f_2 : p1f_1;
    const float* p2f = y ? p2f_2 : p2f_1;
    const float* pcA = y ? pc2 : pc1;
    const float* pcB = y ? pc1 : pc2;
    const int* idx = y ? idx_2 : idx_1;
    ushort_t* buf = y ? buf_2 : buf_1;
    float* stats_out = y ? stats_2 : stats_1;
    int p = blockIdx.x;                    // b*N + n
    int b = p >> 12, n = p & 4095;
    int c = threadIdx.x;
    float pw0 = pos_w[c * 3], pw1 = pos_w[c * 3 + 1], pw2 = pos_w[c * 3 + 2];
    float pb = pos_b[c];
    float p1v = p1f[(size_t)p * CC + c];
    const float* pa = pcA + (size_t)b * 3 * NPTS;
    const float* pc = pcB + (size_t)b * 3 * NPTS;
    float qx = pa[n], qy = pa[NPTS + n], qz = pa[2 * NPTS + n];
    float S = 0.f, Q = 0.f;
    for (int k = 0; k < KNN; ++k) {
        int m = idx[(size_t)p * KNN + k];
        float dx = pc[m] - qx;
        float dy = pc[NPTS + m] - qy;
        float dz = pc[2 * NPTS + m] - qz;
        float pos = pw0 * dx + pw1 * dy + pw2 * dz + pb;
        float v = p2f[((size_t)b * NPTS + m) * CC + c] + p1v + pos;
        buf[((size_t)p * KNN + k) * CC + c] = f2bf(v);
        S += v; Q += v * v;
    }
    redS[c] = S; redQ[c] = Q;
    __syncthreads();
    if (c < 8) {
        float SS = 0.f, QQ = 0.f;
        for (int i = 0; i < 16; ++i) { SS += redS[c * 16 + i]; QQ += redQ[c * 16 + i]; }
        int s = blockIdx.x & 31;
        atomicAdd(&stats_out[s * 32 + (b * 8 + c) * 2],     SS);
        atomicAdd(&stats_out[s * 32 + (b * 8 + c) * 2 + 1], QQ);
    }
}

// ------------------------------------------------- convgn (dual) + coalesced epilogue
__global__ __launch_bounds__(256) void convgn_kernel(
        const ushort_t* xbuf_1, const ushort_t* xbuf_2,
        const float* stats_in_1, const float* stats_in_2,
        const float* __restrict__ gam, const float* __restrict__ bet,
        const ushort_t* __restrict__ W2, const float* __restrict__ bias,
        ushort_t* ybuf_1, ushort_t* ybuf_2,
        float* stats_out_1, float* stats_out_2) {
    __shared__ ushort_t xt[64 * 136];
    __shared__ float sc[CC], sh[CC];
    __shared__ float redS[4][8], redQ[4][8];
    int y = blockIdx.y;
    const ushort_t* xbuf = y ? xbuf_2 : xbuf_1;
    const float* stats_in = y ? stats_in_2 : stats_in_1;
    ushort_t* ybuf = y ? ybuf_2 : ybuf_1;
    float* stats_out = y ? stats_out_2 : stats_out_1;
    int tid = threadIdx.x;
    int s0 = blockIdx.x * 64;
    int b = s0 >> 16;
    if (tid < CC) {
        int g = tid >> 4;
        float S = 0.f, Q = 0.f;
        for (int s = 0; s < 32; ++s) {
            S += stats_in[s * 32 + (b * 8 + g) * 2];
            Q += stats_in[s * 32 + (b * 8 + g) * 2 + 1];
        }
        float mu = S / CNT_PER_GROUP;
        float var = Q / CNT_PER_GROUP - mu * mu;
        float rs = rsqrtf(var + 1e-5f);
        float scale = gam[tid] * rs;
        sc[tid] = scale;
        sh[tid] = bet[tid] - mu * scale;
    }
    __syncthreads();
    #pragma unroll
    for (int j = 0; j < 4; ++j) {
        int idx = tid + 256 * j;
        int row = idx >> 4, c8 = (idx & 15) * 8;
        u16x8 vin = *(const u16x8*)&xbuf[(size_t)(s0 + row) * CC + c8];
        u16x8 vo;
        #pragma unroll
        for (int e = 0; e < 8; ++e) {
            float v = bf2f(vin[e]) * sc[c8 + e] + sh[c8 + e];
            v = v >= 0.f ? v : 0.1f * v;
            vo[e] = f2bf(v);
        }
        *(u16x8*)&xt[row * 136 + c8] = vo;
    }
    __syncthreads();
    int lane = tid & 63, wv = tid >> 6;
    int r0 = wv * 16;
    int quad = lane >> 4;
    f32x4 acc[8];
    #pragma unroll
    for (int t = 0; t < 8; ++t) acc[t] = (f32x4){0.f, 0.f, 0.f, 0.f};
    int aoff = (r0 + (lane & 15)) * 136 + quad * 8;
    #pragma unroll
    for (int kb = 0; kb < 4; ++kb) {
        bf16x8 a = *(const bf16x8*)&xt[aoff + kb * 32];
        const ushort_t* wb = W2 + (size_t)kb * 4096 + lane * 8;
        #pragma unroll
        for (int t = 0; t < 8; ++t) {
            bf16x8 bf = *(const bf16x8*)&wb[t * 512];
            acc[t] = __builtin_amdgcn_mfma_f32_16x16x32_bf16(a, bf, acc[t], 0, 0, 0);
        }
    }
    // epilogue: bias + stats; stage bf16 into wave-private slab (rows r0..r0+15 of xt)
    #pragma unroll
    for (int t = 0; t < 8; ++t) {
        int co = t * 16 + (lane & 15);
        float bv = bias[co];
        float S = 0.f, Q = 0.f;
        #pragma unroll
        for (int reg = 0; reg < 4; ++reg) {
            int rl = r0 + quad * 4 + reg;
            float yv = acc[t][reg] + bv;
            xt[rl * 136 + co] = f2bf(yv);
            S += yv; Q += yv * yv;
        }
        #pragma unroll
        for (int off = 1; off < 64; off <<= 1) {
            S += __shfl_xor(S, off);
            Q += __shfl_xor(Q, off);
        }
        if (lane == 0) { redS[wv][t] = S; redQ[wv][t] = Q; }
    }
    // wave-private slab -> coalesced 16B global stores (no barrier: own rows only)
    #pragma unroll
    for (int i = 0; i < 4; ++i) {
        int chunk = i * 64 + lane;             // 0..255 = row(4b) x c8(4b)
        int rl = r0 + (chunk >> 4);
        int c8 = (chunk & 15) * 8;
        u16x8 v = *(const u16x8*)&xt[rl * 136 + c8];
        *(u16x8*)&ybuf[(size_t)(s0 + rl) * CC + c8] = v;
    }
    __syncthreads();
    if (tid < 8) {
        float S = redS[0][tid] + redS[1][tid] + redS[2][tid] + redS[3][tid];
        float Q = redQ[0][tid] + redQ[1][tid] + redQ[2][tid] + redQ[3][tid];
        int s = blockIdx.x & 31;
        atomicAdd(&stats_out[s * 32 + (b * 8 + tid) * 2],     S);
        atomicAdd(&stats_out[s * 32 + (b * 8 + tid) * 2 + 1], Q);
    }
}

// ------------------------------------------------- maxpool (cross3 tail), n-run writes
__global__ __launch_bounds__(256) void maxpool_kernel(
        const ushort_t* __restrict__ ybuf, const float* __restrict__ stats,
        const float* __restrict__ gam, const float* __restrict__ bet,
        float* __restrict__ outb) {
    int p0 = blockIdx.x * 16;
    int b = p0 >> 12, n0 = p0 & 4095;
    int tid = threadIdx.x;
    int c = tid & 127, half = tid >> 7;
    int g = c >> 4;
    float S = 0.f, Q = 0.f;
    for (int s = 0; s < 32; ++s) {
        S += stats[s * 32 + (b * 8 + g) * 2];
        Q += stats[s * 32 + (b * 8 + g) * 2 + 1];
    }
    float mu = S / CNT_PER_GROUP;
    float var = Q / CNT_PER_GROUP - mu * mu;
    float rs = rsqrtf(var + 1e-5f);
    float scale = gam[c] * rs;
    float shift = bet[c] - mu * scale;
    float* orow = outb + ((size_t)b * CC + c) * NPTS + n0 + half * 8;
    #pragma unroll
    for (int j = 0; j < 8; ++j) {
        int nl = half * 8 + j;
        float mx = -INFINITY;
        for (int k = 0; k < KNN; ++k) {
            float v = bf2f(ybuf[((size_t)(p0 + nl) * KNN + k) * CC + c]) * scale + shift;
            v = v >= 0.f ? v : 0.1f * v;
            mx = fmaxf(mx, v);
        }
        orow[j] = mx;
    }
}

// ------------------------------------------------- fused maxpool + conv (dual)
__global__ __launch_bounds__(256) void maxconv_kernel(
        const ushort_t* ybuf_1, const ushort_t* ybuf_2,
        const float* stats_1, const float* stats_2,
        const float* __restrict__ gam, const float* __restrict__ bet,
        const float* wT_1, const float* wT_2,
        const float* bias_1, const float* bias_2,
        float* outf_1, float* outf_2,
        float* __restrict__ outb) {
    __shared__ float mxs[16][CC + 4];
    int y = blockIdx.y;
    const ushort_t* ybuf = y ? ybuf_2 : ybuf_1;
    const float* stats = y ? stats_2 : stats_1;
    const float* wT = y ? wT_2 : wT_1;
    const float* bias = y ? bias_2 : bias_1;
    float* outf = y ? outf_2 : outf_1;
    float* ob = outb + (size_t)y * 2 * NPTS * CC;
    int p0 = blockIdx.x * 16;
    int b = p0 >> 12, n0 = p0 & 4095;
    int tid = threadIdx.x;
    int c = tid & 127, half = tid >> 7;
    int g = c >> 4;
    float S = 0.f, Q = 0.f;
    for (int s = 0; s < 32; ++s) {
        S += stats[s * 32 + (b * 8 + g) * 2];
        Q += stats[s * 32 + (b * 8 + g) * 2 + 1];
    }
    float mu = S / CNT_PER_GROUP;
    float var = Q / CNT_PER_GROUP - mu * mu;
    float rs = rsqrtf(var + 1e-5f);
    float scale = gam[c] * rs;
    float shift = bet[c] - mu * scale;
    #pragma unroll
    for (int j = 0; j < 8; ++j) {
        int nl = half * 8 + j;
        float mx = -INFINITY;
        for (int k = 0; k < KNN; ++k) {
            float v = bf2f(ybuf[((size_t)(p0 + nl) * KNN + k) * CC + c]) * scale + shift;
            v = v >= 0.f ? v : 0.1f * v;
            mx = fmaxf(mx, v);
        }
        mxs[nl][c] = mx;
    }
    __syncthreads();
    float acc[8];
    float bv = bias[c];
    #pragma unroll
    for (int j = 0; j < 8; ++j) acc[j] = bv;
    for (int ci = 0; ci < CC; ++ci) {
        float wv = wT[(size_t)ci * CC + c];
        #pragma unroll
        for (int j = 0; j < 8; ++j)
            acc[j] += wv * mxs[half * 8 + j][ci];
    }
    #pragma unroll
    for (int j = 0; j < 8; ++j)
        outf[(size_t)(p0 + half * 8 + j) * CC + c] = acc[j];
    float* orow = ob + ((size_t)b * CC + c) * NPTS + n0 + half * 8;
    #pragma unroll
    for (int j = 0; j < 8; ++j) orow[j] = acc[j];
}

extern "C" void kernel_launch(void* const* d_in, const int* in_sizes, int n_in,
                              void* d_out, int out_size, void* d_ws, size_t ws_size,
                              hipStream_t stream) {
    (void)in_sizes; (void)n_in; (void)out_size; (void)ws_size;
    const float* pc1    = (const float*)d_in[0];
    const float* pc2    = (const float*)d_in[1];
    const float* feat1  = (const float*)d_in[2];
    const float* feat2  = (const float*)d_in[3];
    const float* t11_w  = (const float*)d_in[4];
    const float* t11_b  = (const float*)d_in[5];
    const float* t22_w  = (const float*)d_in[6];
    const float* t22_b  = (const float*)d_in[7];
    const float* pos1_w = (const float*)d_in[8];
    const float* pos1_b = (const float*)d_in[9];
    const float* gn1_g  = (const float*)d_in[10];
    const float* gn1_b  = (const float*)d_in[11];
    const float* m1a_w  = (const float*)d_in[12];
    const float* m1a_b  = (const float*)d_in[13];
    const float* m1a_g  = (const float*)d_in[14];
    const float* m1a_be = (const float*)d_in[15];
    const float* m1b_w  = (const float*)d_in[16];
    const float* m1b_b  = (const float*)d_in[17];
    const float* m1b_g  = (const float*)d_in[18];
    const float* m1b_be = (const float*)d_in[19];
    const float* t1_w   = (const float*)d_in[20];
    const float* t1_b   = (const float*)d_in[21];
    const float* t2_w   = (const float*)d_in[22];
    const float* t2_b   = (const float*)d_in[23];
    const float* pos2_w = (const float*)d_in[24];
    const float* pos2_b = (const float*)d_in[25];
    const float* gn2_g  = (const float*)d_in[26];
    const float* gn2_b  = (const float*)d_in[27];
    const float* m2a_w  = (const float*)d_in[28];
    const float* m2a_b  = (const float*)d_in[29];
    const float* m2a_g  = (const float*)d_in[30];
    const float* m2a_be = (const float*)d_in[31];

    float* out = (float*)d_out;
    const size_t PN = 2 * NPTS;              // 8192 points
    const size_t PT = PN * CC;               // 1,048,576 elements per point-tensor
    float* ws   = (float*)d_ws;
    float* f1   = ws;
    float* f2   = f1 + PT;
    float* g1   = f2 + PT;
    float* g2   = g1 + PT;
    float* f1n  = g2 + PT;
    float* f2n  = f1n + PT;
    int*   idx12 = (int*)(f2n + PT);
    int*   idx21 = idx12 + PN * KNN;
    float* stats = (float*)(idx21 + PN * KNN);     // 8 stages * 1024
    float* wTt11 = stats + 8 * STAT_STRIDE;
    float* wTt22 = wTt11 + 64 * CC;
    float* wTt1  = wTt22 + 64 * CC;
    float* wTt2  = wTt1 + CC * CC;
    ushort_t* W2m1a = (ushort_t*)(wTt2 + CC * CC);
    ushort_t* W2m1b = W2m1a + 16384;
    ushort_t* W2m2a = W2m1b + 16384;
    ushort_t* bufX1 = W2m2a + 16384;               // bf16 [PN*KNN*CC] each
    ushort_t* bufY1 = bufX1 + (size_t)PN * KNN * CC;
    ushort_t* bufX2 = bufY1 + (size_t)PN * KNN * CC;
    ushort_t* bufY2 = bufX2 + (size_t)PN * KNN * CC;

    prep_kernel<<<dim3(64, 8), 256, 0, stream>>>(
        t11_w, t22_w, t1_w, t2_w, m1a_w, m1b_w, m2a_w,
        wTt11, wTt22, wTt1, wTt2, W2m1a, W2m1b, W2m2a, stats);

    conv64_kernel<<<dim3(PN / 64, 4), 256, 0, stream>>>(
        feat1, feat2, wTt11, wTt22, t11_b, t22_b, f1, f2, g1, g2);
    knn_kernel<<<dim3(PN / 32, 2), 512, 0, stream>>>(pc1, pc2, idx12, idx21);

    float* st0 = stats;
    // ---- cross1 + cross2 merged (independent pipelines, blockIdx.y selects)
    h0_kernel<<<dim3(PN, 2), 128, 0, stream>>>(
        f1, f2, g1, g2, pc1, pc2, idx12, idx21, pos1_w, pos1_b,
        bufX1, bufX2, st0 + 0 * STAT_STRIDE, st0 + 3 * STAT_STRIDE);
    convgn_kernel<<<dim3(2048, 2), 256, 0, stream>>>(
        bufX1, bufX2, st0 + 0 * STAT_STRIDE, st0 + 3 * STAT_STRIDE,
        gn1_g, gn1_b, W2m1a, m1a_b,
        bufY1, bufY2, st0 + 1 * STAT_STRIDE, st0 + 4 * STAT_STRIDE);
    convgn_kernel<<<dim3(2048, 2), 256, 0, stream>>>(
        bufY1, bufY2, st0 + 1 * STAT_STRIDE, st0 + 4 * STAT_STRIDE,
        m1a_g, m1a_be, W2m1b, m1b_b,
        bufX1, bufX2, st0 + 2 * STAT_STRIDE, st0 + 5 * STAT_STRIDE);
    maxconv_kernel<<<dim3(PN / 16, 2), 256, 0, stream>>>(
        bufX1, bufX2, st0 + 2 * STAT_STRIDE, st0 + 5 * STAT_STRIDE,
        m1b_g, m1b_be, wTt1, wTt2, t1_b, t2_b, f1n, f2n, out);

    // ---- cross3: (pc1, pc2, feat1_new, feat2_new) -> feat1_final
    h0_kernel<<<dim3(PN, 1), 128, 0, stream>>>(
        f1n, f2n, f1n, f2n, pc1, pc2, idx12, idx12, pos2_w, pos2_b,
        bufX1, bufX1, st0 + 6 * STAT_STRIDE, st0 + 6 * STAT_STRIDE);
    convgn_kernel<<<dim3(2048, 1), 256, 0, stream>>>(
        bufX1, bufX1, st0 + 6 * STAT_STRIDE, st0 + 6 * STAT_STRIDE,
        gn2_g, gn2_b, W2m2a, m2a_b,
        bufY1, bufY1, st0 + 7 * STAT_STRIDE, st0 + 7 * STAT_STRIDE);
    maxpool_kernel<<<PN / 16, 256, 0, stream>>>(
        bufY1, st0 + 7 * STAT_STRIDE, m2a_g, m2a_be, out + 2 * PT);
}